// Round 8
// baseline (791.488 us; speedup 1.0000x reference)
//
#include <hip/hip_runtime.h>

typedef unsigned int u32;
typedef unsigned short u16;

// Problem constants (fixed by the reference)
constexpr int Gn  = 5000;     // genes
constexpr int Bn  = 32;       // batch graphs
constexpr int Pn  = 5000;     // perts
constexpr int Nn  = Bn * Gn;  // 160000
constexpr int ECO = 1600000;
constexpr int EGG = 100000;
constexpr int NTILES = Nn / 128;  // 1250, exact
constexpr int PTILES = 40;        // 5120 padded rows / 128
constexpr int NBK = 625;          // co dst-buckets (dst>>8), 625*256 == 160000 exactly
constexpr int EPB2 = ECO / 256;   // 6250 edges per sort block (exact)

// ---- workspace layout (float offsets) ----
constexpr int oS2 = 128;     // reduced S2 raw sums (needed by kfinS3e2)
constexpr int oZERO = 1536;  // stays zero (bias)
constexpr int oA1 = 2048, oB1 = 2112, oA2 = 2176, oB2 = 2240;
constexpr int oA4 = 2304, oB4 = 2432;            // 128 each
constexpr int oA5 = 2560, oB5 = 2624;
constexpr int oAG = 2688, oBG = 2752;
constexpr int oAP1 = 2816, oBP1 = 2880, oAP2 = 2944, oBP2 = 3008;
constexpr int oAvec = 3072, oCvec = 3136, oCcP = 3200;
constexpr int oM  = 4096, oM1 = 8192;            // oM1: concatenated [M1|M2] 64x128
constexpr int oE2 = 16384, oEMB = 18432, oCGRAW = 20480, oCG2 = 22528;
constexpr int oRG  = 24576;
constexpr int oRP  = oRG  + Gn * 64;
constexpr int oQ   = oRP  + Gn * 64;
constexpr int oRGO = oQ   + Gn * 64;
constexpr int oRBG = oRGO + Pn * 64;
constexpr int oPM  = oRBG + Pn * 64;   // PM = RP @ M^T, fp32 [Gn][64] (was oAGO scratch)
constexpr int oABG = oPM + Pn * 64;
constexpr int oM1B = oABG + Pn * 64;
constexpr int oM2B = oM1B + Pn * 64;
constexpr int oDGO = oM2B + Pn * 64;
constexpr int oDBG = oDGO + Pn;
constexpr int oDEG = oDBG + Pn;
constexpr int oW1  = oDEG + Nn;
constexpr int oBUF0 = oW1 + Nn;
constexpr int oBUF1 = oBUF0 + Nn * 64;
constexpr size_t WS_FLOATS = (size_t)oBUF1 + (size_t)Nn * 64;  // ~95 MB

__device__ inline u16 f2bf(float f) {
  u32 u = __float_as_uint(f);
  u = (u + 0x7fffu + ((u >> 16) & 1u)) >> 16;
  return (u16)u;
}
__device__ inline float bflo(u32 v) { return __uint_as_float(v << 16); }
__device__ inline float bfhi(u32 v) { return __uint_as_float(v & 0xffff0000u); }
__device__ inline float bf2f(u16 v) { return __uint_as_float((u32)v << 16); }

typedef __attribute__((ext_vector_type(8))) short short8v;  // 8 bf16 (4 VGPRs)
typedef __attribute__((ext_vector_type(4))) float f32x4;    // MFMA accumulator

__global__ __launch_bounds__(256) void kzero(float* p, int n) {
  int i = blockIdx.x * 256 + threadIdx.x;
  if (i < n) p[i] = 0.f;
}

// row-wise L2 renorm (norm clipped to <=1); optional per-block column stats PARTIALS
// (partial[blk][0..63]=sums, [64..127]=sumsq — no global atomics); optional bf16 copy
__global__ __launch_bounds__(256) void krenorm(const float* __restrict__ in, float* __restrict__ out,
                                               float* __restrict__ partial, u16* __restrict__ outb, int rows) {
  int lane = threadIdx.x & 63, wv = threadIdx.x >> 6;
  int gw = blockIdx.x * 4 + wv, nw = gridDim.x * 4;
  float ps = 0.f, pq = 0.f;
  for (int r = gw; r < rows; r += nw) {
    float v = in[r * 64 + lane];
    float sq = v * v;
    for (int off = 32; off; off >>= 1) sq += __shfl_xor(sq, off, 64);
    float nn = sqrtf(sq);
    float s = fminf(1.f, 1.f / fmaxf(nn, 1e-12f));
    float o = v * s;
    out[r * 64 + lane] = o;
    if (outb) outb[r * 64 + lane] = f2bf(o);
    ps += o; pq += o * o;
  }
  if (!partial) return;
  __shared__ float red[4][64], red2[4][64];
  red[wv][lane] = ps; red2[wv][lane] = pq;
  __syncthreads();
  if (wv == 0) {
    float s = red[0][lane] + red[1][lane] + red[2][lane] + red[3][lane];
    float q = red2[0][lane] + red2[1][lane] + red2[2][lane] + red2[3][lane];
    partial[blockIdx.x * 128 + lane] = s;
    partial[blockIdx.x * 128 + 64 + lane] = q;
  }
}

// reduce per-block partials [nblk][2*outc] over blocks, then BN-finalize:
// a = g*rsqrt(var+eps), b = bt - mean*a.  Optionally emit raw reduced S,Q.
// grid = outc/64, block = 1024 (16 row-segments x 64 cols).
__global__ __launch_bounds__(1024) void kredfin(const float* __restrict__ part, int nblk, int outc,
                                                const float* __restrict__ g, const float* __restrict__ bt,
                                                float* __restrict__ a, float* __restrict__ b,
                                                float* __restrict__ outSQ, float invn) {
  __shared__ float rs[16][64], rq[16][64];
  int t = threadIdx.x, c = t & 63, seg = t >> 6;
  int col = blockIdx.x * 64 + c;
  int pitch = 2 * outc;
  float s = 0.f, q = 0.f;
  for (int r = seg; r < nblk; r += 16) {
    s += part[(size_t)r * pitch + col];
    q += part[(size_t)r * pitch + outc + col];
  }
  rs[seg][c] = s; rq[seg][c] = q;
  __syncthreads();
  if (t < 64) {
    int cc = blockIdx.x * 64 + t;
    float S = 0.f, Q = 0.f;
#pragma unroll
    for (int i = 0; i < 16; i++) { S += rs[i][t]; Q += rq[i][t]; }
    float mean = S * invn;
    float var = Q * invn - mean * mean;
    float sc = g[cc] * rsqrtf(var + 1e-5f);
    a[cc] = sc;
    b[cc] = bt[cc] - mean * sc;
    if (outSQ) { outSQ[cc] = S; outSQ[outc + cc] = Q; }
  }
}

// reduce per-block per-graph partials [NTILES][128] -> S3B[32][64]
__global__ __launch_bounds__(64) void kredB(const float* __restrict__ part, float* __restrict__ S3B) {
  int b = blockIdx.x;   // graph 0..31
  int c = threadIdx.x;  // col 0..63
  float s = 0.f;
  int r0 = (b == 0) ? 0 : ((b - 1) * Gn) / 128;
  int r1 = ((b + 1) * Gn + 127) / 128;
  if (r1 > NTILES) r1 = NTILES;
  for (int r = r0; r < r1; r++) {
    int bLo = (r * 128) / Gn;
    if (bLo == b) s += part[(size_t)r * 128 + c];
    else if (bLo + 1 == b) s += part[(size_t)r * 128 + 64 + c];
  }
  S3B[b * 64 + c] = s;
}

// Mout[i*mpitch+j] = alpha * (A @ Bm)[i][j]; optional cvec = bias + beta * A @ (bv1+bv2)
__global__ __launch_bounds__(256) void ksmallmat(const float* __restrict__ A, const float* __restrict__ Bm,
                                                 float alpha, const float* __restrict__ bias,
                                                 const float* __restrict__ bv1, const float* __restrict__ bv2,
                                                 float beta, float* __restrict__ Mout, int mpitch,
                                                 float* __restrict__ cvec) {
  __shared__ float As[4096], Bs[4096];
  int t = threadIdx.x;
  for (int m = 0; m < 16; m++) { As[m * 256 + t] = A[m * 256 + t]; Bs[m * 256 + t] = Bm[m * 256 + t]; }
  __syncthreads();
  int j = t & 63, ig = t >> 6;
  for (int ii = 0; ii < 16; ii++) {
    int i = ig * 16 + ii;
    float acc = 0.f;
    for (int k = 0; k < 64; k++) acc += As[i * 64 + k] * Bs[k * 64 + j];
    Mout[i * mpitch + j] = alpha * acc;
  }
  if (cvec && t < 64) {
    float acc = bias ? bias[t] : 0.f;
    for (int k = 0; k < 64; k++) {
      float bb = (bv1 ? bv1[k] : 0.f) + (bv2 ? bv2[k] : 0.f);
      acc += beta * As[t * 64 + k] * bb;
    }
    cvec[t] = acc;
  }
}

// histogram with ticket: one atomic per edge (small graphs only)
__global__ __launch_bounds__(256) void khist(const int* __restrict__ dst, int* __restrict__ cnt,
                                             int* __restrict__ ticket, int E) {
  int e = blockIdx.x * 256 + threadIdx.x;
  if (e < E) ticket[e] = atomicAdd(&cnt[dst[e]], 1);
}

// ---- block scan (1024 elems/block) ----
__global__ __launch_bounds__(256) void kscan1(const int* __restrict__ cnt, int* __restrict__ bsum, int n) {
  __shared__ int sh[256];
  int b = blockIdx.x, t = threadIdx.x;
  int base = b * 1024 + t * 4;
  int s = 0;
#pragma unroll
  for (int j = 0; j < 4; j++) { int i = base + j; if (i < n) s += cnt[i]; }
  sh[t] = s; __syncthreads();
  for (int d = 128; d; d >>= 1) { if (t < d) sh[t] += sh[t + d]; __syncthreads(); }
  if (t == 0) bsum[b] = sh[0];
}
__global__ __launch_bounds__(256) void kscan2(int* bsum, int nb, int* off_n) {
  __shared__ int sh[256];
  int t = threadIdx.x;
  int v = (t < nb) ? bsum[t] : 0;
  sh[t] = v;
  __syncthreads();
  for (int d = 1; d < 256; d <<= 1) {
    int u = (t >= d) ? sh[t - d] : 0;
    __syncthreads();
    sh[t] += u;
    __syncthreads();
  }
  if (t < nb) bsum[t] = sh[t] - v;  // exclusive
  if (t == nb - 1 && off_n) *off_n = sh[t];
}
__global__ __launch_bounds__(256) void kscan3(int* __restrict__ cnt, const int* __restrict__ bsum, int n) {
  __shared__ int sh[256];
  int b = blockIdx.x, t = threadIdx.x;
  int base = b * 1024 + t * 4;
  int c0 = (base + 0 < n) ? cnt[base + 0] : 0;
  int c1 = (base + 1 < n) ? cnt[base + 1] : 0;
  int c2 = (base + 2 < n) ? cnt[base + 2] : 0;
  int c3 = (base + 3 < n) ? cnt[base + 3] : 0;
  int tot = c0 + c1 + c2 + c3;
  sh[t] = tot; __syncthreads();
  for (int d = 1; d < 256; d <<= 1) {
    int v = (t >= d) ? sh[t - d] : 0;
    __syncthreads();
    sh[t] += v;
    __syncthreads();
  }
  int excl = sh[t] - tot + bsum[b];
  if (base + 0 < n) cnt[base + 0] = excl;
  if (base + 1 < n) cnt[base + 1] = excl + c0;
  if (base + 2 < n) cnt[base + 2] = excl + c0 + c1;
  if (base + 3 < n) cnt[base + 3] = excl + c0 + c1 + c2;
}

// atomic-free CSR fill using tickets: pack[off[d]+ticket] = (w, src_full)
__global__ __launch_bounds__(256) void kfillt(const int* __restrict__ src, const int* __restrict__ dst,
                                              const float* __restrict__ w, const int* __restrict__ off,
                                              const int* __restrict__ ticket, float2* __restrict__ pack, int E) {
  int e = blockIdx.x * 256 + threadIdx.x;
  if (e >= E) return;
  int d = dst[e];
  int pos = off[d] + ticket[e];
  pack[pos] = make_float2(w[e], __int_as_float(src[e]));
}

// per-row: deg = 1 + sum(w) over CSR row; dinv = rsqrt(deg)
__global__ __launch_bounds__(256) void kdinvrow(const int* __restrict__ off, const float2* __restrict__ pack,
                                                float* __restrict__ dinv, int n) {
  int i = blockIdx.x * 256 + threadIdx.x;
  if (i >= n) return;
  int b0 = off[i], b1 = off[i + 1];
  float s = 1.f;
  for (int j = b0; j < b1; j++) s += pack[j].x;
  dinv[i] = rsqrtf(s);
}

// ===== co-CSR build v2: per-block LDS counting sort, fully streaming writes =====
__global__ __launch_bounds__(256) void kpsort(const int* __restrict__ src, const int* __restrict__ dst,
                                              const float* __restrict__ w, float2* __restrict__ stg,
                                              int* __restrict__ Cg, int* __restrict__ Lg) {
  __shared__ int cnt[NBK];
  __shared__ int loff[NBK];
  __shared__ int cur[NBK];
  __shared__ int ssc[256];
  __shared__ float2 sbuf[EPB2];
  int t = threadIdx.x;
  int e0 = blockIdx.x * EPB2;
  for (int i = t; i < NBK; i += 256) cnt[i] = 0;
  __syncthreads();
  for (int e = e0 + t; e < e0 + EPB2; e += 256) atomicAdd(&cnt[dst[e] >> 8], 1);
  __syncthreads();
  int i0 = t * 3;
  int c3[3];
  int s = 0;
#pragma unroll
  for (int j = 0; j < 3; j++) { int i = i0 + j; c3[j] = (i < NBK) ? cnt[i] : 0; s += c3[j]; }
  ssc[t] = s;
  __syncthreads();
  for (int d = 1; d < 256; d <<= 1) {
    int u = (t >= d) ? ssc[t - d] : 0;
    __syncthreads();
    ssc[t] += u;
    __syncthreads();
  }
  int base = ssc[t] - s;
#pragma unroll
  for (int j = 0; j < 3; j++) {
    int i = i0 + j;
    if (i < NBK) { loff[i] = base; cur[i] = base; }
    base += c3[j];
  }
  __syncthreads();
  for (int e = e0 + t; e < e0 + EPB2; e += 256) {
    int d = dst[e];
    int pos = atomicAdd(&cur[d >> 8], 1);
    sbuf[pos] = make_float2(w[e], __int_as_float(src[e] | ((d & 255) << 18)));
  }
  __syncthreads();
  for (int i = t; i < EPB2; i += 256) stg[(size_t)e0 + i] = sbuf[i];
  for (int i = t; i < NBK; i += 256) {
    Cg[blockIdx.x * NBK + i] = cnt[i];
    Lg[blockIdx.x * NBK + i] = loff[i];
  }
}

// column-sum C over blocks -> bucket totals T
__global__ __launch_bounds__(256) void ksumT(const int* __restrict__ Cg, int* __restrict__ T) {
  int bk = blockIdx.x * 256 + threadIdx.x;
  if (bk >= NBK) return;
  int s = 0;
  for (int blk = 0; blk < 256; blk++) s += Cg[blk * NBK + bk];
  T[bk] = s;
}

// single-block exclusive scan of NBK bucket totals -> bbase; total -> off[Nn]
__global__ __launch_bounds__(256) void kpscan(const int* __restrict__ bcnt, int* __restrict__ bbase,
                                              int* __restrict__ offN) {
  __shared__ int sh[256];
  int t = threadIdx.x;
  int i0 = t * 3;
  int c[3];
  int s = 0;
#pragma unroll
  for (int j = 0; j < 3; j++) { int i = i0 + j; c[j] = (i < NBK) ? bcnt[i] : 0; s += c[j]; }
  sh[t] = s;
  __syncthreads();
  for (int d = 1; d < 256; d <<= 1) {
    int u = (t >= d) ? sh[t - d] : 0;
    __syncthreads();
    sh[t] += u;
    __syncthreads();
  }
  int base = sh[t] - s;
#pragma unroll
  for (int j = 0; j < 3; j++) {
    int i = i0 + j;
    if (i < NBK) bbase[i] = base;
    base += c[j];
  }
  if (t == 255) { bbase[NBK] = base; *offN = base; }
}

// one block per bucket: gather 256 block-segments into LDS, row-hist/scan -> off, dinv;
// LDS-cursor scatter into pack (writes confined to the bucket's contiguous ~20KB range)
__global__ __launch_bounds__(256) void kpcsr2(const int* __restrict__ bbase, const int* __restrict__ Cg,
                                              const int* __restrict__ Lg, const float2* __restrict__ stg,
                                              int* __restrict__ off, float2* __restrict__ pack,
                                              float* __restrict__ dinv) {
  constexpr int CAP = 4096;  // mean 2560, sigma ~51 -> 30-sigma headroom
  __shared__ float2 ebuf[CAP];
  __shared__ int rh[256];
  __shared__ int sc2[256];
  __shared__ float ws[256];
  __shared__ int nEs;
  int bk = blockIdx.x, t = threadIdx.x;
  int myC = Cg[t * NBK + bk];
  int myL = Lg[t * NBK + bk];
  sc2[t] = myC;
  __syncthreads();
  for (int d = 1; d < 256; d <<= 1) {
    int u = (t >= d) ? sc2[t - d] : 0;
    __syncthreads();
    sc2[t] += u;
    __syncthreads();
  }
  int myO = sc2[t] - myC;
  if (t == 255) nEs = sc2[255];
  rh[t] = 0; ws[t] = 0.f;
  __syncthreads();
  int nE = nEs;
  {
    const float2* sp = &stg[(size_t)t * EPB2 + myL];
    for (int i = 0; i < myC; i++) ebuf[myO + i] = sp[i];
  }
  __syncthreads();
  for (int i = t; i < nE; i += 256) {
    float2 p = ebuf[i];
    int r = (__float_as_int(p.y) >> 18) & 255;
    atomicAdd(&rh[r], 1);
    atomicAdd(&ws[r], p.x);
  }
  __syncthreads();
  int cnt = rh[t];
  sc2[t] = cnt;
  __syncthreads();
  for (int d = 1; d < 256; d <<= 1) {
    int u = (t >= d) ? sc2[t - d] : 0;
    __syncthreads();
    sc2[t] += u;
    __syncthreads();
  }
  int gpos = bbase[bk] + sc2[t] - cnt;
  int grow = (bk << 8) + t;  // 625*256 == 160000: always valid
  off[grow] = gpos;
  dinv[grow] = rsqrtf(1.f + ws[t]);
  rh[t] = gpos;  // cursor
  __syncthreads();
  for (int i = t; i < nE; i += 256) {
    float2 p = ebuf[i];
    int r = (__float_as_int(p.y) >> 18) & 255;
    int pos = atomicAdd(&rh[r], 1);
    pack[pos] = p;
  }
}

// wave-per-row CSR gather, bf16 out with pitch+column offset; src masked to 18 bits
// (kept for the small go/bg graphs)
__global__ __launch_bounds__(256) void kgather(const int* __restrict__ off, const float2* __restrict__ pack,
                                               const float* __restrict__ dinv, const float* __restrict__ tab,
                                               u16* __restrict__ aggb, int pitch, int coff, int n) {
  int lane = threadIdx.x & 63;
  int wv = blockIdx.x * 4 + (threadIdx.x >> 6);
  int nw = gridDim.x * 4;
  for (int i = wv; i < n; i += nw) {
    int b0 = off[i], b1 = off[i + 1];
    float di = dinv[i];
    float acc = di * tab[(i % Gn) * 64 + lane];
    for (int base = b0; base < b1; base += 64) {
      int m = b1 - base; if (m > 64) m = 64;
      float cj = 0.f; int idxj = 0;
      if (lane < m) {
        float2 p = pack[base + lane];
        int s = __float_as_int(p.y) & 0x3FFFF;
        cj = p.x * dinv[s];
        idxj = (s % Gn) * 64;
      }
      int j = 0;
      for (; j + 1 < m; j += 2) {
        float c0 = __shfl(cj, j, 64);     int i0 = __shfl(idxj, j, 64);
        float c1 = __shfl(cj, j + 1, 64); int i1 = __shfl(idxj, j + 1, 64);
        float t0 = tab[i0 + lane];
        float t1 = tab[i1 + lane];
        acc = fmaf(c0, t0, acc);
        acc = fmaf(c1, t1, acc);
      }
      if (j < m) {
        float c0 = __shfl(cj, j, 64); int i0 = __shfl(idxj, j, 64);
        acc = fmaf(c0, tab[i0 + lane], acc);
      }
    }
    acc *= di;
    aggb[(size_t)i * pitch + coff + lane] = f2bf(acc);
  }
}

// ===== fused co-gather + t1: t1[i] = di*(di*PM[i%Gn] + sum coef*PM[s]) + Q[i%Gn] =====
// 4-edge-parallel: wave = 4 groups x 16 lanes; group q handles edge st*4+q each step,
// lane holds float4 of the 64-col row. Cross-group shfl_xor reduce at row end.
// bf16 out (pitch 64) + per-block partial stats partS[blk][128].
__global__ __launch_bounds__(256) void kgt1(const int* __restrict__ off, const float2* __restrict__ pack,
                                            const float* __restrict__ dinv, const float4* __restrict__ PM4,
                                            const float4* __restrict__ Q4, u16* __restrict__ Ybf,
                                            float* __restrict__ partS) {
  __shared__ float sred[4][64], sqred[4][64];
  int t = threadIdx.x;
  int lane = t & 63, wv = t >> 6;
  int q = lane >> 4, kq = lane & 15;
  int gw = blockIdx.x * 4 + wv, nw = gridDim.x * 4;
  float4 sS = make_float4(0.f, 0.f, 0.f, 0.f);
  float4 sQ = make_float4(0.f, 0.f, 0.f, 0.f);
  for (int i = gw; i < Nn; i += nw) {
    int g = i % Gn;
    int b0 = off[i], b1 = off[i + 1];
    float di = dinv[i];
    float4 acc = make_float4(0.f, 0.f, 0.f, 0.f);
    if (q == 0) {
      float4 pm = PM4[g * 16 + kq];
      acc.x = di * pm.x; acc.y = di * pm.y; acc.z = di * pm.z; acc.w = di * pm.w;
    }
    for (int base = b0; base < b1; base += 64) {
      int m = b1 - base; if (m > 64) m = 64;
      float cj = 0.f; int idx16 = 0;
      if (lane < m) {
        float2 p = pack[base + lane];
        int s = __float_as_int(p.y) & 0x3FFFF;
        cj = p.x * dinv[s];
        idx16 = (s % Gn) * 16;
      }
      int steps = (m + 3) >> 2;
      for (int st = 0; st < steps; st++) {
        int e = st * 4 + q;
        float c = __shfl(cj, e, 64);
        int ix = __shfl(idx16, e, 64);
        if (e < m) {
          float4 tv = PM4[ix + kq];
          acc.x = fmaf(c, tv.x, acc.x);
          acc.y = fmaf(c, tv.y, acc.y);
          acc.z = fmaf(c, tv.z, acc.z);
          acc.w = fmaf(c, tv.w, acc.w);
        }
      }
    }
    // cross-group reduce (xor 16, 32): all lanes end with the full edge sum
    acc.x += __shfl_xor(acc.x, 16, 64); acc.y += __shfl_xor(acc.y, 16, 64);
    acc.z += __shfl_xor(acc.z, 16, 64); acc.w += __shfl_xor(acc.w, 16, 64);
    acc.x += __shfl_xor(acc.x, 32, 64); acc.y += __shfl_xor(acc.y, 32, 64);
    acc.z += __shfl_xor(acc.z, 32, 64); acc.w += __shfl_xor(acc.w, 32, 64);
    float4 qv = Q4[g * 16 + kq];
    float4 v;
    v.x = fmaf(di, acc.x, qv.x); v.y = fmaf(di, acc.y, qv.y);
    v.z = fmaf(di, acc.z, qv.z); v.w = fmaf(di, acc.w, qv.w);
    if (q == 0) {
      sS.x += v.x; sS.y += v.y; sS.z += v.z; sS.w += v.w;
      sQ.x += v.x * v.x; sQ.y += v.y * v.y; sQ.z += v.z * v.z; sQ.w += v.w * v.w;
      uint2 o;
      o.x = (u32)f2bf(v.x) | ((u32)f2bf(v.y) << 16);
      o.y = (u32)f2bf(v.z) | ((u32)f2bf(v.w) << 16);
      *(uint2*)&Ybf[(size_t)i * 64 + kq * 4] = o;
    }
  }
  if (q == 0) {
    sred[wv][kq * 4 + 0] = sS.x; sred[wv][kq * 4 + 1] = sS.y;
    sred[wv][kq * 4 + 2] = sS.z; sred[wv][kq * 4 + 3] = sS.w;
    sqred[wv][kq * 4 + 0] = sQ.x; sqred[wv][kq * 4 + 1] = sQ.y;
    sqred[wv][kq * 4 + 2] = sQ.z; sqred[wv][kq * 4 + 3] = sQ.w;
  }
  __syncthreads();
  if (t < 64) {
    float s = sred[0][t] + sred[1][t] + sred[2][t] + sred[3][t];
    float qq = sqred[0][t] + sqred[1][t] + sqred[2][t] + sqred[3][t];
    partS[(size_t)blockIdx.x * 128 + t] = s;
    partS[(size_t)blockIdx.x * 128 + 64 + t] = qq;
  }
}

// ===================== MFMA GEMM (one 128-row tile per block) =====================
// out[r][oc] = (PRE? relu(pa*x+pb) : x) @ Wg^T + bias (+ perg[r%Gn])
// stats -> PER-BLOCK PARTIALS: stats[blk][2*OUTC] (streaming stores, no global RMW).
// statB -> partials statB[blk][128] (slot0 = graph R0/Gn, slot1 = next graph).
template <int K, int OUTC, bool PRE, bool EB, bool PERG, bool STATS, bool OUTF32, bool STATB>
__global__ __launch_bounds__(256, 3) void mfgemm(
    const u16* __restrict__ Xb, const float* __restrict__ Wg, const float* __restrict__ bias,
    const float* __restrict__ pa, const float* __restrict__ pb,
    const float* __restrict__ perg, u16* __restrict__ Ybf, float* __restrict__ stats,
    float* __restrict__ statB, int rows) {
  constexpr int NT  = OUTC / 16;   // 16-col output tiles per wave-row
  constexpr int KH  = K / 32;      // MFMA K-steps
  constexpr int SLK = K / 8;       // 16B slots per input row
  constexpr int SLO = OUTC / 8;    // 16B slots per output row
  constexpr int XROW = (K > OUTC ? K : OUTC) * 2;  // bytes per xs row (shared in/out stage)
  __shared__ __align__(16) unsigned char xsb[128 * XROW];
  __shared__ __align__(16) unsigned char wsb[OUTC * K * 2];
  __shared__ float sstat[STATS ? 2 * OUTC : 1];
  __shared__ float sstatB[STATB ? 128 : 1];
  int t = threadIdx.x;
  int l = t & 63, w = t >> 6, lrow = l & 15, lk = l >> 4;
  int R0 = blockIdx.x * 128;

  // ---- stage weights: fp32 -> bf16, swizzled ----
  for (int idx = t; idx < OUTC * SLK; idx += 256) {
    int oc = idx / SLK, s8 = idx % SLK;
    const float* wp = &Wg[oc * K + s8 * 8];
    uint4 o;
    o.x = (u32)f2bf(wp[0]) | ((u32)f2bf(wp[1]) << 16);
    o.y = (u32)f2bf(wp[2]) | ((u32)f2bf(wp[3]) << 16);
    o.z = (u32)f2bf(wp[4]) | ((u32)f2bf(wp[5]) << 16);
    o.w = (u32)f2bf(wp[6]) | ((u32)f2bf(wp[7]) << 16);
    *(uint4*)&wsb[oc * (2 * K) + ((s8 * 16) ^ ((oc & 7) << 4))] = o;
  }
  if constexpr (STATS) for (int idx = t; idx < 2 * OUTC; idx += 256) sstat[idx] = 0.f;
  if constexpr (STATB) for (int idx = t; idx < 128; idx += 256) sstatB[idx] = 0.f;

  // ---- stage input tile: coalesced 16B loads ----
#pragma unroll
  for (int m = 0; m < SLK / 2; m++) {
    int f = m * 256 + t;
    int r = f / SLK, s8 = f % SLK;
    uint4 u = *(const uint4*)&Xb[(size_t)(R0 + r) * K + s8 * 8];
    if constexpr (PRE) {
      int c0 = s8 * 8;
      float4 A0 = *(const float4*)&pa[c0];
      float4 A1 = *(const float4*)&pa[c0 + 4];
      const float* pbb = EB ? &pb[((R0 + r) / Gn) * 64] : pb;
      float4 B0 = *(const float4*)&pbb[c0];
      float4 B1 = *(const float4*)&pbb[c0 + 4];
      float v0 = fmaxf(fmaf(A0.x, bflo(u.x), B0.x), 0.f);
      float v1 = fmaxf(fmaf(A0.y, bfhi(u.x), B0.y), 0.f);
      float v2 = fmaxf(fmaf(A0.z, bflo(u.y), B0.z), 0.f);
      float v3 = fmaxf(fmaf(A0.w, bfhi(u.y), B0.w), 0.f);
      float v4 = fmaxf(fmaf(A1.x, bflo(u.z), B1.x), 0.f);
      float v5 = fmaxf(fmaf(A1.y, bfhi(u.z), B1.y), 0.f);
      float v6 = fmaxf(fmaf(A1.z, bflo(u.w), B1.z), 0.f);
      float v7 = fmaxf(fmaf(A1.w, bfhi(u.w), B1.w), 0.f);
      u.x = (u32)f2bf(v0) | ((u32)f2bf(v1) << 16);
      u.y = (u32)f2bf(v2) | ((u32)f2bf(v3) << 16);
      u.z = (u32)f2bf(v4) | ((u32)f2bf(v5) << 16);
      u.w = (u32)f2bf(v6) | ((u32)f2bf(v7) << 16);
    }
    *(uint4*)&xsb[r * XROW + ((s8 * 16) ^ ((r & 7) << 4))] = u;
  }
  float bcol[NT];
#pragma unroll
  for (int nt = 0; nt < NT; nt++) bcol[nt] = bias[nt * 16 + lrow];
  __syncthreads();

  // ---- MFMA: wave w owns rows w*32..w*32+31, all OUTC cols ----
  short8v af[2][KH];
#pragma unroll
  for (int rt = 0; rt < 2; rt++)
#pragma unroll
    for (int h = 0; h < KH; h++) {
      int row = w * 32 + rt * 16 + lrow;
      af[rt][h] = *(const short8v*)&xsb[row * XROW + ((h * 64 + lk * 16) ^ ((row & 7) << 4))];
    }
  f32x4 acc[2][NT];
#pragma unroll
  for (int rt = 0; rt < 2; rt++)
#pragma unroll
    for (int nt = 0; nt < NT; nt++) {
      f32x4 z = {0.f, 0.f, 0.f, 0.f};
      acc[rt][nt] = z;
    }
#pragma unroll
  for (int nt = 0; nt < NT; nt++) {
    int brow = nt * 16 + lrow;
#pragma unroll
    for (int h = 0; h < KH; h++) {
      short8v bfr = *(const short8v*)&wsb[brow * (2 * K) + ((h * 64 + lk * 16) ^ ((brow & 7) << 4))];
      acc[0][nt] = __builtin_amdgcn_mfma_f32_16x16x32_bf16(af[0][h], bfr, acc[0][nt], 0, 0, 0);
      acc[1][nt] = __builtin_amdgcn_mfma_f32_16x16x32_bf16(af[1][h], bfr, acc[1][nt], 0, 0, 0);
    }
  }
  __syncthreads();  // all xs reads done -> safe to reuse xs as output stage

  // ---- epilogue: bias (+perg), stats (col is lane-invariant), output ----
  float sS[NT], sQ[NT], sB0[NT], sB1[NT];
#pragma unroll
  for (int nt = 0; nt < NT; nt++) { sS[nt] = 0.f; sQ[nt] = 0.f; sB0[nt] = 0.f; sB1[nt] = 0.f; }
  int hiStart = STATB ? (R0 / Gn + 1) * Gn : 0x7fffffff;
  float* Yf = (float*)Ybf;
#pragma unroll
  for (int rt = 0; rt < 2; rt++) {
#pragma unroll
    for (int r = 0; r < 4; r++) {
      int orow = w * 32 + rt * 16 + lk * 4 + r;
      int grow = R0 + orow;
      bool valid = grow < rows;
      int qoff = 0;
      if constexpr (PERG) qoff = (grow % Gn) * 64;
#pragma unroll
      for (int nt = 0; nt < NT; nt++) {
        float v = acc[rt][nt][r] + bcol[nt];
        if constexpr (PERG) v += perg[qoff + nt * 16 + lrow];
        if (valid) {
          if constexpr (STATS) { sS[nt] += v; sQ[nt] += v * v; }
          if constexpr (STATB) { if (grow >= hiStart) sB1[nt] += v; else sB0[nt] += v; }
        }
        if constexpr (OUTF32) {
          if (valid) Yf[(size_t)grow * OUTC + nt * 16 + lrow] = v;
        } else {
          *(u16*)&xsb[orow * (2 * OUTC) + ((2 * (nt * 16 + lrow)) ^ ((orow & 7) << 4))] = f2bf(v);
        }
      }
    }
  }
  if constexpr (STATS) {
#pragma unroll
    for (int nt = 0; nt < NT; nt++) {
      atomicAdd(&sstat[nt * 16 + lrow], sS[nt]);
      atomicAdd(&sstat[OUTC + nt * 16 + lrow], sQ[nt]);
    }
  }
  if constexpr (STATB) {
#pragma unroll
    for (int nt = 0; nt < NT; nt++) {
      atomicAdd(&sstatB[nt * 16 + lrow], sB0[nt]);
      atomicAdd(&sstatB[64 + nt * 16 + lrow], sB1[nt]);
    }
  }
  __syncthreads();

  if constexpr (!OUTF32) {
    // coalesced store: contiguous 1KB per wave-instruction
#pragma unroll
    for (int m = 0; m < SLO / 2; m++) {
      int f = m * 256 + t;
      int r = f / SLO, c8 = f % SLO;
      uint4 o = *(const uint4*)&xsb[r * (2 * OUTC) + ((16 * c8) ^ ((r & 7) << 4))];
      *(uint4*)&Ybf[(size_t)(R0 + r) * OUTC + c8 * 8] = o;
    }
  }
  if constexpr (STATS)
    for (int idx = t; idx < 2 * OUTC; idx += 256) stats[(size_t)blockIdx.x * 2 * OUTC + idx] = sstat[idx];
  if constexpr (STATB)
    for (int idx = t; idx < 128; idx += 256) statB[(size_t)blockIdx.x * 128 + idx] = sstatB[idx];
}

// finalize S3 analytically from reduced S2 (Σt2, Σt2²) + per-graph sums S3B, then build
// Avec = a3*a2, e2[b] = a3*(b2+emb[b]) + b3.  (S3B may alias e2: read before write.)
__global__ __launch_bounds__(256) void kfinS3e2(const float* __restrict__ S2, const float* __restrict__ g,
                                                const float* __restrict__ bt, const float* __restrict__ a2,
                                                const float* __restrict__ b2, const float* __restrict__ emb,
                                                const float* __restrict__ S3B,
                                                float* __restrict__ Avec, float* __restrict__ e2) {
  __shared__ float a3s[64], b3s[64];
  int t = threadIdx.x;
  if (t < 64) {
    float a2c = a2[t], b2c = b2[t];
    float su = 0.f, sxc = 0.f, sc2 = 0.f;
    for (int b = 0; b < Bn; b++) {
      float cb = b2c + emb[b * 64 + t];
      float sb = S3B[b * 64 + t];
      su += cb;
      sxc += cb * sb;
      sc2 += cb * cb;
    }
    float Su = a2c * S2[t] + (float)Gn * su;
    float Sq = a2c * a2c * S2[64 + t] + 2.f * a2c * sxc + (float)Gn * sc2;
    float mean = Su * (1.f / Nn);
    float var = Sq * (1.f / Nn) - mean * mean;
    float sc = g[t] * rsqrtf(var + 1e-5f);
    float sh = bt[t] - mean * sc;
    a3s[t] = sc; b3s[t] = sh;
    Avec[t] = sc * a2c;
  }
  __syncthreads();
  for (int idx = t; idx < 2048; idx += 256) {
    int c = idx & 63;
    e2[idx] = a3s[c] * (b2[c] + emb[idx]) + b3s[c];
  }
}

// w1[i] = dot(a5*R2(bf16)+b5, indv_w1[i%G]) + indv_b1[i%G]
__global__ __launch_bounds__(256) void k13_kernel(const u16* __restrict__ R2, const float* __restrict__ a5,
                                                  const float* __restrict__ b5, const float* __restrict__ iw1,
                                                  const float* __restrict__ ib1, float* __restrict__ w1out,
                                                  int rows) {
  int t = blockIdx.x * 256 + threadIdx.x;
  int i = t >> 4, j = t & 15;
  if (i >= rows) return;
  int g = i % Gn;
  uint2 u = *(const uint2*)&R2[(size_t)i * 64 + j * 4];
  float rx = bflo(u.x), ry = bfhi(u.x), rz = bflo(u.y), rw = bfhi(u.y);
  float4 a = ((const float4*)a5)[j];
  float4 b = ((const float4*)b5)[j];
  float4 w = ((const float4*)iw1)[g * 16 + j];
  float p = (a.x * rx + b.x) * w.x + (a.y * ry + b.y) * w.y +
            (a.z * rz + b.z) * w.z + (a.w * rw + b.w) * w.w;
  for (int off = 8; off; off >>= 1) p += __shfl_xor(p, off, 64);
  if (j == 0) w1out[i] = p + ib1[g];
}

// init cgraw with bias
__global__ __launch_bounds__(256) void kinitcg(const float* __restrict__ cgb1, float* __restrict__ cgraw) {
  int idx = blockIdx.x * 256 + threadIdx.x;
  if (idx < Bn * 64) cgraw[idx] = cgb1[idx & 63];
}

// split-K GEMM: cgraw[b][col] += sum_{k in chunk} w1[b][k]*cgW1[col][k]
__global__ __launch_bounds__(256) void kcg1s(const float* __restrict__ w1, const float* __restrict__ cgW1,
                                             float* __restrict__ cgraw) {
  __shared__ float w1s[64 * 36];
  __shared__ float cgs[64 * 65];
  int t = threadIdx.x;
  int k0 = blockIdx.x * 64;
  int kmax = Gn - k0; if (kmax > 64) kmax = 64;
  for (int idx = t; idx < 2048; idx += 256) {
    int row = idx >> 6, k = idx & 63;
    w1s[k * 36 + row] = (k < kmax) ? w1[row * Gn + k0 + k] : 0.f;
  }
  for (int idx = t; idx < 4096; idx += 256) {
    int col = idx >> 6, k = idx & 63;
    cgs[k * 65 + col] = (k < kmax) ? cgW1[col * Gn + k0 + k] : 0.f;
  }
  __syncthreads();
  int col = t & 63, rg = t >> 6;
  float acc[8];
#pragma unroll
  for (int i = 0; i < 8; i++) acc[i] = 0.f;
  for (int k = 0; k < 64; k++) {
    float wk = cgs[k * 65 + col];
    const float* wr = &w1s[k * 36 + rg * 8];
    float4 r0 = *(const float4*)wr;
    float4 r1 = *(const float4*)(wr + 4);
    acc[0] = fmaf(r0.x, wk, acc[0]);
    acc[1] = fmaf(r0.y, wk, acc[1]);
    acc[2] = fmaf(r0.z, wk, acc[2]);
    acc[3] = fmaf(r0.w, wk, acc[3]);
    acc[4] = fmaf(r1.x, wk, acc[4]);
    acc[5] = fmaf(r1.y, wk, acc[5]);
    acc[6] = fmaf(r1.z, wk, acc[6]);
    acc[7] = fmaf(r1.w, wk, acc[7]);
  }
#pragma unroll
  for (int i = 0; i < 8; i++) atomicAdd(&cgraw[(rg * 8 + i) * 64 + col], acc[i]);
}

// single-block: cg2 = bn2(relu(bn1(cgraw)) @ W2^T + b2)   (BN over 32 rows)
__global__ __launch_bounds__(256) void kcg2(const float* __restrict__ cgraw, const float* __restrict__ g1,
                                            const float* __restrict__ bt1, const float* __restrict__ W2,
                                            const float* __restrict__ b2, const float* __restrict__ g2,
                                            const float* __restrict__ bt2, float* __restrict__ cg2out) {
  int t = threadIdx.x, c = t & 63, bg = t >> 6;
  __shared__ float hmid[2048], sred[4][64], qred[4][64], asc[64], bsh[64];
  float y[8];
  float ps = 0.f, pq = 0.f;
  for (int jb = 0; jb < 8; jb++) {
    int b = bg * 8 + jb;
    float v = cgraw[b * 64 + c];
    y[jb] = v; ps += v; pq += v * v;
  }
  sred[bg][c] = ps; qred[bg][c] = pq;
  __syncthreads();
  if (t < 64) {
    float s = sred[0][t] + sred[1][t] + sred[2][t] + sred[3][t];
    float q = qred[0][t] + qred[1][t] + qred[2][t] + qred[3][t];
    float mean = s * (1.f / 32.f), var = q * (1.f / 32.f) - mean * mean;
    float sc = g1[t] * rsqrtf(var + 1e-5f);
    asc[t] = sc; bsh[t] = bt1[t] - mean * sc;
  }
  __syncthreads();
  for (int jb = 0; jb < 8; jb++) { int b = bg * 8 + jb; hmid[b * 64 + c] = fmaxf(asc[c] * y[jb] + bsh[c], 0.f); }
  __syncthreads();
  ps = 0.f; pq = 0.f;
  for (int jb = 0; jb < 8; jb++) {
    int b = bg * 8 + jb;
    float a = b2[c];
    for (int k = 0; k < 64; k++) a += hmid[b * 64 + k] * W2[c * 64 + k];
    y[jb] = a; ps += a; pq += a * a;
  }
  sred[bg][c] = ps; qred[bg][c] = pq;
  __syncthreads();
  if (t < 64) {
    float s = sred[0][t] + sred[1][t] + sred[2][t] + sred[3][t];
    float q = qred[0][t] + qred[1][t] + qred[2][t] + qred[3][t];
    float mean = s * (1.f / 32.f), var = q * (1.f / 32.f) - mean * mean;
    float sc = g2[t] * rsqrtf(var + 1e-5f);
    asc[t] = sc; bsh[t] = bt2[t] - mean * sc;
  }
  __syncthreads();
  for (int jb = 0; jb < 8; jb++) { int b = bg * 8 + jb; cg2out[b * 64 + c] = asc[c] * y[jb] + bsh[c]; }
}

// single-block: emb = mlp3(pglob[pert_idx]) with BN over 32 rows (m2 is bf16)
__global__ __launch_bounds__(256) void kemb(const u16* __restrict__ m2, const float* __restrict__ aP2,
                                            const float* __restrict__ bP2, const int* __restrict__ pidx,
                                            const float* __restrict__ Wm, const float* __restrict__ bv,
                                            const float* __restrict__ gg, const float* __restrict__ btv,
                                            float* __restrict__ emb) {
  int t = threadIdx.x, c = t & 63, bg = t >> 6;
  __shared__ float xin[2048], hmid[2048], sred[4][64], qred[4][64], asc[64], bsh[64];
  for (int idx = t; idx < 2048; idx += 256) {
    int b = idx >> 6, cc = idx & 63;
    xin[idx] = aP2[cc] * bf2f(m2[(size_t)pidx[b] * 64 + cc]) + bP2[cc];
  }
  __syncthreads();
  float y[8];
  float ps = 0.f, pq = 0.f;
  for (int jb = 0; jb < 8; jb++) {
    int b = bg * 8 + jb;
    float a = bv[c];
    for (int k = 0; k < 64; k++) a += xin[b * 64 + k] * Wm[c * 64 + k];
    y[jb] = a; ps += a; pq += a * a;
  }
  sred[bg][c] = ps; qred[bg][c] = pq;
  __syncthreads();
  if (t < 64) {
    float s = sred[0][t] + sred[1][t] + sred[2][t] + sred[3][t];
    float q = qred[0][t] + qred[1][t] + qred[2][t] + qred[3][t];
    float mean = s * (1.f / 32.f), var = q * (1.f / 32.f) - mean * mean;
    float sc = gg[t] * rsqrtf(var + 1e-5f);
    asc[t] = sc; bsh[t] = btv[t] - mean * sc;
  }
  __syncthreads();
  for (int jb = 0; jb < 8; jb++) { int b = bg * 8 + jb; hmid[b * 64 + c] = fmaxf(asc[c] * y[jb] + bsh[c], 0.f); }
  __syncthreads();
  ps = 0.f; pq = 0.f;
  for (int jb = 0; jb < 8; jb++) {
    int b = bg * 8 + jb;
    float a = bv[64 + c];
    for (int k = 0; k < 64; k++) a += hmid[b * 64 + k] * Wm[4096 + c * 64 + k];
    y[jb] = a; ps += a; pq += a * a;
  }
  sred[bg][c] = ps; qred[bg][c] = pq;
  __syncthreads();
  if (t < 64) {
    float s = sred[0][t] + sred[1][t] + sred[2][t] + sred[3][t];
    float q = qred[0][t] + qred[1][t] + qred[2][t] + qred[3][t];
    float mean = s * (1.f / 32.f), var = q * (1.f / 32.f) - mean * mean;
    float sc = gg[64 + t] * rsqrtf(var + 1e-5f);
    asc[t] = sc; bsh[t] = btv[64 + t] - mean * sc;
  }
  __syncthreads();
  for (int jb = 0; jb < 8; jb++) { int b = bg * 8 + jb; emb[b * 64 + c] = asc[c] * y[jb] + bsh[c]; }
}

// final: out[b][g] = w1*iw2[g][0] + dot(cg2[b], iw2[g][1:65]) + ib2[g] + x[b][g]
__global__ __launch_bounds__(256) void kfinal(const float* __restrict__ w1, const float* __restrict__ cg2,
                                              const float* __restrict__ iw2, const float* __restrict__ ib2,
                                              const float* __restrict__ x, float* __restrict__ out) {
  __shared__ float iws[64 * 65], cgs[2048];
  int t = threadIdx.x;
  int g0 = blockIdx.x * 64;
  for (int idx = t; idx < 64 * 65; idx += 256) {
    int gi = g0 * 65 + idx;
    iws[idx] = (gi < Gn * 65) ? iw2[gi] : 0.f;
  }
  for (int idx = t; idx < 2048; idx += 256) cgs[idx] = cg2[idx];
  __syncthreads();
  int gl = t & 63, bg = t >> 6;
  int g = g0 + gl;
  if (g >= Gn) return;
  float bias = ib2[g];
  for (int jb = 0; jb < 8; jb++) {
    int b = bg * 8 + jb;
    float acc = w1[b * Gn + g] * iws[gl * 65] + bias;
    for (int k = 0; k < 64; k++) acc += cgs[b * 64 + k] * iws[gl * 65 + 1 + k];
    out[b * Gn + g] = acc + x[b * Gn + g];
  }
}

extern "C" void kernel_launch(void* const* d_in, const int* in_sizes, int n_in,
                              void* d_out, int out_size, void* d_ws, size_t ws_size,
                              hipStream_t stream) {
  (void)in_sizes; (void)n_in; (void)out_size;
  if (ws_size < WS_FLOATS * sizeof(float)) return;

  const float* x        = (const float*)d_in[0];
  const int*   pert_idx = (const int*)d_in[1];
  const int*   ei_co    = (const int*)d_in[2];
  const float* w_co     = (const float*)d_in[3];
  const int*   ei_go    = (const int*)d_in[4];
  const float* w_go     = (const float*)d_in[5];
  const int*   ei_bg    = (const int*)d_in[6];
  const float* w_bg     = (const float*)d_in[7];
  const float* gene_tab = (const float*)d_in[8];
  const float* pos_tab  = (const float*)d_in[9];
  const float* go_tab   = (const float*)d_in[10];
  const float* bg_tab   = (const float*)d_in[11];
  const float* bn_g     = (const float*)d_in[12];
  const float* bn_b     = (const float*)d_in[13];
  const float* sg_W     = (const float*)d_in[14];
  const float* sg_b     = (const float*)d_in[15];
  const float* mlp_W    = (const float*)d_in[16];
  const float* mlp_b    = (const float*)d_in[17];
  const float* mlp_g    = (const float*)d_in[18];
  const float* mlp_bt   = (const float*)d_in[19];
  const float* rec_W1   = (const float*)d_in[20];
  const float* rec_b1   = (const float*)d_in[21];
  const float* rec_g1   = (const float*)d_in[22];
  const float* rec_bt1  = (const float*)d_in[23];
  const float* rec_W2   = (const float*)d_in[24];
  const float* rec_b2   = (const float*)d_in[25];
  const float* rec_g2   = (const float*)d_in[26];
  const float* rec_bt2  = (const float*)d_in[27];
  const float* indv_w1  = (const float*)d_in[28];
  const float* indv_b1  = (const float*)d_in[29];
  const float* cg_W1    = (const float*)d_in[30];
  const float* cg_b1    = (const float*)d_in[31];
  const float* cg_g1    = (const float*)d_in[32];
  const float* cg_bt1   = (const float*)d_in[33];
  const float* cg_W2    = (const float*)d_in[34];
  const float* cg_b2    = (const float*)d_in[35];
  const float* cg_g2    = (const float*)d_in[36];
  const float* cg_bt2   = (const float*)d_in[37];
  const float* indv_w2  = (const float*)d_in[38];
  const float* indv_b2  = (const float*)d_in[39];

  float* W = (float*)d_ws;
  float* buf0 = W + oBUF0;
  float* buf1 = W + oBUF1;

  // CSR scratch lives in buf1 lower region (consumed by kgt1 before t2 writes buf1)
  int*    co_off    = (int*)(buf1);                  // 160001
  int*    bbase     = (int*)(buf1 + 200000);         // 626
  int*    Tbk       = (int*)(buf1 + 202000);         // 625 bucket totals
  int*    sbsum     = (int*)(buf1 + 320128);         // <=256 block sums (go/bg scans)
  float2* co_pack   = (float2*)(buf1 + 400000);      // 1.6M float2
  int*    go_cnt    = (int*)(buf1 + 3700000);
  float2* go_pack   = (float2*)(buf1 + 3720000);
  int*    bg_cnt    = (int*)(buf1 + 4000000);
  float2* bg_pack   = (float2*)(buf1 + 4020000);
  u16*    RPB       = (u16*)(buf1 + 4220000);        // [5120][64] bf16 renormed pos tab
  int*    Cg        = (int*)(buf1 + 4500000);        // [256][625] per-block bucket counts
  int*    Lg        = (int*)(buf1 + 4700000);        // [256][625] per-block local offsets
  int*    go_ticket = (int*)(buf1 + 6200000);
  int*    bg_ticket = (int*)(buf1 + 6400000);
  u16*    pgi       = (u16*)(buf1 + 6600000);        // [5120][128] bf16: go cols 0-63, bg 64-127
  u16*    RGB       = (u16*)(buf1 + 6800000);        // [5120][64] bf16 renormed gene tab
  float2* co_stg    = (float2*)(buf1 + 6963840);     // 1.6M float2 block-major sorted staging

  // stats partial buffers: buf1 upper region (dead co_stg space; transient between
  // each producer and its immediate kredfin/kredB — r1 fills ALL of buf0 so buf0 can't host them)
  float* partS = buf1 + 8000000;   // up to [2048][128]
  float* partB = buf1 + 8650000;   // [1250][128]

  // --- phase 0: zero pads, renorm tables, fold small matrices ---
  kzero<<<8, 256, 0, stream>>>(W, 2048);                             // includes oZERO bias
  kzero<<<15, 256, 0, stream>>>(buf1 + 6800000 + 160000, 3840);      // RGB pad rows 5000..5119
  kzero<<<15, 256, 0, stream>>>(buf1 + 4220000 + 160000, 3840);      // RPB pad rows 5000..5119
  kzero<<<30, 256, 0, stream>>>(buf1 + 6600000 + 320000, 7680);      // pgi pad rows 5000..5119
  krenorm<<<160, 256, 0, stream>>>(gene_tab, W + oRG, partS, RGB, Gn);
  kredfin<<<1, 1024, 0, stream>>>(partS, 160, 64, bn_g, bn_b, W + oAG, W + oBG, nullptr, 1.f / Gn);
  krenorm<<<160, 256, 0, stream>>>(pos_tab, W + oRP, nullptr, RPB, Gn);
  krenorm<<<160, 256, 0, stream>>>(go_tab, W + oRGO, nullptr, nullptr, Pn);
  krenorm<<<160, 256, 0, stream>>>(bg_tab, W + oRBG, nullptr, nullptr, Pn);
  ksmallmat<<<1, 256, 0, stream>>>(mlp_W + 8192, sg_W, 0.2f, mlp_b + 128, sg_b, nullptr, 0.2f,
                                   W + oM, 64, W + oCvec);
  ksmallmat<<<1, 256, 0, stream>>>(mlp_W, sg_W + 4096, 1.f, nullptr, nullptr, nullptr, 0.f,
                                   W + oM1, 128, nullptr);
  ksmallmat<<<1, 256, 0, stream>>>(mlp_W, sg_W + 8192, 1.f, mlp_b, sg_b + 64, sg_b + 128, 1.f,
                                   W + oM1 + 64, 128, W + oCcP);
  // Q = relu(AG*RG+BG) @ Mw^T + Cvec  (fp32, perg for the fused t1 gather)
  mfgemm<64, 64, true, false, false, false, true, false><<<PTILES, 256, 0, stream>>>(
      RGB, mlp_W + 8192, W + oCvec, W + oAG, W + oBG, nullptr, (u16*)(W + oQ), nullptr, nullptr, Gn);
  // PM = RP @ M^T  (fp32, the gather table for fused t1)
  mfgemm<64, 64, false, false, false, false, true, false><<<PTILES, 256, 0, stream>>>(
      RPB, W + oM, W + oZERO, nullptr, nullptr, nullptr, (u16*)(W + oPM), nullptr, nullptr, Gn);

  // --- go graph ---
  kzero<<<(5001 + 255) / 256, 256, 0, stream>>>((float*)go_cnt, 5001);
  khist<<<(EGG + 255) / 256, 256, 0, stream>>>(ei_go + EGG, go_cnt, go_ticket, EGG);
  kscan1<<<5, 256, 0, stream>>>(go_cnt, sbsum, Pn);
  kscan2<<<1, 256, 0, stream>>>(sbsum, 5, go_cnt + Pn);
  kscan3<<<5, 256, 0, stream>>>(go_cnt, sbsum, Pn);
  kfillt<<<(EGG + 255) / 256, 256, 0, stream>>>(ei_go, ei_go + EGG, w_go, go_cnt, go_ticket, go_pack, EGG);
  kdinvrow<<<(Pn + 255) / 256, 256, 0, stream>>>(go_cnt, go_pack, W + oDGO, Pn);
  kgather<<<512, 256, 0, stream>>>(go_cnt, go_pack, W + oDGO, W + oRGO, pgi, 128, 0, Pn);

  // --- bg graph ---
  kzero<<<(5001 + 255) / 256, 256, 0, stream>>>((float*)bg_cnt, 5001);
  khist<<<(EGG + 255) / 256, 256, 0, stream>>>(ei_bg + EGG, bg_cnt, bg_ticket, EGG);
  kscan1<<<5, 256, 0, stream>>>(bg_cnt, sbsum, Pn);
  kscan2<<<1, 256, 0, stream>>>(sbsum, 5, bg_cnt + Pn);
  kscan3<<<5, 256, 0, stream>>>(bg_cnt, sbsum, Pn);
  kfillt<<<(EGG + 255) / 256, 256, 0, stream>>>(ei_bg, ei_bg + EGG, w_bg, bg_cnt, bg_ticket, bg_pack, EGG);
  kdinvrow<<<(Pn + 255) / 256, 256, 0, stream>>>(bg_cnt, bg_pack, W + oDBG, Pn);
  kgather<<<512, 256, 0, stream>>>(bg_cnt, bg_pack, W + oDBG, W + oRBG, pgi, 128, 64, Pn);

  // --- pert path (MFMA, bf16) ---
  mfgemm<128, 64, false, false, false, true, false, false><<<PTILES, 256, 0, stream>>>(
      pgi, W + oM1, W + oCcP, nullptr, nullptr, nullptr, (u16*)(W + oM1B), partS, nullptr, Pn);
  kredfin<<<1, 1024, 0, stream>>>(partS, PTILES, 64, mlp_g, mlp_bt, W + oAP1, W + oBP1, nullptr, 1.f / Pn);
  mfgemm<64, 64, true, false, false, true, false, false><<<PTILES, 256, 0, stream>>>(
      (u16*)(W + oM1B), mlp_W + 4096, mlp_b + 64, W + oAP1, W + oBP1, nullptr,
      (u16*)(W + oM2B), partS, nullptr, Pn);
  kredfin<<<1, 1024, 0, stream>>>(partS, PTILES, 64, mlp_g + 64, mlp_bt + 64, W + oAP2, W + oBP2, nullptr, 1.f / Pn);
  kemb<<<1, 256, 0, stream>>>((u16*)(W + oM2B), W + oAP2, W + oBP2, pert_idx,
                              mlp_W + 16384, mlp_b + 256, mlp_g + 256, mlp_bt + 256, W + oEMB);

  // --- co graph: LDS counting-sort CSR build ---
  kpsort<<<256, 256, 0, stream>>>(ei_co, ei_co + ECO, w_co, co_stg, Cg, Lg);
  ksumT<<<3, 256, 0, stream>>>(Cg, Tbk);
  kpscan<<<1, 256, 0, stream>>>(Tbk, bbase, co_off + Nn);
  kpcsr2<<<NBK, 256, 0, stream>>>(bbase, Cg, Lg, co_stg, co_off, co_pack, W + oDEG);

  // --- fused gather+t1: t1 -> buf0 (bf16), partial stats ---
  kgt1<<<2048, 256, 0, stream>>>(co_off, co_pack, W + oDEG, (const float4*)(W + oPM),
                                 (const float4*)(W + oQ), (u16*)buf0, partS);
  kredfin<<<1, 1024, 0, stream>>>(partS, 2048, 64, mlp_g + 128, mlp_bt + 128, W + oA1, W + oB1, nullptr, 1.f / Nn);

  // --- main N pipeline: t1(buf0) -> t2(buf1) -> r1(buf0) -> r2(buf1) ---
  // t2 = relu(a1*t1+b1)@W11^T + b11; stats + per-graph sums
  mfgemm<64, 64, true, false, false, true, false, true><<<NTILES, 256, 0, stream>>>(
      (const u16*)buf0, mlp_W + 12288, mlp_b + 192, W + oA1, W + oB1, nullptr,
      (u16*)buf1, partS, partB, Nn);
  kredfin<<<1, 1024, 0, stream>>>(partS, NTILES, 64, mlp_g + 192, mlp_bt + 192, W + oA2, W + oB2, W + oS2, 1.f / Nn);
  kredB<<<32, 64, 0, stream>>>(partB, W + oE2);
  // S3 analytic + fold: Avec = a3*a2, e2 = a3*(b2+emb)+b3
  kfinS3e2<<<1, 256, 0, stream>>>(W + oS2, bn_g + 64, bn_b + 64, W + oA2, W + oB2, W + oEMB,
                                  W + oE2, W + oAvec, W + oE2);
  // r1 = relu(Avec*t2 + e2[b]) @ W1^T + b1 (128 cols)
  mfgemm<64, 128, true, true, false, true, false, false><<<NTILES, 256, 0, stream>>>(
      (const u16*)buf1, rec_W1, rec_b1, W + oAvec, W + oE2, nullptr, (u16*)buf0, partS, nullptr, Nn);
  kredfin<<<2, 1024, 0, stream>>>(partS, NTILES, 128, rec_g1, rec_bt1, W + oA4, W + oB4, nullptr, 1.f / Nn);
  // r2 = relu(a4*r1+b4)@W2^T + b2
  mfgemm<128, 64, true, false, false, true, false, false><<<NTILES, 256, 0, stream>>>(
      (const u16*)buf0, rec_W2, rec_b2, W + oA4, W + oB4, nullptr, (u16*)buf1, partS, nullptr, Nn);
  kredfin<<<1, 1024, 0, stream>>>(partS, NTILES, 64, rec_g2, rec_bt2, W + oA5, W + oB5, nullptr, 1.f / Nn);
  k13_kernel<<<(Nn * 16 + 255) / 256, 256, 0, stream>>>((const u16*)buf1, W + oA5, W + oB5, indv_w1, indv_b1,
                                                        W + oW1, Nn);
  // cross-gene state
  kinitcg<<<8, 256, 0, stream>>>(cg_b1, W + oCGRAW);
  kcg1s<<<(Gn + 63) / 64, 256, 0, stream>>>(W + oW1, cg_W1, W + oCGRAW);
  kcg2<<<1, 256, 0, stream>>>(W + oCGRAW, cg_g1, cg_bt1, cg_W2, cg_b2, cg_g2, cg_bt2, W + oCG2);
  kfinal<<<(Gn + 63) / 64, 256, 0, stream>>>(W + oW1, W + oCG2, indv_w2, indv_b2, x, (float*)d_out);
}

// Round 10
// 750.967 us; speedup vs baseline: 1.0540x; 1.0540x over previous
//
#include <hip/hip_runtime.h>

typedef unsigned int u32;
typedef unsigned short u16;

// Problem constants (fixed by the reference)
constexpr int Gn  = 5000;     // genes
constexpr int Bn  = 32;       // batch graphs
constexpr int Pn  = 5000;     // perts
constexpr int Nn  = Bn * Gn;  // 160000
constexpr int ECO = 1600000;
constexpr int EGG = 100000;
constexpr int NTILES = Nn / 128;  // 1250, exact
constexpr int PTILES = 40;        // 5120 padded rows / 128
constexpr int NBK = 625;          // co dst-buckets (dst>>8), 625*256 == 160000 exactly
constexpr int EPB2 = ECO / 256;   // 6250 edges per sort block (exact)

// ---- workspace layout (float offsets) ----
constexpr int oS2 = 128;     // reduced S2 raw sums (needed by kfinS3e2)
constexpr int oZERO = 1536;  // stays zero (bias)
constexpr int oA1 = 2048, oB1 = 2112, oA2 = 2176, oB2 = 2240;
constexpr int oA4 = 2304, oB4 = 2432;            // 128 each
constexpr int oA5 = 2560, oB5 = 2624;
constexpr int oAG = 2688, oBG = 2752;
constexpr int oAP1 = 2816, oBP1 = 2880, oAP2 = 2944, oBP2 = 3008;
constexpr int oAvec = 3072, oCvec = 3136, oCcP = 3200;
constexpr int oM  = 4096, oM1 = 8192;            // oM1: concatenated [M1|M2] 64x128
constexpr int oE2 = 16384, oEMB = 18432, oCGRAW = 20480, oCG2 = 22528;
constexpr int oRG  = 24576;
constexpr int oRP  = oRG  + Gn * 64;
constexpr int oQ   = oRP  + Gn * 64;
constexpr int oRGO = oQ   + Gn * 64;
constexpr int oRBG = oRGO + Pn * 64;
constexpr int oPM  = oRBG + Pn * 64;   // PMB bf16 [5120][64] (in 1.28MB fp32-sized slot)
constexpr int oABG = oPM + Pn * 64;
constexpr int oM1B = oABG + Pn * 64;
constexpr int oM2B = oM1B + Pn * 64;
constexpr int oDGO = oM2B + Pn * 64;
constexpr int oDBG = oDGO + Pn;
constexpr int oDEG = oDBG + Pn;
constexpr int oW1  = oDEG + Nn;
constexpr int oBUF0 = oW1 + Nn;
constexpr int oBUF1 = oBUF0 + Nn * 64;
constexpr size_t WS_FLOATS = (size_t)oBUF1 + (size_t)Nn * 64;  // ~95 MB

__device__ inline u16 f2bf(float f) {
  u32 u = __float_as_uint(f);
  u = (u + 0x7fffu + ((u >> 16) & 1u)) >> 16;
  return (u16)u;
}
__device__ inline float bflo(u32 v) { return __uint_as_float(v << 16); }
__device__ inline float bfhi(u32 v) { return __uint_as_float(v & 0xffff0000u); }
__device__ inline float bf2f(u16 v) { return __uint_as_float((u32)v << 16); }

typedef __attribute__((ext_vector_type(8))) short short8v;  // 8 bf16 (4 VGPRs)
typedef __attribute__((ext_vector_type(4))) float f32x4;    // MFMA accumulator

__global__ __launch_bounds__(256) void kzero(float* p, int n) {
  int i = blockIdx.x * 256 + threadIdx.x;
  if (i < n) p[i] = 0.f;
}

// row-wise L2 renorm (norm clipped to <=1); optional per-block column stats PARTIALS
__global__ __launch_bounds__(256) void krenorm(const float* __restrict__ in, float* __restrict__ out,
                                               float* __restrict__ partial, u16* __restrict__ outb, int rows) {
  int lane = threadIdx.x & 63, wv = threadIdx.x >> 6;
  int gw = blockIdx.x * 4 + wv, nw = gridDim.x * 4;
  float ps = 0.f, pq = 0.f;
  for (int r = gw; r < rows; r += nw) {
    float v = in[r * 64 + lane];
    float sq = v * v;
    for (int off = 32; off; off >>= 1) sq += __shfl_xor(sq, off, 64);
    float nn = sqrtf(sq);
    float s = fminf(1.f, 1.f / fmaxf(nn, 1e-12f));
    float o = v * s;
    out[r * 64 + lane] = o;
    if (outb) outb[r * 64 + lane] = f2bf(o);
    ps += o; pq += o * o;
  }
  if (!partial) return;
  __shared__ float red[4][64], red2[4][64];
  red[wv][lane] = ps; red2[wv][lane] = pq;
  __syncthreads();
  if (wv == 0) {
    float s = red[0][lane] + red[1][lane] + red[2][lane] + red[3][lane];
    float q = red2[0][lane] + red2[1][lane] + red2[2][lane] + red2[3][lane];
    partial[blockIdx.x * 128 + lane] = s;
    partial[blockIdx.x * 128 + 64 + lane] = q;
  }
}

// reduce per-block partials [nblk][2*outc] over blocks, then BN-finalize.
__global__ __launch_bounds__(1024) void kredfin(const float* __restrict__ part, int nblk, int outc,
                                                const float* __restrict__ g, const float* __restrict__ bt,
                                                float* __restrict__ a, float* __restrict__ b,
                                                float* __restrict__ outSQ, float invn) {
  __shared__ float rs[16][64], rq[16][64];
  int t = threadIdx.x, c = t & 63, seg = t >> 6;
  int col = blockIdx.x * 64 + c;
  int pitch = 2 * outc;
  float s = 0.f, q = 0.f;
  for (int r = seg; r < nblk; r += 16) {
    s += part[(size_t)r * pitch + col];
    q += part[(size_t)r * pitch + outc + col];
  }
  rs[seg][c] = s; rq[seg][c] = q;
  __syncthreads();
  if (t < 64) {
    int cc = blockIdx.x * 64 + t;
    float S = 0.f, Q = 0.f;
#pragma unroll
    for (int i = 0; i < 16; i++) { S += rs[i][t]; Q += rq[i][t]; }
    float mean = S * invn;
    float var = Q * invn - mean * mean;
    float sc = g[cc] * rsqrtf(var + 1e-5f);
    a[cc] = sc;
    b[cc] = bt[cc] - mean * sc;
    if (outSQ) { outSQ[cc] = S; outSQ[outc + cc] = Q; }
  }
}

// reduce per-block per-graph partials [NTILES][128] -> S3B[32][64]
__global__ __launch_bounds__(64) void kredB(const float* __restrict__ part, float* __restrict__ S3B) {
  int b = blockIdx.x;   // graph 0..31
  int c = threadIdx.x;  // col 0..63
  float s = 0.f;
  int r0 = (b == 0) ? 0 : ((b - 1) * Gn) / 128;
  int r1 = ((b + 1) * Gn + 127) / 128;
  if (r1 > NTILES) r1 = NTILES;
  for (int r = r0; r < r1; r++) {
    int bLo = (r * 128) / Gn;
    if (bLo == b) s += part[(size_t)r * 128 + c];
    else if (bLo + 1 == b) s += part[(size_t)r * 128 + 64 + c];
  }
  S3B[b * 64 + c] = s;
}

// Mout[i*mpitch+j] = alpha * (A @ Bm)[i][j]; optional cvec = bias + beta * A @ (bv1+bv2)
__global__ __launch_bounds__(256) void ksmallmat(const float* __restrict__ A, const float* __restrict__ Bm,
                                                 float alpha, const float* __restrict__ bias,
                                                 const float* __restrict__ bv1, const float* __restrict__ bv2,
                                                 float beta, float* __restrict__ Mout, int mpitch,
                                                 float* __restrict__ cvec) {
  __shared__ float As[4096], Bs[4096];
  int t = threadIdx.x;
  for (int m = 0; m < 16; m++) { As[m * 256 + t] = A[m * 256 + t]; Bs[m * 256 + t] = Bm[m * 256 + t]; }
  __syncthreads();
  int j = t & 63, ig = t >> 6;
  for (int ii = 0; ii < 16; ii++) {
    int i = ig * 16 + ii;
    float acc = 0.f;
    for (int k = 0; k < 64; k++) acc += As[i * 64 + k] * Bs[k * 64 + j];
    Mout[i * mpitch + j] = alpha * acc;
  }
  if (cvec && t < 64) {
    float acc = bias ? bias[t] : 0.f;
    for (int k = 0; k < 64; k++) {
      float bb = (bv1 ? bv1[k] : 0.f) + (bv2 ? bv2[k] : 0.f);
      acc += beta * As[t * 64 + k] * bb;
    }
    cvec[t] = acc;
  }
}

// histogram with ticket: one atomic per edge (small graphs only)
__global__ __launch_bounds__(256) void khist(const int* __restrict__ dst, int* __restrict__ cnt,
                                             int* __restrict__ ticket, int E) {
  int e = blockIdx.x * 256 + threadIdx.x;
  if (e < E) ticket[e] = atomicAdd(&cnt[dst[e]], 1);
}

// ---- block scan (1024 elems/block) ----
__global__ __launch_bounds__(256) void kscan1(const int* __restrict__ cnt, int* __restrict__ bsum, int n) {
  __shared__ int sh[256];
  int b = blockIdx.x, t = threadIdx.x;
  int base = b * 1024 + t * 4;
  int s = 0;
#pragma unroll
  for (int j = 0; j < 4; j++) { int i = base + j; if (i < n) s += cnt[i]; }
  sh[t] = s; __syncthreads();
  for (int d = 128; d; d >>= 1) { if (t < d) sh[t] += sh[t + d]; __syncthreads(); }
  if (t == 0) bsum[b] = sh[0];
}
__global__ __launch_bounds__(256) void kscan2(int* bsum, int nb, int* off_n) {
  __shared__ int sh[256];
  int t = threadIdx.x;
  int v = (t < nb) ? bsum[t] : 0;
  sh[t] = v;
  __syncthreads();
  for (int d = 1; d < 256; d <<= 1) {
    int u = (t >= d) ? sh[t - d] : 0;
    __syncthreads();
    sh[t] += u;
    __syncthreads();
  }
  if (t < nb) bsum[t] = sh[t] - v;  // exclusive
  if (t == nb - 1 && off_n) *off_n = sh[t];
}
__global__ __launch_bounds__(256) void kscan3(int* __restrict__ cnt, const int* __restrict__ bsum, int n) {
  __shared__ int sh[256];
  int b = blockIdx.x, t = threadIdx.x;
  int base = b * 1024 + t * 4;
  int c0 = (base + 0 < n) ? cnt[base + 0] : 0;
  int c1 = (base + 1 < n) ? cnt[base + 1] : 0;
  int c2 = (base + 2 < n) ? cnt[base + 2] : 0;
  int c3 = (base + 3 < n) ? cnt[base + 3] : 0;
  int tot = c0 + c1 + c2 + c3;
  sh[t] = tot; __syncthreads();
  for (int d = 1; d < 256; d <<= 1) {
    int v = (t >= d) ? sh[t - d] : 0;
    __syncthreads();
    sh[t] += v;
    __syncthreads();
  }
  int excl = sh[t] - tot + bsum[b];
  if (base + 0 < n) cnt[base + 0] = excl;
  if (base + 1 < n) cnt[base + 1] = excl + c0;
  if (base + 2 < n) cnt[base + 2] = excl + c0 + c1;
  if (base + 3 < n) cnt[base + 3] = excl + c0 + c1 + c2;
}

// atomic-free CSR fill using tickets: pack[off[d]+ticket] = (w, src_full)
__global__ __launch_bounds__(256) void kfillt(const int* __restrict__ src, const int* __restrict__ dst,
                                              const float* __restrict__ w, const int* __restrict__ off,
                                              const int* __restrict__ ticket, float2* __restrict__ pack, int E) {
  int e = blockIdx.x * 256 + threadIdx.x;
  if (e >= E) return;
  int d = dst[e];
  int pos = off[d] + ticket[e];
  pack[pos] = make_float2(w[e], __int_as_float(src[e]));
}

// per-row: deg = 1 + sum(w) over CSR row; dinv = rsqrt(deg)
__global__ __launch_bounds__(256) void kdinvrow(const int* __restrict__ off, const float2* __restrict__ pack,
                                                float* __restrict__ dinv, int n) {
  int i = blockIdx.x * 256 + threadIdx.x;
  if (i >= n) return;
  int b0 = off[i], b1 = off[i + 1];
  float s = 1.f;
  for (int j = b0; j < b1; j++) s += pack[j].x;
  dinv[i] = rsqrtf(s);
}

// ===== co-CSR build v2: per-block LDS counting sort, fully streaming writes =====
__global__ __launch_bounds__(256) void kpsort(const int* __restrict__ src, const int* __restrict__ dst,
                                              const float* __restrict__ w, float2* __restrict__ stg,
                                              int* __restrict__ Cg, int* __restrict__ Lg) {
  __shared__ int cnt[NBK];
  __shared__ int loff[NBK];
  __shared__ int cur[NBK];
  __shared__ int ssc[256];
  __shared__ float2 sbuf[EPB2];
  int t = threadIdx.x;
  int e0 = blockIdx.x * EPB2;
  for (int i = t; i < NBK; i += 256) cnt[i] = 0;
  __syncthreads();
  for (int e = e0 + t; e < e0 + EPB2; e += 256) atomicAdd(&cnt[dst[e] >> 8], 1);
  __syncthreads();
  int i0 = t * 3;
  int c3[3];
  int s = 0;
#pragma unroll
  for (int j = 0; j < 3; j++) { int i = i0 + j; c3[j] = (i < NBK) ? cnt[i] : 0; s += c3[j]; }
  ssc[t] = s;
  __syncthreads();
  for (int d = 1; d < 256; d <<= 1) {
    int u = (t >= d) ? ssc[t - d] : 0;
    __syncthreads();
    ssc[t] += u;
    __syncthreads();
  }
  int base = ssc[t] - s;
#pragma unroll
  for (int j = 0; j < 3; j++) {
    int i = i0 + j;
    if (i < NBK) { loff[i] = base; cur[i] = base; }
    base += c3[j];
  }
  __syncthreads();
  for (int e = e0 + t; e < e0 + EPB2; e += 256) {
    int d = dst[e];
    int pos = atomicAdd(&cur[d >> 8], 1);
    sbuf[pos] = make_float2(w[e], __int_as_float(src[e] | ((d & 255) << 18)));
  }
  __syncthreads();
  for (int i = t; i < EPB2; i += 256) stg[(size_t)e0 + i] = sbuf[i];
  for (int i = t; i < NBK; i += 256) {
    Cg[blockIdx.x * NBK + i] = cnt[i];
    Lg[blockIdx.x * NBK + i] = loff[i];
  }
}

// column-sum C over blocks -> bucket totals T
__global__ __launch_bounds__(256) void ksumT(const int* __restrict__ Cg, int* __restrict__ T) {
  int bk = blockIdx.x * 256 + threadIdx.x;
  if (bk >= NBK) return;
  int s = 0;
  for (int blk = 0; blk < 256; blk++) s += Cg[blk * NBK + bk];
  T[bk] = s;
}

// single-block exclusive scan of NBK bucket totals -> bbase; total -> off[Nn]
__global__ __launch_bounds__(256) void kpscan(const int* __restrict__ bcnt, int* __restrict__ bbase,
                                              int* __restrict__ offN) {
  __shared__ int sh[256];
  int t = threadIdx.x;
  int i0 = t * 3;
  int c[3];
  int s = 0;
#pragma unroll
  for (int j = 0; j < 3; j++) { int i = i0 + j; c[j] = (i < NBK) ? bcnt[i] : 0; s += c[j]; }
  sh[t] = s;
  __syncthreads();
  for (int d = 1; d < 256; d <<= 1) {
    int u = (t >= d) ? sh[t - d] : 0;
    __syncthreads();
    sh[t] += u;
    __syncthreads();
  }
  int base = sh[t] - s;
#pragma unroll
  for (int j = 0; j < 3; j++) {
    int i = i0 + j;
    if (i < NBK) bbase[i] = base;
    base += c[j];
  }
  if (t == 255) { bbase[NBK] = base; *offN = base; }
}

// one block per bucket: gather 256 block-segments into LDS, row-hist/scan -> off, dinv;
// LDS-cursor scatter into pack (writes confined to the bucket's contiguous ~20KB range)
__global__ __launch_bounds__(256) void kpcsr2(const int* __restrict__ bbase, const int* __restrict__ Cg,
                                              const int* __restrict__ Lg, const float2* __restrict__ stg,
                                              int* __restrict__ off, float2* __restrict__ pack,
                                              float* __restrict__ dinv) {
  constexpr int CAP = 4096;  // mean 2560, sigma ~51 -> 30-sigma headroom
  __shared__ float2 ebuf[CAP];
  __shared__ int rh[256];
  __shared__ int sc2[256];
  __shared__ float ws[256];
  __shared__ int nEs;
  int bk = blockIdx.x, t = threadIdx.x;
  int myC = Cg[t * NBK + bk];
  int myL = Lg[t * NBK + bk];
  sc2[t] = myC;
  __syncthreads();
  for (int d = 1; d < 256; d <<= 1) {
    int u = (t >= d) ? sc2[t - d] : 0;
    __syncthreads();
    sc2[t] += u;
    __syncthreads();
  }
  int myO = sc2[t] - myC;
  if (t == 255) nEs = sc2[255];
  rh[t] = 0; ws[t] = 0.f;
  __syncthreads();
  int nE = nEs;
  {
    const float2* sp = &stg[(size_t)t * EPB2 + myL];
    for (int i = 0; i < myC; i++) ebuf[myO + i] = sp[i];
  }
  __syncthreads();
  for (int i = t; i < nE; i += 256) {
    float2 p = ebuf[i];
    int r = (__float_as_int(p.y) >> 18) & 255;
    atomicAdd(&rh[r], 1);
    atomicAdd(&ws[r], p.x);
  }
  __syncthreads();
  int cnt = rh[t];
  sc2[t] = cnt;
  __syncthreads();
  for (int d = 1; d < 256; d <<= 1) {
    int u = (t >= d) ? sc2[t - d] : 0;
    __syncthreads();
    sc2[t] += u;
    __syncthreads();
  }
  int gpos = bbase[bk] + sc2[t] - cnt;
  int grow = (bk << 8) + t;  // 625*256 == 160000: always valid
  off[grow] = gpos;
  dinv[grow] = rsqrtf(1.f + ws[t]);
  rh[t] = gpos;  // cursor
  __syncthreads();
  for (int i = t; i < nE; i += 256) {
    float2 p = ebuf[i];
    int r = (__float_as_int(p.y) >> 18) & 255;
    int pos = atomicAdd(&rh[r], 1);
    pack[pos] = p;
  }
}

// wave-per-row CSR gather, bf16 out with pitch+column offset; src masked to 18 bits
// (kept for the small go/bg graphs)
__global__ __launch_bounds__(256) void kgather(const int* __restrict__ off, const float2* __restrict__ pack,
                                               const float* __restrict__ dinv, const float* __restrict__ tab,
                                               u16* __restrict__ aggb, int pitch, int coff, int n) {
  int lane = threadIdx.x & 63;
  int wv = blockIdx.x * 4 + (threadIdx.x >> 6);
  int nw = gridDim.x * 4;
  for (int i = wv; i < n; i += nw) {
    int b0 = off[i], b1 = off[i + 1];
    float di = dinv[i];
    float acc = di * tab[(i % Gn) * 64 + lane];
    for (int base = b0; base < b1; base += 64) {
      int m = b1 - base; if (m > 64) m = 64;
      float cj = 0.f; int idxj = 0;
      if (lane < m) {
        float2 p = pack[base + lane];
        int s = __float_as_int(p.y) & 0x3FFFF;
        cj = p.x * dinv[s];
        idxj = (s % Gn) * 64;
      }
      int j = 0;
      for (; j + 1 < m; j += 2) {
        float c0 = __shfl(cj, j, 64);     int i0 = __shfl(idxj, j, 64);
        float c1 = __shfl(cj, j + 1, 64); int i1 = __shfl(idxj, j + 1, 64);
        float t0 = tab[i0 + lane];
        float t1 = tab[i1 + lane];
        acc = fmaf(c0, t0, acc);
        acc = fmaf(c1, t1, acc);
      }
      if (j < m) {
        float c0 = __shfl(cj, j, 64); int i0 = __shfl(idxj, j, 64);
        acc = fmaf(c0, tab[i0 + lane], acc);
      }
    }
    acc *= di;
    aggb[(size_t)i * pitch + coff + lane] = f2bf(acc);
  }
}

// ===== fused co-gather + t1, 8-lane-group version (R8 post-mortem: per-ROW cost
// dominates at avg degree 10 — amortize it 8x). Wave = 8 groups x 8 lanes; group
// handles one row; lane holds 8 cols (uint4 of bf16 from table PMB). No cross-group
// reduce. Rows assigned consecutively within a wave -> coalesced off/dinv/pack/stores.
// t1[i] = di*(di*PMB[i%Gn] + sum coef*PMB[s%Gn]) + Q[i%Gn]
__global__ __launch_bounds__(256) void kgt2(const int* __restrict__ off, const float2* __restrict__ pack,
                                            const float* __restrict__ dinv, const uint4* __restrict__ PMB,
                                            const float4* __restrict__ Q4, u16* __restrict__ Ybf,
                                            float* __restrict__ partS) {
  __shared__ float sstat[128];
  int t = threadIdx.x;
  int lane = t & 63, wv = t >> 6;
  int grp = lane >> 3, le = lane & 7;
  for (int idx = t; idx < 128; idx += 256) sstat[idx] = 0.f;
  __syncthreads();
  float sS[8], sQ[8];
#pragma unroll
  for (int j = 0; j < 8; j++) { sS[j] = 0.f; sQ[j] = 0.f; }
  int base0 = (blockIdx.x * 4 + wv) * 8;
  int stride = gridDim.x * 32;
  for (int i0 = base0; i0 < Nn; i0 += stride) {
    int i = i0 + grp;  // i0 is a multiple of 8 and < Nn (Nn % 8 == 0) -> i < Nn
    int g = i % Gn;
    int b0 = off[i], b1 = off[i + 1];
    float di = dinv[i];
    float acc[8];
    {  // self loop: di * PMB[g]
      uint4 tv = PMB[g * 8 + le];
      acc[0] = di * bflo(tv.x); acc[1] = di * bfhi(tv.x);
      acc[2] = di * bflo(tv.y); acc[3] = di * bfhi(tv.y);
      acc[4] = di * bflo(tv.z); acc[5] = di * bfhi(tv.z);
      acc[6] = di * bflo(tv.w); acc[7] = di * bfhi(tv.w);
    }
    for (int base = b0; base < b1; base += 8) {
      int m = b1 - base; if (m > 8) m = 8;
      float cj = 0.f; int ix = 0;
      if (le < m) {
        float2 p = pack[base + le];
        int s = __float_as_int(p.y) & 0x3FFFF;
        cj = p.x * dinv[s];
        ix = s % Gn;
      }
#pragma unroll
      for (int e = 0; e < 8; e++) {
        float c = __shfl(cj, grp * 8 + e, 64);
        int x = __shfl(ix, grp * 8 + e, 64);
        if (e < m) {
          uint4 tv = PMB[x * 8 + le];
          acc[0] = fmaf(c, bflo(tv.x), acc[0]);
          acc[1] = fmaf(c, bfhi(tv.x), acc[1]);
          acc[2] = fmaf(c, bflo(tv.y), acc[2]);
          acc[3] = fmaf(c, bfhi(tv.y), acc[3]);
          acc[4] = fmaf(c, bflo(tv.z), acc[4]);
          acc[5] = fmaf(c, bfhi(tv.z), acc[5]);
          acc[6] = fmaf(c, bflo(tv.w), acc[6]);
          acc[7] = fmaf(c, bfhi(tv.w), acc[7]);
        }
      }
    }
    float4 q0 = Q4[g * 16 + le * 2];
    float4 q1 = Q4[g * 16 + le * 2 + 1];
    float v[8];
    v[0] = fmaf(di, acc[0], q0.x); v[1] = fmaf(di, acc[1], q0.y);
    v[2] = fmaf(di, acc[2], q0.z); v[3] = fmaf(di, acc[3], q0.w);
    v[4] = fmaf(di, acc[4], q1.x); v[5] = fmaf(di, acc[5], q1.y);
    v[6] = fmaf(di, acc[6], q1.z); v[7] = fmaf(di, acc[7], q1.w);
#pragma unroll
    for (int j = 0; j < 8; j++) { sS[j] += v[j]; sQ[j] += v[j] * v[j]; }
    uint4 o;
    o.x = (u32)f2bf(v[0]) | ((u32)f2bf(v[1]) << 16);
    o.y = (u32)f2bf(v[2]) | ((u32)f2bf(v[3]) << 16);
    o.z = (u32)f2bf(v[4]) | ((u32)f2bf(v[5]) << 16);
    o.w = (u32)f2bf(v[6]) | ((u32)f2bf(v[7]) << 16);
    *(uint4*)&Ybf[(size_t)i * 64 + le * 8] = o;
  }
#pragma unroll
  for (int j = 0; j < 8; j++) {
    atomicAdd(&sstat[le * 8 + j], sS[j]);
    atomicAdd(&sstat[64 + le * 8 + j], sQ[j]);
  }
  __syncthreads();
  for (int idx = t; idx < 128; idx += 256) partS[(size_t)blockIdx.x * 128 + idx] = sstat[idx];
}

// ===================== MFMA GEMM (one 128-row tile per block) =====================
template <int K, int OUTC, bool PRE, bool EB, bool PERG, bool STATS, bool OUTF32, bool STATB>
__global__ __launch_bounds__(256, 3) void mfgemm(
    const u16* __restrict__ Xb, const float* __restrict__ Wg, const float* __restrict__ bias,
    const float* __restrict__ pa, const float* __restrict__ pb,
    const float* __restrict__ perg, u16* __restrict__ Ybf, float* __restrict__ stats,
    float* __restrict__ statB, int rows) {
  constexpr int NT  = OUTC / 16;   // 16-col output tiles per wave-row
  constexpr int KH  = K / 32;      // MFMA K-steps
  constexpr int SLK = K / 8;       // 16B slots per input row
  constexpr int SLO = OUTC / 8;    // 16B slots per output row
  constexpr int XROW = (K > OUTC ? K : OUTC) * 2;  // bytes per xs row (shared in/out stage)
  __shared__ __align__(16) unsigned char xsb[128 * XROW];
  __shared__ __align__(16) unsigned char wsb[OUTC * K * 2];
  __shared__ float sstat[STATS ? 2 * OUTC : 1];
  __shared__ float sstatB[STATB ? 128 : 1];
  int t = threadIdx.x;
  int l = t & 63, w = t >> 6, lrow = l & 15, lk = l >> 4;
  int R0 = blockIdx.x * 128;

  // ---- stage weights: fp32 -> bf16, swizzled ----
  for (int idx = t; idx < OUTC * SLK; idx += 256) {
    int oc = idx / SLK, s8 = idx % SLK;
    const float* wp = &Wg[oc * K + s8 * 8];
    uint4 o;
    o.x = (u32)f2bf(wp[0]) | ((u32)f2bf(wp[1]) << 16);
    o.y = (u32)f2bf(wp[2]) | ((u32)f2bf(wp[3]) << 16);
    o.z = (u32)f2bf(wp[4]) | ((u32)f2bf(wp[5]) << 16);
    o.w = (u32)f2bf(wp[6]) | ((u32)f2bf(wp[7]) << 16);
    *(uint4*)&wsb[oc * (2 * K) + ((s8 * 16) ^ ((oc & 7) << 4))] = o;
  }
  if constexpr (STATS) for (int idx = t; idx < 2 * OUTC; idx += 256) sstat[idx] = 0.f;
  if constexpr (STATB) for (int idx = t; idx < 128; idx += 256) sstatB[idx] = 0.f;

  // ---- stage input tile: coalesced 16B loads ----
#pragma unroll
  for (int m = 0; m < SLK / 2; m++) {
    int f = m * 256 + t;
    int r = f / SLK, s8 = f % SLK;
    uint4 u = *(const uint4*)&Xb[(size_t)(R0 + r) * K + s8 * 8];
    if constexpr (PRE) {
      int c0 = s8 * 8;
      float4 A0 = *(const float4*)&pa[c0];
      float4 A1 = *(const float4*)&pa[c0 + 4];
      const float* pbb = EB ? &pb[((R0 + r) / Gn) * 64] : pb;
      float4 B0 = *(const float4*)&pbb[c0];
      float4 B1 = *(const float4*)&pbb[c0 + 4];
      float v0 = fmaxf(fmaf(A0.x, bflo(u.x), B0.x), 0.f);
      float v1 = fmaxf(fmaf(A0.y, bfhi(u.x), B0.y), 0.f);
      float v2 = fmaxf(fmaf(A0.z, bflo(u.y), B0.z), 0.f);
      float v3 = fmaxf(fmaf(A0.w, bfhi(u.y), B0.w), 0.f);
      float v4 = fmaxf(fmaf(A1.x, bflo(u.z), B1.x), 0.f);
      float v5 = fmaxf(fmaf(A1.y, bfhi(u.z), B1.y), 0.f);
      float v6 = fmaxf(fmaf(A1.z, bflo(u.w), B1.z), 0.f);
      float v7 = fmaxf(fmaf(A1.w, bfhi(u.w), B1.w), 0.f);
      u.x = (u32)f2bf(v0) | ((u32)f2bf(v1) << 16);
      u.y = (u32)f2bf(v2) | ((u32)f2bf(v3) << 16);
      u.z = (u32)f2bf(v4) | ((u32)f2bf(v5) << 16);
      u.w = (u32)f2bf(v6) | ((u32)f2bf(v7) << 16);
    }
    *(uint4*)&xsb[r * XROW + ((s8 * 16) ^ ((r & 7) << 4))] = u;
  }
  float bcol[NT];
#pragma unroll
  for (int nt = 0; nt < NT; nt++) bcol[nt] = bias[nt * 16 + lrow];
  __syncthreads();

  // ---- MFMA: wave w owns rows w*32..w*32+31, all OUTC cols ----
  short8v af[2][KH];
#pragma unroll
  for (int rt = 0; rt < 2; rt++)
#pragma unroll
    for (int h = 0; h < KH; h++) {
      int row = w * 32 + rt * 16 + lrow;
      af[rt][h] = *(const short8v*)&xsb[row * XROW + ((h * 64 + lk * 16) ^ ((row & 7) << 4))];
    }
  f32x4 acc[2][NT];
#pragma unroll
  for (int rt = 0; rt < 2; rt++)
#pragma unroll
    for (int nt = 0; nt < NT; nt++) {
      f32x4 z = {0.f, 0.f, 0.f, 0.f};
      acc[rt][nt] = z;
    }
#pragma unroll
  for (int nt = 0; nt < NT; nt++) {
    int brow = nt * 16 + lrow;
#pragma unroll
    for (int h = 0; h < KH; h++) {
      short8v bfr = *(const short8v*)&wsb[brow * (2 * K) + ((h * 64 + lk * 16) ^ ((brow & 7) << 4))];
      acc[0][nt] = __builtin_amdgcn_mfma_f32_16x16x32_bf16(af[0][h], bfr, acc[0][nt], 0, 0, 0);
      acc[1][nt] = __builtin_amdgcn_mfma_f32_16x16x32_bf16(af[1][h], bfr, acc[1][nt], 0, 0, 0);
    }
  }
  __syncthreads();  // all xs reads done -> safe to reuse xs as output stage

  // ---- epilogue ----
  float sS[NT], sQ[NT], sB0[NT], sB1[NT];
#pragma unroll
  for (int nt = 0; nt < NT; nt++) { sS[nt] = 0.f; sQ[nt] = 0.f; sB0[nt] = 0.f; sB1[nt] = 0.f; }
  int hiStart = STATB ? (R0 / Gn + 1) * Gn : 0x7fffffff;
  float* Yf = (float*)Ybf;
#pragma unroll
  for (int rt = 0; rt < 2; rt++) {
#pragma unroll
    for (int r = 0; r < 4; r++) {
      int orow = w * 32 + rt * 16 + lk * 4 + r;
      int grow = R0 + orow;
      bool valid = grow < rows;
      int qoff = 0;
      if constexpr (PERG) qoff = (grow % Gn) * 64;
#pragma unroll
      for (int nt = 0; nt < NT; nt++) {
        float v = acc[rt][nt][r] + bcol[nt];
        if constexpr (PERG) v += perg[qoff + nt * 16 + lrow];
        if (valid) {
          if constexpr (STATS) { sS[nt] += v; sQ[nt] += v * v; }
          if constexpr (STATB) { if (grow >= hiStart) sB1[nt] += v; else sB0[nt] += v; }
        }
        if constexpr (OUTF32) {
          if (valid) Yf[(size_t)grow * OUTC + nt * 16 + lrow] = v;
        } else {
          *(u16*)&xsb[orow * (2 * OUTC) + ((2 * (nt * 16 + lrow)) ^ ((orow & 7) << 4))] = f2bf(v);
        }
      }
    }
  }
  if constexpr (STATS) {
#pragma unroll
    for (int nt = 0; nt < NT; nt++) {
      atomicAdd(&sstat[nt * 16 + lrow], sS[nt]);
      atomicAdd(&sstat[OUTC + nt * 16 + lrow], sQ[nt]);
    }
  }
  if constexpr (STATB) {
#pragma unroll
    for (int nt = 0; nt < NT; nt++) {
      atomicAdd(&sstatB[nt * 16 + lrow], sB0[nt]);
      atomicAdd(&sstatB[64 + nt * 16 + lrow], sB1[nt]);
    }
  }
  __syncthreads();

  if constexpr (!OUTF32) {
#pragma unroll
    for (int m = 0; m < SLO / 2; m++) {
      int f = m * 256 + t;
      int r = f / SLO, c8 = f % SLO;
      uint4 o = *(const uint4*)&xsb[r * (2 * OUTC) + ((16 * c8) ^ ((r & 7) << 4))];
      *(uint4*)&Ybf[(size_t)(R0 + r) * OUTC + c8 * 8] = o;
    }
  }
  if constexpr (STATS)
    for (int idx = t; idx < 2 * OUTC; idx += 256) stats[(size_t)blockIdx.x * 2 * OUTC + idx] = sstat[idx];
  if constexpr (STATB)
    for (int idx = t; idx < 128; idx += 256) statB[(size_t)blockIdx.x * 128 + idx] = sstatB[idx];
}

// finalize S3 analytically; Avec = a3*a2, e2[b] = a3*(b2+emb[b]) + b3.
__global__ __launch_bounds__(256) void kfinS3e2(const float* __restrict__ S2, const float* __restrict__ g,
                                                const float* __restrict__ bt, const float* __restrict__ a2,
                                                const float* __restrict__ b2, const float* __restrict__ emb,
                                                const float* __restrict__ S3B,
                                                float* __restrict__ Avec, float* __restrict__ e2) {
  __shared__ float a3s[64], b3s[64];
  int t = threadIdx.x;
  if (t < 64) {
    float a2c = a2[t], b2c = b2[t];
    float su = 0.f, sxc = 0.f, sc2 = 0.f;
    for (int b = 0; b < Bn; b++) {
      float cb = b2c + emb[b * 64 + t];
      float sb = S3B[b * 64 + t];
      su += cb;
      sxc += cb * sb;
      sc2 += cb * cb;
    }
    float Su = a2c * S2[t] + (float)Gn * su;
    float Sq = a2c * a2c * S2[64 + t] + 2.f * a2c * sxc + (float)Gn * sc2;
    float mean = Su * (1.f / Nn);
    float var = Sq * (1.f / Nn) - mean * mean;
    float sc = g[t] * rsqrtf(var + 1e-5f);
    float sh = bt[t] - mean * sc;
    a3s[t] = sc; b3s[t] = sh;
    Avec[t] = sc * a2c;
  }
  __syncthreads();
  for (int idx = t; idx < 2048; idx += 256) {
    int c = idx & 63;
    e2[idx] = a3s[c] * (b2[c] + emb[idx]) + b3s[c];
  }
}

// w1[i] = dot(a5*R2(bf16)+b5, indv_w1[i%G]) + indv_b1[i%G]
__global__ __launch_bounds__(256) void k13_kernel(const u16* __restrict__ R2, const float* __restrict__ a5,
                                                  const float* __restrict__ b5, const float* __restrict__ iw1,
                                                  const float* __restrict__ ib1, float* __restrict__ w1out,
                                                  int rows) {
  int t = blockIdx.x * 256 + threadIdx.x;
  int i = t >> 4, j = t & 15;
  if (i >= rows) return;
  int g = i % Gn;
  uint2 u = *(const uint2*)&R2[(size_t)i * 64 + j * 4];
  float rx = bflo(u.x), ry = bfhi(u.x), rz = bflo(u.y), rw = bfhi(u.y);
  float4 a = ((const float4*)a5)[j];
  float4 b = ((const float4*)b5)[j];
  float4 w = ((const float4*)iw1)[g * 16 + j];
  float p = (a.x * rx + b.x) * w.x + (a.y * ry + b.y) * w.y +
            (a.z * rz + b.z) * w.z + (a.w * rw + b.w) * w.w;
  for (int off = 8; off; off >>= 1) p += __shfl_xor(p, off, 64);
  if (j == 0) w1out[i] = p + ib1[g];
}

// init cgraw with bias
__global__ __launch_bounds__(256) void kinitcg(const float* __restrict__ cgb1, float* __restrict__ cgraw) {
  int idx = blockIdx.x * 256 + threadIdx.x;
  if (idx < Bn * 64) cgraw[idx] = cgb1[idx & 63];
}

// split-K GEMM: cgraw[b][col] += sum_{k in chunk} w1[b][k]*cgW1[col][k]
__global__ __launch_bounds__(256) void kcg1s(const float* __restrict__ w1, const float* __restrict__ cgW1,
                                             float* __restrict__ cgraw) {
  __shared__ float w1s[64 * 36];
  __shared__ float cgs[64 * 65];
  int t = threadIdx.x;
  int k0 = blockIdx.x * 64;
  int kmax = Gn - k0; if (kmax > 64) kmax = 64;
  for (int idx = t; idx < 2048; idx += 256) {
    int row = idx >> 6, k = idx & 63;
    w1s[k * 36 + row] = (k < kmax) ? w1[row * Gn + k0 + k] : 0.f;
  }
  for (int idx = t; idx < 4096; idx += 256) {
    int col = idx >> 6, k = idx & 63;
    cgs[k * 65 + col] = (k < kmax) ? cgW1[col * Gn + k0 + k] : 0.f;
  }
  __syncthreads();
  int col = t & 63, rg = t >> 6;
  float acc[8];
#pragma unroll
  for (int i = 0; i < 8; i++) acc[i] = 0.f;
  for (int k = 0; k < 64; k++) {
    float wk = cgs[k * 65 + col];
    const float* wr = &w1s[k * 36 + rg * 8];
    float4 r0 = *(const float4*)wr;
    float4 r1 = *(const float4*)(wr + 4);
    acc[0] = fmaf(r0.x, wk, acc[0]);
    acc[1] = fmaf(r0.y, wk, acc[1]);
    acc[2] = fmaf(r0.z, wk, acc[2]);
    acc[3] = fmaf(r0.w, wk, acc[3]);
    acc[4] = fmaf(r1.x, wk, acc[4]);
    acc[5] = fmaf(r1.y, wk, acc[5]);
    acc[6] = fmaf(r1.z, wk, acc[6]);
    acc[7] = fmaf(r1.w, wk, acc[7]);
  }
#pragma unroll
  for (int i = 0; i < 8; i++) atomicAdd(&cgraw[(rg * 8 + i) * 64 + col], acc[i]);
}

// single-block: cg2 = bn2(relu(bn1(cgraw)) @ W2^T + b2)   (BN over 32 rows)
__global__ __launch_bounds__(256) void kcg2(const float* __restrict__ cgraw, const float* __restrict__ g1,
                                            const float* __restrict__ bt1, const float* __restrict__ W2,
                                            const float* __restrict__ b2, const float* __restrict__ g2,
                                            const float* __restrict__ bt2, float* __restrict__ cg2out) {
  int t = threadIdx.x, c = t & 63, bg = t >> 6;
  __shared__ float hmid[2048], sred[4][64], qred[4][64], asc[64], bsh[64];
  float y[8];
  float ps = 0.f, pq = 0.f;
  for (int jb = 0; jb < 8; jb++) {
    int b = bg * 8 + jb;
    float v = cgraw[b * 64 + c];
    y[jb] = v; ps += v; pq += v * v;
  }
  sred[bg][c] = ps; qred[bg][c] = pq;
  __syncthreads();
  if (t < 64) {
    float s = sred[0][t] + sred[1][t] + sred[2][t] + sred[3][t];
    float q = qred[0][t] + qred[1][t] + qred[2][t] + qred[3][t];
    float mean = s * (1.f / 32.f), var = q * (1.f / 32.f) - mean * mean;
    float sc = g1[t] * rsqrtf(var + 1e-5f);
    asc[t] = sc; bsh[t] = bt1[t] - mean * sc;
  }
  __syncthreads();
  for (int jb = 0; jb < 8; jb++) { int b = bg * 8 + jb; hmid[b * 64 + c] = fmaxf(asc[c] * y[jb] + bsh[c], 0.f); }
  __syncthreads();
  ps = 0.f; pq = 0.f;
  for (int jb = 0; jb < 8; jb++) {
    int b = bg * 8 + jb;
    float a = b2[c];
    for (int k = 0; k < 64; k++) a += hmid[b * 64 + k] * W2[c * 64 + k];
    y[jb] = a; ps += a; pq += a * a;
  }
  sred[bg][c] = ps; qred[bg][c] = pq;
  __syncthreads();
  if (t < 64) {
    float s = sred[0][t] + sred[1][t] + sred[2][t] + sred[3][t];
    float q = qred[0][t] + qred[1][t] + qred[2][t] + qred[3][t];
    float mean = s * (1.f / 32.f), var = q * (1.f / 32.f) - mean * mean;
    float sc = g2[t] * rsqrtf(var + 1e-5f);
    asc[t] = sc; bsh[t] = bt2[t] - mean * sc;
  }
  __syncthreads();
  for (int jb = 0; jb < 8; jb++) { int b = bg * 8 + jb; cg2out[b * 64 + c] = asc[c] * y[jb] + bsh[c]; }
}

// single-block: emb = mlp3(pglob[pert_idx]) with BN over 32 rows (m2 is bf16)
__global__ __launch_bounds__(256) void kemb(const u16* __restrict__ m2, const float* __restrict__ aP2,
                                            const float* __restrict__ bP2, const int* __restrict__ pidx,
                                            const float* __restrict__ Wm, const float* __restrict__ bv,
                                            const float* __restrict__ gg, const float* __restrict__ btv,
                                            float* __restrict__ emb) {
  int t = threadIdx.x, c = t & 63, bg = t >> 6;
  __shared__ float xin[2048], hmid[2048], sred[4][64], qred[4][64], asc[64], bsh[64];
  for (int idx = t; idx < 2048; idx += 256) {
    int b = idx >> 6, cc = idx & 63;
    xin[idx] = aP2[cc] * bf2f(m2[(size_t)pidx[b] * 64 + cc]) + bP2[cc];
  }
  __syncthreads();
  float y[8];
  float ps = 0.f, pq = 0.f;
  for (int jb = 0; jb < 8; jb++) {
    int b = bg * 8 + jb;
    float a = bv[c];
    for (int k = 0; k < 64; k++) a += xin[b * 64 + k] * Wm[c * 64 + k];
    y[jb] = a; ps += a; pq += a * a;
  }
  sred[bg][c] = ps; qred[bg][c] = pq;
  __syncthreads();
  if (t < 64) {
    float s = sred[0][t] + sred[1][t] + sred[2][t] + sred[3][t];
    float q = qred[0][t] + qred[1][t] + qred[2][t] + qred[3][t];
    float mean = s * (1.f / 32.f), var = q * (1.f / 32.f) - mean * mean;
    float sc = gg[t] * rsqrtf(var + 1e-5f);
    asc[t] = sc; bsh[t] = btv[t] - mean * sc;
  }
  __syncthreads();
  for (int jb = 0; jb < 8; jb++) { int b = bg * 8 + jb; hmid[b * 64 + c] = fmaxf(asc[c] * y[jb] + bsh[c], 0.f); }
  __syncthreads();
  ps = 0.f; pq = 0.f;
  for (int jb = 0; jb < 8; jb++) {
    int b = bg * 8 + jb;
    float a = bv[64 + c];
    for (int k = 0; k < 64; k++) a += hmid[b * 64 + k] * Wm[4096 + c * 64 + k];
    y[jb] = a; ps += a; pq += a * a;
  }
  sred[bg][c] = ps; qred[bg][c] = pq;
  __syncthreads();
  if (t < 64) {
    float s = sred[0][t] + sred[1][t] + sred[2][t] + sred[3][t];
    float q = qred[0][t] + qred[1][t] + qred[2][t] + qred[3][t];
    float mean = s * (1.f / 32.f), var = q * (1.f / 32.f) - mean * mean;
    float sc = gg[64 + t] * rsqrtf(var + 1e-5f);
    asc[t] = sc; bsh[t] = btv[64 + t] - mean * sc;
  }
  __syncthreads();
  for (int jb = 0; jb < 8; jb++) { int b = bg * 8 + jb; emb[b * 64 + c] = asc[c] * y[jb] + bsh[c]; }
}

// final: out[b][g] = w1*iw2[g][0] + dot(cg2[b], iw2[g][1:65]) + ib2[g] + x[b][g]
__global__ __launch_bounds__(256) void kfinal(const float* __restrict__ w1, const float* __restrict__ cg2,
                                              const float* __restrict__ iw2, const float* __restrict__ ib2,
                                              const float* __restrict__ x, float* __restrict__ out) {
  __shared__ float iws[64 * 65], cgs[2048];
  int t = threadIdx.x;
  int g0 = blockIdx.x * 64;
  for (int idx = t; idx < 64 * 65; idx += 256) {
    int gi = g0 * 65 + idx;
    iws[idx] = (gi < Gn * 65) ? iw2[gi] : 0.f;
  }
  for (int idx = t; idx < 2048; idx += 256) cgs[idx] = cg2[idx];
  __syncthreads();
  int gl = t & 63, bg = t >> 6;
  int g = g0 + gl;
  if (g >= Gn) return;
  float bias = ib2[g];
  for (int jb = 0; jb < 8; jb++) {
    int b = bg * 8 + jb;
    float acc = w1[b * Gn + g] * iws[gl * 65] + bias;
    for (int k = 0; k < 64; k++) acc += cgs[b * 64 + k] * iws[gl * 65 + 1 + k];
    out[b * Gn + g] = acc + x[b * Gn + g];
  }
}

extern "C" void kernel_launch(void* const* d_in, const int* in_sizes, int n_in,
                              void* d_out, int out_size, void* d_ws, size_t ws_size,
                              hipStream_t stream) {
  (void)in_sizes; (void)n_in; (void)out_size;
  if (ws_size < WS_FLOATS * sizeof(float)) return;

  const float* x        = (const float*)d_in[0];
  const int*   pert_idx = (const int*)d_in[1];
  const int*   ei_co    = (const int*)d_in[2];
  const float* w_co     = (const float*)d_in[3];
  const int*   ei_go    = (const int*)d_in[4];
  const float* w_go     = (const float*)d_in[5];
  const int*   ei_bg    = (const int*)d_in[6];
  const float* w_bg     = (const float*)d_in[7];
  const float* gene_tab = (const float*)d_in[8];
  const float* pos_tab  = (const float*)d_in[9];
  const float* go_tab   = (const float*)d_in[10];
  const float* bg_tab   = (const float*)d_in[11];
  const float* bn_g     = (const float*)d_in[12];
  const float* bn_b     = (const float*)d_in[13];
  const float* sg_W     = (const float*)d_in[14];
  const float* sg_b     = (const float*)d_in[15];
  const float* mlp_W    = (const float*)d_in[16];
  const float* mlp_b    = (const float*)d_in[17];
  const float* mlp_g    = (const float*)d_in[18];
  const float* mlp_bt   = (const float*)d_in[19];
  const float* rec_W1   = (const float*)d_in[20];
  const float* rec_b1   = (const float*)d_in[21];
  const float* rec_g1   = (const float*)d_in[22];
  const float* rec_bt1  = (const float*)d_in[23];
  const float* rec_W2   = (const float*)d_in[24];
  const float* rec_b2   = (const float*)d_in[25];
  const float* rec_g2   = (const float*)d_in[26];
  const float* rec_bt2  = (const float*)d_in[27];
  const float* indv_w1  = (const float*)d_in[28];
  const float* indv_b1  = (const float*)d_in[29];
  const float* cg_W1    = (const float*)d_in[30];
  const float* cg_b1    = (const float*)d_in[31];
  const float* cg_g1    = (const float*)d_in[32];
  const float* cg_bt1   = (const float*)d_in[33];
  const float* cg_W2    = (const float*)d_in[34];
  const float* cg_b2    = (const float*)d_in[35];
  const float* cg_g2    = (const float*)d_in[36];
  const float* cg_bt2   = (const float*)d_in[37];
  const float* indv_w2  = (const float*)d_in[38];
  const float* indv_b2  = (const float*)d_in[39];

  float* W = (float*)d_ws;
  float* buf0 = W + oBUF0;
  float* buf1 = W + oBUF1;

  // CSR scratch lives in buf1 lower region (consumed by kgt2 before t2 writes buf1)
  int*    co_off    = (int*)(buf1);                  // 160001
  int*    bbase     = (int*)(buf1 + 200000);         // 626
  int*    Tbk       = (int*)(buf1 + 202000);         // 625 bucket totals
  int*    sbsum     = (int*)(buf1 + 320128);         // <=256 block sums (go/bg scans)
  float2* co_pack   = (float2*)(buf1 + 400000);      // 1.6M float2
  int*    go_cnt    = (int*)(buf1 + 3700000);
  float2* go_pack   = (float2*)(buf1 + 3720000);
  int*    bg_cnt    = (int*)(buf1 + 4000000);
  float2* bg_pack   = (float2*)(buf1 + 4020000);
  u16*    RPB       = (u16*)(buf1 + 4220000);        // [5120][64] bf16 renormed pos tab
  int*    Cg        = (int*)(buf1 + 4500000);        // [256][625] per-block bucket counts
  int*    Lg        = (int*)(buf1 + 4700000);        // [256][625] per-block local offsets
  int*    go_ticket = (int*)(buf1 + 6200000);
  int*    bg_ticket = (int*)(buf1 + 6400000);
  u16*    pgi       = (u16*)(buf1 + 6600000);        // [5120][128] bf16: go cols 0-63, bg 64-127
  u16*    RGB       = (u16*)(buf1 + 6800000);        // [5120][64] bf16 renormed gene tab
  float2* co_stg    = (float2*)(buf1 + 6963840);     // 1.6M float2 block-major sorted staging

  // stats partial buffers: buf1 upper region (dead co_stg space by the time they're used)
  float* partS = buf1 + 8000000;   // up to [2048][128]
  float* partB = buf1 + 8650000;   // [1250][128]

  // --- phase 0: zero pads, renorm tables, fold small matrices ---
  kzero<<<8, 256, 0, stream>>>(W, 2048);                             // includes oZERO bias
  kzero<<<15, 256, 0, stream>>>(buf1 + 6800000 + 160000, 3840);      // RGB pad rows 5000..5119
  kzero<<<15, 256, 0, stream>>>(buf1 + 4220000 + 160000, 3840);      // RPB pad rows 5000..5119
  kzero<<<30, 256, 0, stream>>>(buf1 + 6600000 + 320000, 7680);      // pgi pad rows 5000..5119
  krenorm<<<160, 256, 0, stream>>>(gene_tab, W + oRG, partS, RGB, Gn);
  kredfin<<<1, 1024, 0, stream>>>(partS, 160, 64, bn_g, bn_b, W + oAG, W + oBG, nullptr, 1.f / Gn);
  krenorm<<<160, 256, 0, stream>>>(pos_tab, W + oRP, nullptr, RPB, Gn);
  krenorm<<<160, 256, 0, stream>>>(go_tab, W + oRGO, nullptr, nullptr, Pn);
  krenorm<<<160, 256, 0, stream>>>(bg_tab, W + oRBG, nullptr, nullptr, Pn);
  ksmallmat<<<1, 256, 0, stream>>>(mlp_W + 8192, sg_W, 0.2f, mlp_b + 128, sg_b, nullptr, 0.2f,
                                   W + oM, 64, W + oCvec);
  ksmallmat<<<1, 256, 0, stream>>>(mlp_W, sg_W + 4096, 1.f, nullptr, nullptr, nullptr, 0.f,
                                   W + oM1, 128, nullptr);
  ksmallmat<<<1, 256, 0, stream>>>(mlp_W, sg_W + 8192, 1.f, mlp_b, sg_b + 64, sg_b + 128, 1.f,
                                   W + oM1 + 64, 128, W + oCcP);
  // Q = relu(AG*RG+BG) @ Mw^T + Cvec  (fp32, added per-row by the fused t1 gather)
  mfgemm<64, 64, true, false, false, false, true, false><<<PTILES, 256, 0, stream>>>(
      RGB, mlp_W + 8192, W + oCvec, W + oAG, W + oBG, nullptr, (u16*)(W + oQ), nullptr, nullptr, Gn);
  // PMB = RP @ M^T  (bf16, the gather table for fused t1; pad rows are zeros)
  mfgemm<64, 64, false, false, false, false, false, false><<<PTILES, 256, 0, stream>>>(
      RPB, W + oM, W + oZERO, nullptr, nullptr, nullptr, (u16*)(W + oPM), nullptr, nullptr, Gn);

  // --- go graph ---
  kzero<<<(5001 + 255) / 256, 256, 0, stream>>>((float*)go_cnt, 5001);
  khist<<<(EGG + 255) / 256, 256, 0, stream>>>(ei_go + EGG, go_cnt, go_ticket, EGG);
  kscan1<<<5, 256, 0, stream>>>(go_cnt, sbsum, Pn);
  kscan2<<<1, 256, 0, stream>>>(sbsum, 5, go_cnt + Pn);
  kscan3<<<5, 256, 0, stream>>>(go_cnt, sbsum, Pn);
  kfillt<<<(EGG + 255) / 256, 256, 0, stream>>>(ei_go, ei_go + EGG, w_go, go_cnt, go_ticket, go_pack, EGG);
  kdinvrow<<<(Pn + 255) / 256, 256, 0, stream>>>(go_cnt, go_pack, W + oDGO, Pn);
  kgather<<<512, 256, 0, stream>>>(go_cnt, go_pack, W + oDGO, W + oRGO, pgi, 128, 0, Pn);

  // --- bg graph ---
  kzero<<<(5001 + 255) / 256, 256, 0, stream>>>((float*)bg_cnt, 5001);
  khist<<<(EGG + 255) / 256, 256, 0, stream>>>(ei_bg + EGG, bg_cnt, bg_ticket, EGG);
  kscan1<<<5, 256, 0, stream>>>(bg_cnt, sbsum, Pn);
  kscan2<<<1, 256, 0, stream>>>(sbsum, 5, bg_cnt + Pn);
  kscan3<<<5, 256, 0, stream>>>(bg_cnt, sbsum, Pn);
  kfillt<<<(EGG + 255) / 256, 256, 0, stream>>>(ei_bg, ei_bg + EGG, w_bg, bg_cnt, bg_ticket, bg_pack, EGG);
  kdinvrow<<<(Pn + 255) / 256, 256, 0, stream>>>(bg_cnt, bg_pack, W + oDBG, Pn);
  kgather<<<512, 256, 0, stream>>>(bg_cnt, bg_pack, W + oDBG, W + oRBG, pgi, 128, 64, Pn);

  // --- pert path (MFMA, bf16) ---
  mfgemm<128, 64, false, false, false, true, false, false><<<PTILES, 256, 0, stream>>>(
      pgi, W + oM1, W + oCcP, nullptr, nullptr, nullptr, (u16*)(W + oM1B), partS, nullptr, Pn);
  kredfin<<<1, 1024, 0, stream>>>(partS, PTILES, 64, mlp_g, mlp_bt, W + oAP1, W + oBP1, nullptr, 1.f / Pn);
  mfgemm<64, 64, true, false, false, true, false, false><<<PTILES, 256, 0, stream>>>(
      (u16*)(W + oM1B), mlp_W + 4096, mlp_b + 64, W + oAP1, W + oBP1, nullptr,
      (u16*)(W + oM2B), partS, nullptr, Pn);
  kredfin<<<1, 1024, 0, stream>>>(partS, PTILES, 64, mlp_g + 64, mlp_bt + 64, W + oAP2, W + oBP2, nullptr, 1.f / Pn);
  kemb<<<1, 256, 0, stream>>>((u16*)(W + oM2B), W + oAP2, W + oBP2, pert_idx,
                              mlp_W + 16384, mlp_b + 256, mlp_g + 256, mlp_bt + 256, W + oEMB);

  // --- co graph: LDS counting-sort CSR build ---
  kpsort<<<256, 256, 0, stream>>>(ei_co, ei_co + ECO, w_co, co_stg, Cg, Lg);
  ksumT<<<3, 256, 0, stream>>>(Cg, Tbk);
  kpscan<<<1, 256, 0, stream>>>(Tbk, bbase, co_off + Nn);
  kpcsr2<<<NBK, 256, 0, stream>>>(bbase, Cg, Lg, co_stg, co_off, co_pack, W + oDEG);

  // --- fused gather+t1 (8-lane-group): t1 -> buf0 (bf16), partial stats ---
  kgt2<<<2048, 256, 0, stream>>>(co_off, co_pack, W + oDEG, (const uint4*)(W + oPM),
                                 (const float4*)(W + oQ), (u16*)buf0, partS);
  kredfin<<<1, 1024, 0, stream>>>(partS, 2048, 64, mlp_g + 128, mlp_bt + 128, W + oA1, W + oB1, nullptr, 1.f / Nn);

  // --- main N pipeline: t1(buf0) -> t2(buf1) -> r1(buf0) -> r2(buf1) ---
  mfgemm<64, 64, true, false, false, true, false, true><<<NTILES, 256, 0, stream>>>(
      (const u16*)buf0, mlp_W + 12288, mlp_b + 192, W + oA1, W + oB1, nullptr,
      (u16*)buf1, partS, partB, Nn);
  kredfin<<<1, 1024, 0, stream>>>(partS, NTILES, 64, mlp_g + 192, mlp_bt + 192, W + oA2, W + oB2, W + oS2, 1.f / Nn);
  kredB<<<32, 64, 0, stream>>>(partB, W + oE2);
  kfinS3e2<<<1, 256, 0, stream>>>(W + oS2, bn_g + 64, bn_b + 64, W + oA2, W + oB2, W + oEMB,
                                  W + oE2, W + oAvec, W + oE2);
  mfgemm<64, 128, true, true, false, true, false, false><<<NTILES, 256, 0, stream>>>(
      (const u16*)buf1, rec_W1, rec_b1, W + oAvec, W + oE2, nullptr, (u16*)buf0, partS, nullptr, Nn);
  kredfin<<<2, 1024, 0, stream>>>(partS, NTILES, 128, rec_g1, rec_bt1, W + oA4, W + oB4, nullptr, 1.f / Nn);
  mfgemm<128, 64, true, false, false, true, false, false><<<NTILES, 256, 0, stream>>>(
      (const u16*)buf0, rec_W2, rec_b2, W + oA4, W + oB4, nullptr, (u16*)buf1, partS, nullptr, Nn);
  kredfin<<<1, 1024, 0, stream>>>(partS, NTILES, 64, rec_g2, rec_bt2, W + oA5, W + oB5, nullptr, 1.f / Nn);
  k13_kernel<<<(Nn * 16 + 255) / 256, 256, 0, stream>>>((const u16*)buf1, W + oA5, W + oB5, indv_w1, indv_b1,
                                                        W + oW1, Nn);
  // cross-gene state
  kinitcg<<<8, 256, 0, stream>>>(cg_b1, W + oCGRAW);
  kcg1s<<<(Gn + 63) / 64, 256, 0, stream>>>(W + oW1, cg_W1, W + oCGRAW);
  kcg2<<<1, 256, 0, stream>>>(W + oCGRAW, cg_g1, cg_bt1, cg_W2, cg_b2, cg_g2, cg_bt2, W + oCG2);
  kfinal<<<(Gn + 63) / 64, 256, 0, stream>>>(W + oW1, W + oCG2, indv_w2, indv_b2, x, (float*)d_out);
}

// Round 11
// 704.986 us; speedup vs baseline: 1.1227x; 1.0652x over previous
//
#include <hip/hip_runtime.h>

typedef unsigned int u32;
typedef unsigned short u16;

// Problem constants (fixed by the reference)
constexpr int Gn  = 5000;     // genes
constexpr int Bn  = 32;       // batch graphs
constexpr int Pn  = 5000;     // perts
constexpr int Nn  = Bn * Gn;  // 160000
constexpr int ECO = 1600000;
constexpr int EGG = 100000;
constexpr int NTILES = Nn / 128;  // 1250, exact
constexpr int PTILES = 40;        // 5120 padded rows / 128
constexpr int NBK = 625;          // co dst-buckets (dst>>8), 625*256 == 160000 exactly
constexpr int EPB2 = ECO / 256;   // 6250 edges per sort block (exact)
constexpr int NBE = (EGG + 255) / 256;  // 391 blocks per small-graph edge pass

// ---- workspace layout (float offsets) ----
constexpr int oS2 = 128;     // reduced S2 raw sums (needed by kfinS3e2)
constexpr int oZERO = 1536;  // stays zero (bias)
constexpr int oA1 = 2048, oB1 = 2112, oA2 = 2176, oB2 = 2240;
constexpr int oA4 = 2304, oB4 = 2432;            // 128 each
constexpr int oA5 = 2560, oB5 = 2624;
constexpr int oAG = 2688, oBG = 2752;
constexpr int oAP1 = 2816, oBP1 = 2880, oAP2 = 2944, oBP2 = 3008;
constexpr int oAvec = 3072, oCvec = 3136, oCcP = 3200;
constexpr int oM  = 4096, oM1 = 8192;            // oM1: concatenated [M1|M2] 64x128
constexpr int oE2 = 16384, oEMB = 18432, oCGRAW = 20480, oCG2 = 22528;
constexpr int oRG  = 24576;
constexpr int oRP  = oRG  + Gn * 64;
constexpr int oQ   = oRP  + Gn * 64;
constexpr int oRGO = oQ   + Gn * 64;
constexpr int oRBG = oRGO + Pn * 64;
constexpr int oPM  = oRBG + Pn * 64;   // PMB bf16 [5120][64] (in 1.28MB fp32-sized slot)
constexpr int oABG = oPM + Pn * 64;
constexpr int oM1B = oABG + Pn * 64;
constexpr int oM2B = oM1B + Pn * 64;
constexpr int oDGO = oM2B + Pn * 64;
constexpr int oDBG = oDGO + Pn;
constexpr int oDEG = oDBG + Pn;
constexpr int oW1  = oDEG + Nn;
constexpr int oBUF0 = oW1 + Nn;
constexpr int oBUF1 = oBUF0 + Nn * 64;
constexpr size_t WS_FLOATS = (size_t)oBUF1 + (size_t)Nn * 64;  // ~95 MB

__device__ inline u16 f2bf(float f) {
  u32 u = __float_as_uint(f);
  u = (u + 0x7fffu + ((u >> 16) & 1u)) >> 16;
  return (u16)u;
}
__device__ inline float bflo(u32 v) { return __uint_as_float(v << 16); }
__device__ inline float bfhi(u32 v) { return __uint_as_float(v & 0xffff0000u); }
__device__ inline float bf2f(u16 v) { return __uint_as_float((u32)v << 16); }

typedef __attribute__((ext_vector_type(8))) short short8v;  // 8 bf16 (4 VGPRs)
typedef __attribute__((ext_vector_type(4))) float f32x4;    // MFMA accumulator

// zero up to 4 disjoint ranges in one launch (kills 3 extra dispatches)
__global__ __launch_bounds__(256) void kzero4(float* p0, int n0, float* p1, int n1,
                                              float* p2, int n2, float* p3, int n3) {
  int i = blockIdx.x * 256 + threadIdx.x;
  if (i < n0) p0[i] = 0.f;
  if (i < n1) p1[i] = 0.f;
  if (i < n2) p2[i] = 0.f;
  if (i < n3) p3[i] = 0.f;
}
__global__ __launch_bounds__(256) void kzero2(int* a, int* b, int n) {
  int i = blockIdx.x * 256 + threadIdx.x;
  if (i < n) { a[i] = 0; b[i] = 0; }
}

// merged 4-table row renorm (all tables are 5000x64); seg = blockIdx/160.
// seg0 also emits per-block column-stat partials (for the gene-tab BN).
__global__ __launch_bounds__(256) void krenorm4(const float* __restrict__ in0, const float* __restrict__ in1,
                                                const float* __restrict__ in2, const float* __restrict__ in3,
                                                float* __restrict__ o0, float* __restrict__ o1,
                                                float* __restrict__ o2, float* __restrict__ o3,
                                                u16* __restrict__ ob0, u16* __restrict__ ob1,
                                                float* __restrict__ partial) {
  int seg = blockIdx.x / 160, blk = blockIdx.x % 160;
  const float* in = seg == 0 ? in0 : seg == 1 ? in1 : seg == 2 ? in2 : in3;
  float* out = seg == 0 ? o0 : seg == 1 ? o1 : seg == 2 ? o2 : o3;
  u16* outb = seg == 0 ? ob0 : seg == 1 ? ob1 : nullptr;
  int lane = threadIdx.x & 63, wvv = threadIdx.x >> 6;
  int gw = blk * 4 + wvv, nw = 640;
  float ps = 0.f, pq = 0.f;
  for (int r = gw; r < 5000; r += nw) {
    float v = in[r * 64 + lane];
    float sq = v * v;
    for (int off = 32; off; off >>= 1) sq += __shfl_xor(sq, off, 64);
    float nn = sqrtf(sq);
    float s = fminf(1.f, 1.f / fmaxf(nn, 1e-12f));
    float o = v * s;
    out[r * 64 + lane] = o;
    if (outb) outb[r * 64 + lane] = f2bf(o);
    ps += o; pq += o * o;
  }
  if (seg != 0) return;
  __shared__ float red[4][64], red2[4][64];
  red[wvv][lane] = ps; red2[wvv][lane] = pq;
  __syncthreads();
  if (wvv == 0) {
    float s = red[0][lane] + red[1][lane] + red[2][lane] + red[3][lane];
    float q = red2[0][lane] + red2[1][lane] + red2[2][lane] + red2[3][lane];
    partial[blk * 128 + lane] = s;
    partial[blk * 128 + 64 + lane] = q;
  }
}

// reduce per-block partials [nblk][2*outc] over blocks, then BN-finalize.
__global__ __launch_bounds__(1024) void kredfin(const float* __restrict__ part, int nblk, int outc,
                                                const float* __restrict__ g, const float* __restrict__ bt,
                                                float* __restrict__ a, float* __restrict__ b,
                                                float* __restrict__ outSQ, float invn) {
  __shared__ float rs[16][64], rq[16][64];
  int t = threadIdx.x, c = t & 63, seg = t >> 6;
  int col = blockIdx.x * 64 + c;
  int pitch = 2 * outc;
  float s = 0.f, q = 0.f;
  for (int r = seg; r < nblk; r += 16) {
    s += part[(size_t)r * pitch + col];
    q += part[(size_t)r * pitch + outc + col];
  }
  rs[seg][c] = s; rq[seg][c] = q;
  __syncthreads();
  if (t < 64) {
    int cc = blockIdx.x * 64 + t;
    float S = 0.f, Q = 0.f;
#pragma unroll
    for (int i = 0; i < 16; i++) { S += rs[i][t]; Q += rq[i][t]; }
    float mean = S * invn;
    float var = Q * invn - mean * mean;
    float sc = g[cc] * rsqrtf(var + 1e-5f);
    a[cc] = sc;
    b[cc] = bt[cc] - mean * sc;
    if (outSQ) { outSQ[cc] = S; outSQ[outc + cc] = Q; }
  }
}

// reduce per-block per-graph partials [NTILES][128] -> S3B[32][64]
__global__ __launch_bounds__(64) void kredB(const float* __restrict__ part, float* __restrict__ S3B) {
  int b = blockIdx.x;   // graph 0..31
  int c = threadIdx.x;  // col 0..63
  float s = 0.f;
  int r0 = (b == 0) ? 0 : ((b - 1) * Gn) / 128;
  int r1 = ((b + 1) * Gn + 127) / 128;
  if (r1 > NTILES) r1 = NTILES;
  for (int r = r0; r < r1; r++) {
    int bLo = (r * 128) / Gn;
    if (bLo == b) s += part[(size_t)r * 128 + c];
    else if (bLo + 1 == b) s += part[(size_t)r * 128 + 64 + c];
  }
  S3B[b * 64 + c] = s;
}

// Mout[i*mpitch+j] = alpha * (A @ Bm)[i][j]; optional cvec = bias + beta * A @ (bv1+bv2)
__global__ __launch_bounds__(256) void ksmallmat(const float* __restrict__ A, const float* __restrict__ Bm,
                                                 float alpha, const float* __restrict__ bias,
                                                 const float* __restrict__ bv1, const float* __restrict__ bv2,
                                                 float beta, float* __restrict__ Mout, int mpitch,
                                                 float* __restrict__ cvec) {
  __shared__ float As[4096], Bs[4096];
  int t = threadIdx.x;
  for (int m = 0; m < 16; m++) { As[m * 256 + t] = A[m * 256 + t]; Bs[m * 256 + t] = Bm[m * 256 + t]; }
  __syncthreads();
  int j = t & 63, ig = t >> 6;
  for (int ii = 0; ii < 16; ii++) {
    int i = ig * 16 + ii;
    float acc = 0.f;
    for (int k = 0; k < 64; k++) acc += As[i * 64 + k] * Bs[k * 64 + j];
    Mout[i * mpitch + j] = alpha * acc;
  }
  if (cvec && t < 64) {
    float acc = bias ? bias[t] : 0.f;
    for (int k = 0; k < 64; k++) {
      float bb = (bv1 ? bv1[k] : 0.f) + (bv2 ? bv2[k] : 0.f);
      acc += beta * As[t * 64 + k] * bb;
    }
    cvec[t] = acc;
  }
}

// ===== merged go+bg small-graph CSR build (blockIdx split halves dispatch count) =====
__global__ __launch_bounds__(256) void khist2(const int* __restrict__ dA, int* __restrict__ cA, int* __restrict__ tA,
                                              const int* __restrict__ dB, int* __restrict__ cB, int* __restrict__ tB,
                                              int E, int nbe) {
  int sel = blockIdx.x >= nbe;
  int blk = sel ? blockIdx.x - nbe : blockIdx.x;
  const int* dst = sel ? dB : dA;
  int* cnt = sel ? cB : cA;
  int* tick = sel ? tB : tA;
  int e = blk * 256 + threadIdx.x;
  if (e < E) tick[e] = atomicAdd(&cnt[dst[e]], 1);
}

__global__ __launch_bounds__(256) void kscan1m(const int* __restrict__ cA, const int* __restrict__ cB,
                                               int* __restrict__ bsA, int* __restrict__ bsB, int n, int nblk) {
  __shared__ int sh[256];
  int sel = blockIdx.x >= nblk;
  int b = sel ? blockIdx.x - nblk : blockIdx.x;
  const int* cnt = sel ? cB : cA;
  int* bsum = sel ? bsB : bsA;
  int t = threadIdx.x;
  int base = b * 1024 + t * 4;
  int s = 0;
#pragma unroll
  for (int j = 0; j < 4; j++) { int i = base + j; if (i < n) s += cnt[i]; }
  sh[t] = s; __syncthreads();
  for (int d = 128; d; d >>= 1) { if (t < d) sh[t] += sh[t + d]; __syncthreads(); }
  if (t == 0) bsum[b] = sh[0];
}

// segmented dual exclusive scan: lanes 0-127 scan A's nb block sums, 128-255 B's
__global__ __launch_bounds__(256) void kscan2m(int* __restrict__ bsA, int* __restrict__ bsB, int nb,
                                               int* __restrict__ totA, int* __restrict__ totB) {
  __shared__ int sh[256];
  int t = threadIdx.x;
  int sel = t >> 7, lt = t & 127;
  int* bsum = sel ? bsB : bsA;
  int v = (lt < nb) ? bsum[lt] : 0;
  sh[t] = v;
  __syncthreads();
  for (int d = 1; d < 128; d <<= 1) {
    int u = (lt >= d) ? sh[t - d] : 0;
    __syncthreads();
    sh[t] += u;
    __syncthreads();
  }
  if (lt < nb) bsum[lt] = sh[t] - v;  // exclusive
  if (lt == nb - 1) *(sel ? totB : totA) = sh[t];
}

__global__ __launch_bounds__(256) void kscan3m(int* __restrict__ cA, int* __restrict__ cB,
                                               const int* __restrict__ bsA, const int* __restrict__ bsB,
                                               int n, int nblk) {
  __shared__ int sh[256];
  int sel = blockIdx.x >= nblk;
  int b = sel ? blockIdx.x - nblk : blockIdx.x;
  int* cnt = sel ? cB : cA;
  const int* bsum = sel ? bsB : bsA;
  int t = threadIdx.x;
  int base = b * 1024 + t * 4;
  int c0 = (base + 0 < n) ? cnt[base + 0] : 0;
  int c1 = (base + 1 < n) ? cnt[base + 1] : 0;
  int c2 = (base + 2 < n) ? cnt[base + 2] : 0;
  int c3 = (base + 3 < n) ? cnt[base + 3] : 0;
  int tot = c0 + c1 + c2 + c3;
  sh[t] = tot; __syncthreads();
  for (int d = 1; d < 256; d <<= 1) {
    int v = (t >= d) ? sh[t - d] : 0;
    __syncthreads();
    sh[t] += v;
    __syncthreads();
  }
  int excl = sh[t] - tot + bsum[b];
  if (base + 0 < n) cnt[base + 0] = excl;
  if (base + 1 < n) cnt[base + 1] = excl + c0;
  if (base + 2 < n) cnt[base + 2] = excl + c0 + c1;
  if (base + 3 < n) cnt[base + 3] = excl + c0 + c1 + c2;
}

__global__ __launch_bounds__(256) void kfilltm(const int* __restrict__ sA, const int* __restrict__ dA,
                                               const float* __restrict__ wA, const int* __restrict__ oA,
                                               const int* __restrict__ tA, float2* __restrict__ pA,
                                               const int* __restrict__ sB, const int* __restrict__ dB,
                                               const float* __restrict__ wB, const int* __restrict__ oB,
                                               const int* __restrict__ tB, float2* __restrict__ pB,
                                               int E, int nbe) {
  int sel = blockIdx.x >= nbe;
  int blk = sel ? blockIdx.x - nbe : blockIdx.x;
  const int* src = sel ? sB : sA;
  const int* dst = sel ? dB : dA;
  const float* w = sel ? wB : wA;
  const int* off = sel ? oB : oA;
  const int* tick = sel ? tB : tA;
  float2* pack = sel ? pB : pA;
  int e = blk * 256 + threadIdx.x;
  if (e >= E) return;
  int d = dst[e];
  pack[off[d] + tick[e]] = make_float2(w[e], __int_as_float(src[e]));
}

__global__ __launch_bounds__(256) void kdinvrowm(const int* __restrict__ oA, const float2* __restrict__ pA,
                                                 float* __restrict__ vA, const int* __restrict__ oB,
                                                 const float2* __restrict__ pB, float* __restrict__ vB,
                                                 int n, int nbe) {
  int sel = blockIdx.x >= nbe;
  int blk = sel ? blockIdx.x - nbe : blockIdx.x;
  const int* off = sel ? oB : oA;
  const float2* pack = sel ? pB : pA;
  float* dinv = sel ? vB : vA;
  int i = blk * 256 + threadIdx.x;
  if (i >= n) return;
  int b0 = off[i], b1 = off[i + 1];
  float s = 1.f;
  for (int j = b0; j < b1; j++) s += pack[j].x;
  dinv[i] = rsqrtf(s);
}

// merged go+bg gather into pgi (go cols 0-63, bg cols 64-127)
__global__ __launch_bounds__(256) void kgatherm(const int* __restrict__ oA, const float2* __restrict__ pA,
                                                const float* __restrict__ vA, const float* __restrict__ tA,
                                                const int* __restrict__ oB, const float2* __restrict__ pB,
                                                const float* __restrict__ vB, const float* __restrict__ tB,
                                                u16* __restrict__ aggb, int n, int halfBlocks) {
  int sel = blockIdx.x >= halfBlocks;
  int blk = sel ? blockIdx.x - halfBlocks : blockIdx.x;
  const int* off = sel ? oB : oA;
  const float2* pack = sel ? pB : pA;
  const float* dinv = sel ? vB : vA;
  const float* tab = sel ? tB : tA;
  int coff = sel ? 64 : 0;
  int lane = threadIdx.x & 63;
  int wvv = blk * 4 + (threadIdx.x >> 6);
  int nw = halfBlocks * 4;
  for (int i = wvv; i < n; i += nw) {
    int b0 = off[i], b1 = off[i + 1];
    float di = dinv[i];
    float acc = di * tab[(i % Gn) * 64 + lane];
    for (int base = b0; base < b1; base += 64) {
      int m = b1 - base; if (m > 64) m = 64;
      float cj = 0.f; int idxj = 0;
      if (lane < m) {
        float2 p = pack[base + lane];
        int s = __float_as_int(p.y) & 0x3FFFF;
        cj = p.x * dinv[s];
        idxj = (s % Gn) * 64;
      }
      int j = 0;
      for (; j + 1 < m; j += 2) {
        float c0 = __shfl(cj, j, 64);     int i0 = __shfl(idxj, j, 64);
        float c1 = __shfl(cj, j + 1, 64); int i1 = __shfl(idxj, j + 1, 64);
        float t0 = tab[i0 + lane];
        float t1 = tab[i1 + lane];
        acc = fmaf(c0, t0, acc);
        acc = fmaf(c1, t1, acc);
      }
      if (j < m) {
        float c0 = __shfl(cj, j, 64); int i0 = __shfl(idxj, j, 64);
        acc = fmaf(c0, tab[i0 + lane], acc);
      }
    }
    acc *= di;
    aggb[(size_t)i * 128 + coff + lane] = f2bf(acc);
  }
}

// ===== co-CSR build v2: per-block LDS counting sort, fully streaming writes =====
__global__ __launch_bounds__(256) void kpsort(const int* __restrict__ src, const int* __restrict__ dst,
                                              const float* __restrict__ w, float2* __restrict__ stg,
                                              int* __restrict__ Cg, int* __restrict__ Lg) {
  __shared__ int cnt[NBK];
  __shared__ int loff[NBK];
  __shared__ int cur[NBK];
  __shared__ int ssc[256];
  __shared__ float2 sbuf[EPB2];
  int t = threadIdx.x;
  int e0 = blockIdx.x * EPB2;
  for (int i = t; i < NBK; i += 256) cnt[i] = 0;
  __syncthreads();
  for (int e = e0 + t; e < e0 + EPB2; e += 256) atomicAdd(&cnt[dst[e] >> 8], 1);
  __syncthreads();
  int i0 = t * 3;
  int c3[3];
  int s = 0;
#pragma unroll
  for (int j = 0; j < 3; j++) { int i = i0 + j; c3[j] = (i < NBK) ? cnt[i] : 0; s += c3[j]; }
  ssc[t] = s;
  __syncthreads();
  for (int d = 1; d < 256; d <<= 1) {
    int u = (t >= d) ? ssc[t - d] : 0;
    __syncthreads();
    ssc[t] += u;
    __syncthreads();
  }
  int base = ssc[t] - s;
#pragma unroll
  for (int j = 0; j < 3; j++) {
    int i = i0 + j;
    if (i < NBK) { loff[i] = base; cur[i] = base; }
    base += c3[j];
  }
  __syncthreads();
  for (int e = e0 + t; e < e0 + EPB2; e += 256) {
    int d = dst[e];
    int pos = atomicAdd(&cur[d >> 8], 1);
    sbuf[pos] = make_float2(w[e], __int_as_float(src[e] | ((d & 255) << 18)));
  }
  __syncthreads();
  for (int i = t; i < EPB2; i += 256) stg[(size_t)e0 + i] = sbuf[i];
  for (int i = t; i < NBK; i += 256) {
    Cg[blockIdx.x * NBK + i] = cnt[i];
    Lg[blockIdx.x * NBK + i] = loff[i];
  }
}

// column-sum C over blocks -> bucket totals T
__global__ __launch_bounds__(256) void ksumT(const int* __restrict__ Cg, int* __restrict__ T) {
  int bk = blockIdx.x * 256 + threadIdx.x;
  if (bk >= NBK) return;
  int s = 0;
  for (int blk = 0; blk < 256; blk++) s += Cg[blk * NBK + bk];
  T[bk] = s;
}

// single-block exclusive scan of NBK bucket totals -> bbase; total -> off[Nn]
__global__ __launch_bounds__(256) void kpscan(const int* __restrict__ bcnt, int* __restrict__ bbase,
                                              int* __restrict__ offN) {
  __shared__ int sh[256];
  int t = threadIdx.x;
  int i0 = t * 3;
  int c[3];
  int s = 0;
#pragma unroll
  for (int j = 0; j < 3; j++) { int i = i0 + j; c[j] = (i < NBK) ? bcnt[i] : 0; s += c[j]; }
  sh[t] = s;
  __syncthreads();
  for (int d = 1; d < 256; d <<= 1) {
    int u = (t >= d) ? sh[t - d] : 0;
    __syncthreads();
    sh[t] += u;
    __syncthreads();
  }
  int base = sh[t] - s;
#pragma unroll
  for (int j = 0; j < 3; j++) {
    int i = i0 + j;
    if (i < NBK) bbase[i] = base;
    base += c[j];
  }
  if (t == 255) { bbase[NBK] = base; *offN = base; }
}

// one block per bucket: gather 256 block-segments into LDS, row-hist/scan -> off, dinv;
// LDS-cursor scatter into pack (writes confined to the bucket's contiguous ~20KB range)
__global__ __launch_bounds__(256) void kpcsr2(const int* __restrict__ bbase, const int* __restrict__ Cg,
                                              const int* __restrict__ Lg, const float2* __restrict__ stg,
                                              int* __restrict__ off, float2* __restrict__ pack,
                                              float* __restrict__ dinv) {
  constexpr int CAP = 4096;  // mean 2560, sigma ~51 -> 30-sigma headroom
  __shared__ float2 ebuf[CAP];
  __shared__ int rh[256];
  __shared__ int sc2[256];
  __shared__ float ws[256];
  __shared__ int nEs;
  int bk = blockIdx.x, t = threadIdx.x;
  int myC = Cg[t * NBK + bk];
  int myL = Lg[t * NBK + bk];
  sc2[t] = myC;
  __syncthreads();
  for (int d = 1; d < 256; d <<= 1) {
    int u = (t >= d) ? sc2[t - d] : 0;
    __syncthreads();
    sc2[t] += u;
    __syncthreads();
  }
  int myO = sc2[t] - myC;
  if (t == 255) nEs = sc2[255];
  rh[t] = 0; ws[t] = 0.f;
  __syncthreads();
  int nE = nEs;
  {
    const float2* sp = &stg[(size_t)t * EPB2 + myL];
    for (int i = 0; i < myC; i++) ebuf[myO + i] = sp[i];
  }
  __syncthreads();
  for (int i = t; i < nE; i += 256) {
    float2 p = ebuf[i];
    int r = (__float_as_int(p.y) >> 18) & 255;
    atomicAdd(&rh[r], 1);
    atomicAdd(&ws[r], p.x);
  }
  __syncthreads();
  int cnt = rh[t];
  sc2[t] = cnt;
  __syncthreads();
  for (int d = 1; d < 256; d <<= 1) {
    int u = (t >= d) ? sc2[t - d] : 0;
    __syncthreads();
    sc2[t] += u;
    __syncthreads();
  }
  int gpos = bbase[bk] + sc2[t] - cnt;
  int grow = (bk << 8) + t;  // 625*256 == 160000: always valid
  off[grow] = gpos;
  dinv[grow] = rsqrtf(1.f + ws[t]);
  rh[t] = gpos;  // cursor
  __syncthreads();
  for (int i = t; i < nE; i += 256) {
    float2 p = ebuf[i];
    int r = (__float_as_int(p.y) >> 18) & 255;
    int pos = atomicAdd(&rh[r], 1);
    pack[pos] = p;
  }
}

// ===== fused co-gather + t1, v3: 8-lane groups, TWO rows per group (R10 post-mortem:
// nothing saturated at 1 row/group -> latency-bound; double the independent
// pack->dinv->shuffle->PMB chains in flight). Rows i0+grp and i0+8+grp.
// t1[i] = di*(di*PMB[i%Gn] + sum coef*PMB[s%Gn]) + Q[i%Gn]
__global__ __launch_bounds__(256) void kgt3(const int* __restrict__ off, const float2* __restrict__ pack,
                                            const float* __restrict__ dinv, const uint4* __restrict__ PMB,
                                            const float4* __restrict__ Q4, u16* __restrict__ Ybf,
                                            float* __restrict__ partS) {
  __shared__ float sstat[128];
  int t = threadIdx.x;
  int lane = t & 63, wvv = t >> 6;
  int grp = lane >> 3, le = lane & 7;
  for (int idx = t; idx < 128; idx += 256) sstat[idx] = 0.f;
  __syncthreads();
  float sS[8], sQ[8];
#pragma unroll
  for (int j = 0; j < 8; j++) { sS[j] = 0.f; sQ[j] = 0.f; }
  int base0 = (blockIdx.x * 4 + wvv) * 16;
  int stride = gridDim.x * 64;
  for (int i0 = base0; i0 < Nn; i0 += stride) {
    int iA = i0 + grp, iB = i0 + 8 + grp;   // Nn % 64 == 0 -> both valid
    int gA = iA % Gn, gB = iB % Gn;
    int a0 = off[iA], a1 = off[iA + 1];
    int b0 = off[iB], b1 = off[iB + 1];
    float diA = dinv[iA], diB = dinv[iB];
    float accA[8], accB[8];
    {
      uint4 tA = PMB[gA * 8 + le];
      uint4 tB = PMB[gB * 8 + le];
      accA[0] = diA * bflo(tA.x); accA[1] = diA * bfhi(tA.x);
      accA[2] = diA * bflo(tA.y); accA[3] = diA * bfhi(tA.y);
      accA[4] = diA * bflo(tA.z); accA[5] = diA * bfhi(tA.z);
      accA[6] = diA * bflo(tA.w); accA[7] = diA * bfhi(tA.w);
      accB[0] = diB * bflo(tB.x); accB[1] = diB * bfhi(tB.x);
      accB[2] = diB * bflo(tB.y); accB[3] = diB * bfhi(tB.y);
      accB[4] = diB * bflo(tB.z); accB[5] = diB * bfhi(tB.z);
      accB[6] = diB * bflo(tB.w); accB[7] = diB * bfhi(tB.w);
    }
    int curA = a0, curB = b0;
    while (curA < a1 || curB < b1) {
      int mA = a1 - curA; mA = mA > 8 ? 8 : (mA < 0 ? 0 : mA);
      int mB = b1 - curB; mB = mB > 8 ? 8 : (mB < 0 ? 0 : mB);
      float cjA = 0.f, cjB = 0.f; int ixA = 0, ixB = 0;
      if (le < mA) {
        float2 p = pack[curA + le];
        int s = __float_as_int(p.y) & 0x3FFFF;
        cjA = p.x * dinv[s];
        ixA = s % Gn;
      }
      if (le < mB) {
        float2 p = pack[curB + le];
        int s = __float_as_int(p.y) & 0x3FFFF;
        cjB = p.x * dinv[s];
        ixB = s % Gn;
      }
#pragma unroll
      for (int e = 0; e < 8; e++) {
        float cA = __shfl(cjA, grp * 8 + e, 64); int xA = __shfl(ixA, grp * 8 + e, 64);
        float cB = __shfl(cjB, grp * 8 + e, 64); int xB = __shfl(ixB, grp * 8 + e, 64);
        if (e < mA) {
          uint4 tv = PMB[xA * 8 + le];
          accA[0] = fmaf(cA, bflo(tv.x), accA[0]); accA[1] = fmaf(cA, bfhi(tv.x), accA[1]);
          accA[2] = fmaf(cA, bflo(tv.y), accA[2]); accA[3] = fmaf(cA, bfhi(tv.y), accA[3]);
          accA[4] = fmaf(cA, bflo(tv.z), accA[4]); accA[5] = fmaf(cA, bfhi(tv.z), accA[5]);
          accA[6] = fmaf(cA, bflo(tv.w), accA[6]); accA[7] = fmaf(cA, bfhi(tv.w), accA[7]);
        }
        if (e < mB) {
          uint4 tv = PMB[xB * 8 + le];
          accB[0] = fmaf(cB, bflo(tv.x), accB[0]); accB[1] = fmaf(cB, bfhi(tv.x), accB[1]);
          accB[2] = fmaf(cB, bflo(tv.y), accB[2]); accB[3] = fmaf(cB, bfhi(tv.y), accB[3]);
          accB[4] = fmaf(cB, bflo(tv.z), accB[4]); accB[5] = fmaf(cB, bfhi(tv.z), accB[5]);
          accB[6] = fmaf(cB, bflo(tv.w), accB[6]); accB[7] = fmaf(cB, bfhi(tv.w), accB[7]);
        }
      }
      curA += mA; curB += mB;
    }
    {
      float4 q0 = Q4[gA * 16 + le * 2];
      float4 q1 = Q4[gA * 16 + le * 2 + 1];
      float v[8];
      v[0] = fmaf(diA, accA[0], q0.x); v[1] = fmaf(diA, accA[1], q0.y);
      v[2] = fmaf(diA, accA[2], q0.z); v[3] = fmaf(diA, accA[3], q0.w);
      v[4] = fmaf(diA, accA[4], q1.x); v[5] = fmaf(diA, accA[5], q1.y);
      v[6] = fmaf(diA, accA[6], q1.z); v[7] = fmaf(diA, accA[7], q1.w);
#pragma unroll
      for (int j = 0; j < 8; j++) { sS[j] += v[j]; sQ[j] += v[j] * v[j]; }
      uint4 o;
      o.x = (u32)f2bf(v[0]) | ((u32)f2bf(v[1]) << 16);
      o.y = (u32)f2bf(v[2]) | ((u32)f2bf(v[3]) << 16);
      o.z = (u32)f2bf(v[4]) | ((u32)f2bf(v[5]) << 16);
      o.w = (u32)f2bf(v[6]) | ((u32)f2bf(v[7]) << 16);
      *(uint4*)&Ybf[(size_t)iA * 64 + le * 8] = o;
    }
    {
      float4 q0 = Q4[gB * 16 + le * 2];
      float4 q1 = Q4[gB * 16 + le * 2 + 1];
      float v[8];
      v[0] = fmaf(diB, accB[0], q0.x); v[1] = fmaf(diB, accB[1], q0.y);
      v[2] = fmaf(diB, accB[2], q0.z); v[3] = fmaf(diB, accB[3], q0.w);
      v[4] = fmaf(diB, accB[4], q1.x); v[5] = fmaf(diB, accB[5], q1.y);
      v[6] = fmaf(diB, accB[6], q1.z); v[7] = fmaf(diB, accB[7], q1.w);
#pragma unroll
      for (int j = 0; j < 8; j++) { sS[j] += v[j]; sQ[j] += v[j] * v[j]; }
      uint4 o;
      o.x = (u32)f2bf(v[0]) | ((u32)f2bf(v[1]) << 16);
      o.y = (u32)f2bf(v[2]) | ((u32)f2bf(v[3]) << 16);
      o.z = (u32)f2bf(v[4]) | ((u32)f2bf(v[5]) << 16);
      o.w = (u32)f2bf(v[6]) | ((u32)f2bf(v[7]) << 16);
      *(uint4*)&Ybf[(size_t)iB * 64 + le * 8] = o;
    }
  }
#pragma unroll
  for (int j = 0; j < 8; j++) {
    atomicAdd(&sstat[le * 8 + j], sS[j]);
    atomicAdd(&sstat[64 + le * 8 + j], sQ[j]);
  }
  __syncthreads();
  for (int idx = t; idx < 128; idx += 256) partS[(size_t)blockIdx.x * 128 + idx] = sstat[idx];
}

// ===================== MFMA GEMM (one 128-row tile per block) =====================
template <int K, int OUTC, bool PRE, bool EB, bool PERG, bool STATS, bool OUTF32, bool STATB>
__global__ __launch_bounds__(256, 3) void mfgemm(
    const u16* __restrict__ Xb, const float* __restrict__ Wg, const float* __restrict__ bias,
    const float* __restrict__ pa, const float* __restrict__ pb,
    const float* __restrict__ perg, u16* __restrict__ Ybf, float* __restrict__ stats,
    float* __restrict__ statB, int rows) {
  constexpr int NT  = OUTC / 16;   // 16-col output tiles per wave-row
  constexpr int KH  = K / 32;      // MFMA K-steps
  constexpr int SLK = K / 8;       // 16B slots per input row
  constexpr int SLO = OUTC / 8;    // 16B slots per output row
  constexpr int XROW = (K > OUTC ? K : OUTC) * 2;  // bytes per xs row (shared in/out stage)
  __shared__ __align__(16) unsigned char xsb[128 * XROW];
  __shared__ __align__(16) unsigned char wsb[OUTC * K * 2];
  __shared__ float sstat[STATS ? 2 * OUTC : 1];
  __shared__ float sstatB[STATB ? 128 : 1];
  int t = threadIdx.x;
  int l = t & 63, w = t >> 6, lrow = l & 15, lk = l >> 4;
  int R0 = blockIdx.x * 128;

  // ---- stage weights: fp32 -> bf16, swizzled ----
  for (int idx = t; idx < OUTC * SLK; idx += 256) {
    int oc = idx / SLK, s8 = idx % SLK;
    const float* wp = &Wg[oc * K + s8 * 8];
    uint4 o;
    o.x = (u32)f2bf(wp[0]) | ((u32)f2bf(wp[1]) << 16);
    o.y = (u32)f2bf(wp[2]) | ((u32)f2bf(wp[3]) << 16);
    o.z = (u32)f2bf(wp[4]) | ((u32)f2bf(wp[5]) << 16);
    o.w = (u32)f2bf(wp[6]) | ((u32)f2bf(wp[7]) << 16);
    *(uint4*)&wsb[oc * (2 * K) + ((s8 * 16) ^ ((oc & 7) << 4))] = o;
  }
  if constexpr (STATS) for (int idx = t; idx < 2 * OUTC; idx += 256) sstat[idx] = 0.f;
  if constexpr (STATB) for (int idx = t; idx < 128; idx += 256) sstatB[idx] = 0.f;

  // ---- stage input tile: coalesced 16B loads ----
#pragma unroll
  for (int m = 0; m < SLK / 2; m++) {
    int f = m * 256 + t;
    int r = f / SLK, s8 = f % SLK;
    uint4 u = *(const uint4*)&Xb[(size_t)(R0 + r) * K + s8 * 8];
    if constexpr (PRE) {
      int c0 = s8 * 8;
      float4 A0 = *(const float4*)&pa[c0];
      float4 A1 = *(const float4*)&pa[c0 + 4];
      const float* pbb = EB ? &pb[((R0 + r) / Gn) * 64] : pb;
      float4 B0 = *(const float4*)&pbb[c0];
      float4 B1 = *(const float4*)&pbb[c0 + 4];
      float v0 = fmaxf(fmaf(A0.x, bflo(u.x), B0.x), 0.f);
      float v1 = fmaxf(fmaf(A0.y, bfhi(u.x), B0.y), 0.f);
      float v2 = fmaxf(fmaf(A0.z, bflo(u.y), B0.z), 0.f);
      float v3 = fmaxf(fmaf(A0.w, bfhi(u.y), B0.w), 0.f);
      float v4 = fmaxf(fmaf(A1.x, bflo(u.z), B1.x), 0.f);
      float v5 = fmaxf(fmaf(A1.y, bfhi(u.z), B1.y), 0.f);
      float v6 = fmaxf(fmaf(A1.z, bflo(u.w), B1.z), 0.f);
      float v7 = fmaxf(fmaf(A1.w, bfhi(u.w), B1.w), 0.f);
      u.x = (u32)f2bf(v0) | ((u32)f2bf(v1) << 16);
      u.y = (u32)f2bf(v2) | ((u32)f2bf(v3) << 16);
      u.z = (u32)f2bf(v4) | ((u32)f2bf(v5) << 16);
      u.w = (u32)f2bf(v6) | ((u32)f2bf(v7) << 16);
    }
    *(uint4*)&xsb[r * XROW + ((s8 * 16) ^ ((r & 7) << 4))] = u;
  }
  float bcol[NT];
#pragma unroll
  for (int nt = 0; nt < NT; nt++) bcol[nt] = bias[nt * 16 + lrow];
  __syncthreads();

  // ---- MFMA: wave w owns rows w*32..w*32+31, all OUTC cols ----
  short8v af[2][KH];
#pragma unroll
  for (int rt = 0; rt < 2; rt++)
#pragma unroll
    for (int h = 0; h < KH; h++) {
      int row = w * 32 + rt * 16 + lrow;
      af[rt][h] = *(const short8v*)&xsb[row * XROW + ((h * 64 + lk * 16) ^ ((row & 7) << 4))];
    }
  f32x4 acc[2][NT];
#pragma unroll
  for (int rt = 0; rt < 2; rt++)
#pragma unroll
    for (int nt = 0; nt < NT; nt++) {
      f32x4 z = {0.f, 0.f, 0.f, 0.f};
      acc[rt][nt] = z;
    }
#pragma unroll
  for (int nt = 0; nt < NT; nt++) {
    int brow = nt * 16 + lrow;
#pragma unroll
    for (int h = 0; h < KH; h++) {
      short8v bfr = *(const short8v*)&wsb[brow * (2 * K) + ((h * 64 + lk * 16) ^ ((brow & 7) << 4))];
      acc[0][nt] = __builtin_amdgcn_mfma_f32_16x16x32_bf16(af[0][h], bfr, acc[0][nt], 0, 0, 0);
      acc[1][nt] = __builtin_amdgcn_mfma_f32_16x16x32_bf16(af[1][h], bfr, acc[1][nt], 0, 0, 0);
    }
  }
  __syncthreads();  // all xs reads done -> safe to reuse xs as output stage

  // ---- epilogue ----
  float sS[NT], sQ[NT], sB0[NT], sB1[NT];
#pragma unroll
  for (int nt = 0; nt < NT; nt++) { sS[nt] = 0.f; sQ[nt] = 0.f; sB0[nt] = 0.f; sB1[nt] = 0.f; }
  int hiStart = STATB ? (R0 / Gn + 1) * Gn : 0x7fffffff;
  float* Yf = (float*)Ybf;
#pragma unroll
  for (int rt = 0; rt < 2; rt++) {
#pragma unroll
    for (int r = 0; r < 4; r++) {
      int orow = w * 32 + rt * 16 + lk * 4 + r;
      int grow = R0 + orow;
      bool valid = grow < rows;
      int qoff = 0;
      if constexpr (PERG) qoff = (grow % Gn) * 64;
#pragma unroll
      for (int nt = 0; nt < NT; nt++) {
        float v = acc[rt][nt][r] + bcol[nt];
        if constexpr (PERG) v += perg[qoff + nt * 16 + lrow];
        if (valid) {
          if constexpr (STATS) { sS[nt] += v; sQ[nt] += v * v; }
          if constexpr (STATB) { if (grow >= hiStart) sB1[nt] += v; else sB0[nt] += v; }
        }
        if constexpr (OUTF32) {
          if (valid) Yf[(size_t)grow * OUTC + nt * 16 + lrow] = v;
        } else {
          *(u16*)&xsb[orow * (2 * OUTC) + ((2 * (nt * 16 + lrow)) ^ ((orow & 7) << 4))] = f2bf(v);
        }
      }
    }
  }
  if constexpr (STATS) {
#pragma unroll
    for (int nt = 0; nt < NT; nt++) {
      atomicAdd(&sstat[nt * 16 + lrow], sS[nt]);
      atomicAdd(&sstat[OUTC + nt * 16 + lrow], sQ[nt]);
    }
  }
  if constexpr (STATB) {
#pragma unroll
    for (int nt = 0; nt < NT; nt++) {
      atomicAdd(&sstatB[nt * 16 + lrow], sB0[nt]);
      atomicAdd(&sstatB[64 + nt * 16 + lrow], sB1[nt]);
    }
  }
  __syncthreads();

  if constexpr (!OUTF32) {
#pragma unroll
    for (int m = 0; m < SLO / 2; m++) {
      int f = m * 256 + t;
      int r = f / SLO, c8 = f % SLO;
      uint4 o = *(const uint4*)&xsb[r * (2 * OUTC) + ((16 * c8) ^ ((r & 7) << 4))];
      *(uint4*)&Ybf[(size_t)(R0 + r) * OUTC + c8 * 8] = o;
    }
  }
  if constexpr (STATS)
    for (int idx = t; idx < 2 * OUTC; idx += 256) stats[(size_t)blockIdx.x * 2 * OUTC + idx] = sstat[idx];
  if constexpr (STATB)
    for (int idx = t; idx < 128; idx += 256) statB[(size_t)blockIdx.x * 128 + idx] = sstatB[idx];
}

// finalize S3 analytically; Avec = a3*a2, e2[b] = a3*(b2+emb[b]) + b3.
__global__ __launch_bounds__(256) void kfinS3e2(const float* __restrict__ S2, const float* __restrict__ g,
                                                const float* __restrict__ bt, const float* __restrict__ a2,
                                                const float* __restrict__ b2, const float* __restrict__ emb,
                                                const float* __restrict__ S3B,
                                                float* __restrict__ Avec, float* __restrict__ e2) {
  __shared__ float a3s[64], b3s[64];
  int t = threadIdx.x;
  if (t < 64) {
    float a2c = a2[t], b2c = b2[t];
    float su = 0.f, sxc = 0.f, sc2 = 0.f;
    for (int b = 0; b < Bn; b++) {
      float cb = b2c + emb[b * 64 + t];
      float sb = S3B[b * 64 + t];
      su += cb;
      sxc += cb * sb;
      sc2 += cb * cb;
    }
    float Su = a2c * S2[t] + (float)Gn * su;
    float Sq = a2c * a2c * S2[64 + t] + 2.f * a2c * sxc + (float)Gn * sc2;
    float mean = Su * (1.f / Nn);
    float var = Sq * (1.f / Nn) - mean * mean;
    float sc = g[t] * rsqrtf(var + 1e-5f);
    float sh = bt[t] - mean * sc;
    a3s[t] = sc; b3s[t] = sh;
    Avec[t] = sc * a2c;
  }
  __syncthreads();
  for (int idx = t; idx < 2048; idx += 256) {
    int c = idx & 63;
    e2[idx] = a3s[c] * (b2[c] + emb[idx]) + b3s[c];
  }
}

// w1[i] = dot(a5*R2(bf16)+b5, indv_w1[i%G]) + indv_b1[i%G]
__global__ __launch_bounds__(256) void k13_kernel(const u16* __restrict__ R2, const float* __restrict__ a5,
                                                  const float* __restrict__ b5, const float* __restrict__ iw1,
                                                  const float* __restrict__ ib1, float* __restrict__ w1out,
                                                  int rows) {
  int t = blockIdx.x * 256 + threadIdx.x;
  int i = t >> 4, j = t & 15;
  if (i >= rows) return;
  int g = i % Gn;
  uint2 u = *(const uint2*)&R2[(size_t)i * 64 + j * 4];
  float rx = bflo(u.x), ry = bfhi(u.x), rz = bflo(u.y), rw = bfhi(u.y);
  float4 a = ((const float4*)a5)[j];
  float4 b = ((const float4*)b5)[j];
  float4 w = ((const float4*)iw1)[g * 16 + j];
  float p = (a.x * rx + b.x) * w.x + (a.y * ry + b.y) * w.y +
            (a.z * rz + b.z) * w.z + (a.w * rw + b.w) * w.w;
  for (int off = 8; off; off >>= 1) p += __shfl_xor(p, off, 64);
  if (j == 0) w1out[i] = p + ib1[g];
}

// init cgraw with bias
__global__ __launch_bounds__(256) void kinitcg(const float* __restrict__ cgb1, float* __restrict__ cgraw) {
  int idx = blockIdx.x * 256 + threadIdx.x;
  if (idx < Bn * 64) cgraw[idx] = cgb1[idx & 63];
}

// split-K GEMM: cgraw[b][col] += sum_{k in chunk} w1[b][k]*cgW1[col][k]
__global__ __launch_bounds__(256) void kcg1s(const float* __restrict__ w1, const float* __restrict__ cgW1,
                                             float* __restrict__ cgraw) {
  __shared__ float w1s[64 * 36];
  __shared__ float cgs[64 * 65];
  int t = threadIdx.x;
  int k0 = blockIdx.x * 64;
  int kmax = Gn - k0; if (kmax > 64) kmax = 64;
  for (int idx = t; idx < 2048; idx += 256) {
    int row = idx >> 6, k = idx & 63;
    w1s[k * 36 + row] = (k < kmax) ? w1[row * Gn + k0 + k] : 0.f;
  }
  for (int idx = t; idx < 4096; idx += 256) {
    int col = idx >> 6, k = idx & 63;
    cgs[k * 65 + col] = (k < kmax) ? cgW1[col * Gn + k0 + k] : 0.f;
  }
  __syncthreads();
  int col = t & 63, rg = t >> 6;
  float acc[8];
#pragma unroll
  for (int i = 0; i < 8; i++) acc[i] = 0.f;
  for (int k = 0; k < 64; k++) {
    float wk = cgs[k * 65 + col];
    const float* wr = &w1s[k * 36 + rg * 8];
    float4 r0 = *(const float4*)wr;
    float4 r1 = *(const float4*)(wr + 4);
    acc[0] = fmaf(r0.x, wk, acc[0]);
    acc[1] = fmaf(r0.y, wk, acc[1]);
    acc[2] = fmaf(r0.z, wk, acc[2]);
    acc[3] = fmaf(r0.w, wk, acc[3]);
    acc[4] = fmaf(r1.x, wk, acc[4]);
    acc[5] = fmaf(r1.y, wk, acc[5]);
    acc[6] = fmaf(r1.z, wk, acc[6]);
    acc[7] = fmaf(r1.w, wk, acc[7]);
  }
#pragma unroll
  for (int i = 0; i < 8; i++) atomicAdd(&cgraw[(rg * 8 + i) * 64 + col], acc[i]);
}

// single-block: cg2 = bn2(relu(bn1(cgraw)) @ W2^T + b2)   (BN over 32 rows)
__global__ __launch_bounds__(256) void kcg2(const float* __restrict__ cgraw, const float* __restrict__ g1,
                                            const float* __restrict__ bt1, const float* __restrict__ W2,
                                            const float* __restrict__ b2, const float* __restrict__ g2,
                                            const float* __restrict__ bt2, float* __restrict__ cg2out) {
  int t = threadIdx.x, c = t & 63, bg = t >> 6;
  __shared__ float hmid[2048], sred[4][64], qred[4][64], asc[64], bsh[64];
  float y[8];
  float ps = 0.f, pq = 0.f;
  for (int jb = 0; jb < 8; jb++) {
    int b = bg * 8 + jb;
    float v = cgraw[b * 64 + c];
    y[jb] = v; ps += v; pq += v * v;
  }
  sred[bg][c] = ps; qred[bg][c] = pq;
  __syncthreads();
  if (t < 64) {
    float s = sred[0][t] + sred[1][t] + sred[2][t] + sred[3][t];
    float q = qred[0][t] + qred[1][t] + qred[2][t] + qred[3][t];
    float mean = s * (1.f / 32.f), var = q * (1.f / 32.f) - mean * mean;
    float sc = g1[t] * rsqrtf(var + 1e-5f);
    asc[t] = sc; bsh[t] = bt1[t] - mean * sc;
  }
  __syncthreads();
  for (int jb = 0; jb < 8; jb++) { int b = bg * 8 + jb; hmid[b * 64 + c] = fmaxf(asc[c] * y[jb] + bsh[c], 0.f); }
  __syncthreads();
  ps = 0.f; pq = 0.f;
  for (int jb = 0; jb < 8; jb++) {
    int b = bg * 8 + jb;
    float a = b2[c];
    for (int k = 0; k < 64; k++) a += hmid[b * 64 + k] * W2[c * 64 + k];
    y[jb] = a; ps += a; pq += a * a;
  }
  sred[bg][c] = ps; qred[bg][c] = pq;
  __syncthreads();
  if (t < 64) {
    float s = sred[0][t] + sred[1][t] + sred[2][t] + sred[3][t];
    float q = qred[0][t] + qred[1][t] + qred[2][t] + qred[3][t];
    float mean = s * (1.f / 32.f), var = q * (1.f / 32.f) - mean * mean;
    float sc = g2[t] * rsqrtf(var + 1e-5f);
    asc[t] = sc; bsh[t] = bt2[t] - mean * sc;
  }
  __syncthreads();
  for (int jb = 0; jb < 8; jb++) { int b = bg * 8 + jb; cg2out[b * 64 + c] = asc[c] * y[jb] + bsh[c]; }
}

// single-block: emb = mlp3(pglob[pert_idx]) with BN over 32 rows (m2 is bf16)
__global__ __launch_bounds__(256) void kemb(const u16* __restrict__ m2, const float* __restrict__ aP2,
                                            const float* __restrict__ bP2, const int* __restrict__ pidx,
                                            const float* __restrict__ Wm, const float* __restrict__ bv,
                                            const float* __restrict__ gg, const float* __restrict__ btv,
                                            float* __restrict__ emb) {
  int t = threadIdx.x, c = t & 63, bg = t >> 6;
  __shared__ float xin[2048], hmid[2048], sred[4][64], qred[4][64], asc[64], bsh[64];
  for (int idx = t; idx < 2048; idx += 256) {
    int b = idx >> 6, cc = idx & 63;
    xin[idx] = aP2[cc] * bf2f(m2[(size_t)pidx[b] * 64 + cc]) + bP2[cc];
  }
  __syncthreads();
  float y[8];
  float ps = 0.f, pq = 0.f;
  for (int jb = 0; jb < 8; jb++) {
    int b = bg * 8 + jb;
    float a = bv[c];
    for (int k = 0; k < 64; k++) a += xin[b * 64 + k] * Wm[c * 64 + k];
    y[jb] = a; ps += a; pq += a * a;
  }
  sred[bg][c] = ps; qred[bg][c] = pq;
  __syncthreads();
  if (t < 64) {
    float s = sred[0][t] + sred[1][t] + sred[2][t] + sred[3][t];
    float q = qred[0][t] + qred[1][t] + qred[2][t] + qred[3][t];
    float mean = s * (1.f / 32.f), var = q * (1.f / 32.f) - mean * mean;
    float sc = gg[t] * rsqrtf(var + 1e-5f);
    asc[t] = sc; bsh[t] = btv[t] - mean * sc;
  }
  __syncthreads();
  for (int jb = 0; jb < 8; jb++) { int b = bg * 8 + jb; hmid[b * 64 + c] = fmaxf(asc[c] * y[jb] + bsh[c], 0.f); }
  __syncthreads();
  ps = 0.f; pq = 0.f;
  for (int jb = 0; jb < 8; jb++) {
    int b = bg * 8 + jb;
    float a = bv[64 + c];
    for (int k = 0; k < 64; k++) a += hmid[b * 64 + k] * Wm[4096 + c * 64 + k];
    y[jb] = a; ps += a; pq += a * a;
  }
  sred[bg][c] = ps; qred[bg][c] = pq;
  __syncthreads();
  if (t < 64) {
    float s = sred[0][t] + sred[1][t] + sred[2][t] + sred[3][t];
    float q = qred[0][t] + qred[1][t] + qred[2][t] + qred[3][t];
    float mean = s * (1.f / 32.f), var = q * (1.f / 32.f) - mean * mean;
    float sc = gg[64 + t] * rsqrtf(var + 1e-5f);
    asc[t] = sc; bsh[t] = btv[64 + t] - mean * sc;
  }
  __syncthreads();
  for (int jb = 0; jb < 8; jb++) { int b = bg * 8 + jb; emb[b * 64 + c] = asc[c] * y[jb] + bsh[c]; }
}

// final: out[b][g] = w1*iw2[g][0] + dot(cg2[b], iw2[g][1:65]) + ib2[g] + x[b][g]
__global__ __launch_bounds__(256) void kfinal(const float* __restrict__ w1, const float* __restrict__ cg2,
                                              const float* __restrict__ iw2, const float* __restrict__ ib2,
                                              const float* __restrict__ x, float* __restrict__ out) {
  __shared__ float iws[64 * 65], cgs[2048];
  int t = threadIdx.x;
  int g0 = blockIdx.x * 64;
  for (int idx = t; idx < 64 * 65; idx += 256) {
    int gi = g0 * 65 + idx;
    iws[idx] = (gi < Gn * 65) ? iw2[gi] : 0.f;
  }
  for (int idx = t; idx < 2048; idx += 256) cgs[idx] = cg2[idx];
  __syncthreads();
  int gl = t & 63, bg = t >> 6;
  int g = g0 + gl;
  if (g >= Gn) return;
  float bias = ib2[g];
  for (int jb = 0; jb < 8; jb++) {
    int b = bg * 8 + jb;
    float acc = w1[b * Gn + g] * iws[gl * 65] + bias;
    for (int k = 0; k < 64; k++) acc += cgs[b * 64 + k] * iws[gl * 65 + 1 + k];
    out[b * Gn + g] = acc + x[b * Gn + g];
  }
}

extern "C" void kernel_launch(void* const* d_in, const int* in_sizes, int n_in,
                              void* d_out, int out_size, void* d_ws, size_t ws_size,
                              hipStream_t stream) {
  (void)in_sizes; (void)n_in; (void)out_size;
  if (ws_size < WS_FLOATS * sizeof(float)) return;

  const float* x        = (const float*)d_in[0];
  const int*   pert_idx = (const int*)d_in[1];
  const int*   ei_co    = (const int*)d_in[2];
  const float* w_co     = (const float*)d_in[3];
  const int*   ei_go    = (const int*)d_in[4];
  const float* w_go     = (const float*)d_in[5];
  const int*   ei_bg    = (const int*)d_in[6];
  const float* w_bg     = (const float*)d_in[7];
  const float* gene_tab = (const float*)d_in[8];
  const float* pos_tab  = (const float*)d_in[9];
  const float* go_tab   = (const float*)d_in[10];
  const float* bg_tab   = (const float*)d_in[11];
  const float* bn_g     = (const float*)d_in[12];
  const float* bn_b     = (const float*)d_in[13];
  const float* sg_W     = (const float*)d_in[14];
  const float* sg_b     = (const float*)d_in[15];
  const float* mlp_W    = (const float*)d_in[16];
  const float* mlp_b    = (const float*)d_in[17];
  const float* mlp_g    = (const float*)d_in[18];
  const float* mlp_bt   = (const float*)d_in[19];
  const float* rec_W1   = (const float*)d_in[20];
  const float* rec_b1   = (const float*)d_in[21];
  const float* rec_g1   = (const float*)d_in[22];
  const float* rec_bt1  = (const float*)d_in[23];
  const float* rec_W2   = (const float*)d_in[24];
  const float* rec_b2   = (const float*)d_in[25];
  const float* rec_g2   = (const float*)d_in[26];
  const float* rec_bt2  = (const float*)d_in[27];
  const float* indv_w1  = (const float*)d_in[28];
  const float* indv_b1  = (const float*)d_in[29];
  const float* cg_W1    = (const float*)d_in[30];
  const float* cg_b1    = (const float*)d_in[31];
  const float* cg_g1    = (const float*)d_in[32];
  const float* cg_bt1   = (const float*)d_in[33];
  const float* cg_W2    = (const float*)d_in[34];
  const float* cg_b2    = (const float*)d_in[35];
  const float* cg_g2    = (const float*)d_in[36];
  const float* cg_bt2   = (const float*)d_in[37];
  const float* indv_w2  = (const float*)d_in[38];
  const float* indv_b2  = (const float*)d_in[39];

  float* W = (float*)d_ws;
  float* buf0 = W + oBUF0;
  float* buf1 = W + oBUF1;

  // CSR scratch lives in buf1 lower region (consumed by kgt3 before t2 writes buf1)
  int*    co_off    = (int*)(buf1);                  // 160001
  int*    bbase     = (int*)(buf1 + 200000);         // 626
  int*    Tbk       = (int*)(buf1 + 202000);         // 625 bucket totals
  int*    sbsum     = (int*)(buf1 + 320128);         // go block sums; bg at +64
  float2* co_pack   = (float2*)(buf1 + 400000);      // 1.6M float2
  int*    go_cnt    = (int*)(buf1 + 3700000);
  float2* go_pack   = (float2*)(buf1 + 3720000);
  int*    bg_cnt    = (int*)(buf1 + 4000000);
  float2* bg_pack   = (float2*)(buf1 + 4020000);
  u16*    RPB       = (u16*)(buf1 + 4220000);        // [5120][64] bf16 renormed pos tab
  int*    Cg        = (int*)(buf1 + 4500000);        // [256][625] per-block bucket counts
  int*    Lg        = (int*)(buf1 + 4700000);        // [256][625] per-block local offsets
  int*    go_ticket = (int*)(buf1 + 6200000);
  int*    bg_ticket = (int*)(buf1 + 6400000);
  u16*    pgi       = (u16*)(buf1 + 6600000);        // [5120][128] bf16: go cols 0-63, bg 64-127
  u16*    RGB       = (u16*)(buf1 + 6800000);        // [5120][64] bf16 renormed gene tab
  float2* co_stg    = (float2*)(buf1 + 6963840);     // 1.6M float2 block-major sorted staging

  // stats partial buffers: buf1 upper region (dead co_stg space by the time they're used)
  float* partS = buf1 + 8000000;   // up to [2048][128]
  float* partB = buf1 + 8650000;   // [1250][128]

  // --- phase 0: zero pads + stats (one launch), renorm all 4 tables (one launch) ---
  kzero4<<<30, 256, 0, stream>>>(W, 2048,
                                 buf1 + 6800000 + 160000, 3840,    // RGB pad rows 5000..5119
                                 buf1 + 4220000 + 160000, 3840,    // RPB pad rows 5000..5119
                                 buf1 + 6600000 + 320000, 7680);   // pgi pad rows 5000..5119
  krenorm4<<<640, 256, 0, stream>>>(gene_tab, pos_tab, go_tab, bg_tab,
                                    W + oRG, W + oRP, W + oRGO, W + oRBG,
                                    RGB, RPB, partS);
  kredfin<<<1, 1024, 0, stream>>>(partS, 160, 64, bn_g, bn_b, W + oAG, W + oBG, nullptr, 1.f / Gn);
  ksmallmat<<<1, 256, 0, stream>>>(mlp_W + 8192, sg_W, 0.2f, mlp_b + 128, sg_b, nullptr, 0.2f,
                                   W + oM, 64, W + oCvec);
  ksmallmat<<<1, 256, 0, stream>>>(mlp_W, sg_W + 4096, 1.f, nullptr, nullptr, nullptr, 0.f,
                                   W + oM1, 128, nullptr);
  ksmallmat<<<1, 256, 0, stream>>>(mlp_W, sg_W + 8192, 1.f, mlp_b, sg_b + 64, sg_b + 128, 1.f,
                                   W + oM1 + 64, 128, W + oCcP);
  // Q = relu(AG*RG+BG) @ Mw^T + Cvec  (fp32, added per-row by the fused t1 gather)
  mfgemm<64, 64, true, false, false, false, true, false><<<PTILES, 256, 0, stream>>>(
      RGB, mlp_W + 8192, W + oCvec, W + oAG, W + oBG, nullptr, (u16*)(W + oQ), nullptr, nullptr, Gn);
  // PMB = RP @ M^T  (bf16, the gather table for fused t1; pad rows are zeros)
  mfgemm<64, 64, false, false, false, false, false, false><<<PTILES, 256, 0, stream>>>(
      RPB, W + oM, W + oZERO, nullptr, nullptr, nullptr, (u16*)(W + oPM), nullptr, nullptr, Gn);

  // --- go+bg graphs (merged dual-graph pipeline) ---
  kzero2<<<20, 256, 0, stream>>>(go_cnt, bg_cnt, 5001);
  khist2<<<2 * NBE, 256, 0, stream>>>(ei_go + EGG, go_cnt, go_ticket,
                                      ei_bg + EGG, bg_cnt, bg_ticket, EGG, NBE);
  kscan1m<<<10, 256, 0, stream>>>(go_cnt, bg_cnt, sbsum, sbsum + 64, Pn, 5);
  kscan2m<<<1, 256, 0, stream>>>(sbsum, sbsum + 64, 5, go_cnt + Pn, bg_cnt + Pn);
  kscan3m<<<10, 256, 0, stream>>>(go_cnt, bg_cnt, sbsum, sbsum + 64, Pn, 5);
  kfilltm<<<2 * NBE, 256, 0, stream>>>(ei_go, ei_go + EGG, w_go, go_cnt, go_ticket, go_pack,
                                       ei_bg, ei_bg + EGG, w_bg, bg_cnt, bg_ticket, bg_pack, EGG, NBE);
  kdinvrowm<<<40, 256, 0, stream>>>(go_cnt, go_pack, W + oDGO, bg_cnt, bg_pack, W + oDBG, Pn, 20);
  kgatherm<<<1024, 256, 0, stream>>>(go_cnt, go_pack, W + oDGO, W + oRGO,
                                     bg_cnt, bg_pack, W + oDBG, W + oRBG, pgi, Pn, 512);

  // --- pert path (MFMA, bf16) ---
  mfgemm<128, 64, false, false, false, true, false, false><<<PTILES, 256, 0, stream>>>(
      pgi, W + oM1, W + oCcP, nullptr, nullptr, nullptr, (u16*)(W + oM1B), partS, nullptr, Pn);
  kredfin<<<1, 1024, 0, stream>>>(partS, PTILES, 64, mlp_g, mlp_bt, W + oAP1, W + oBP1, nullptr, 1.f / Pn);
  mfgemm<64, 64, true, false, false, true, false, false><<<PTILES, 256, 0, stream>>>(
      (u16*)(W + oM1B), mlp_W + 4096, mlp_b + 64, W + oAP1, W + oBP1, nullptr,
      (u16*)(W + oM2B), partS, nullptr, Pn);
  kredfin<<<1, 1024, 0, stream>>>(partS, PTILES, 64, mlp_g + 64, mlp_bt + 64, W + oAP2, W + oBP2, nullptr, 1.f / Pn);
  kemb<<<1, 256, 0, stream>>>((u16*)(W + oM2B), W + oAP2, W + oBP2, pert_idx,
                              mlp_W + 16384, mlp_b + 256, mlp_g + 256, mlp_bt + 256, W + oEMB);

  // --- co graph: LDS counting-sort CSR build ---
  kpsort<<<256, 256, 0, stream>>>(ei_co, ei_co + ECO, w_co, co_stg, Cg, Lg);
  ksumT<<<3, 256, 0, stream>>>(Cg, Tbk);
  kpscan<<<1, 256, 0, stream>>>(Tbk, bbase, co_off + Nn);
  kpcsr2<<<NBK, 256, 0, stream>>>(bbase, Cg, Lg, co_stg, co_off, co_pack, W + oDEG);

  // --- fused gather+t1 (2 rows per 8-lane group): t1 -> buf0 (bf16), partial stats ---
  kgt3<<<2048, 256, 0, stream>>>(co_off, co_pack, W + oDEG, (const uint4*)(W + oPM),
                                 (const float4*)(W + oQ), (u16*)buf0, partS);
  kredfin<<<1, 1024, 0, stream>>>(partS, 2048, 64, mlp_g + 128, mlp_bt + 128, W + oA1, W + oB1, nullptr, 1.f / Nn);

  // --- main N pipeline: t1(buf0) -> t2(buf1) -> r1(buf0) -> r2(buf1) ---
  mfgemm<64, 64, true, false, false, true, false, true><<<NTILES, 256, 0, stream>>>(
      (const u16*)buf0, mlp_W + 12288, mlp_b + 192, W + oA1, W + oB1, nullptr,
      (u16*)buf1, partS, partB, Nn);
  kredfin<<<1, 1024, 0, stream>>>(partS, NTILES, 64, mlp_g + 192, mlp_bt + 192, W + oA2, W + oB2, W + oS2, 1.f / Nn);
  kredB<<<32, 64, 0, stream>>>(partB, W + oE2);
  kfinS3e2<<<1, 256, 0, stream>>>(W + oS2, bn_g + 64, bn_b + 64, W + oA2, W + oB2, W + oEMB,
                                  W + oE2, W + oAvec, W + oE2);
  mfgemm<64, 128, true, true, false, true, false, false><<<NTILES, 256, 0, stream>>>(
      (const u16*)buf1, rec_W1, rec_b1, W + oAvec, W + oE2, nullptr, (u16*)buf0, partS, nullptr, Nn);
  kredfin<<<2, 1024, 0, stream>>>(partS, NTILES, 128, rec_g1, rec_bt1, W + oA4, W + oB4, nullptr, 1.f / Nn);
  mfgemm<128, 64, true, false, false, true, false, false><<<NTILES, 256, 0, stream>>>(
      (const u16*)buf0, rec_W2, rec_b2, W + oA4, W + oB4, nullptr, (u16*)buf1, partS, nullptr, Nn);
  kredfin<<<1, 1024, 0, stream>>>(partS, NTILES, 64, rec_g2, rec_bt2, W + oA5, W + oB5, nullptr, 1.f / Nn);
  k13_kernel<<<(Nn * 16 + 255) / 256, 256, 0, stream>>>((const u16*)buf1, W + oA5, W + oB5, indv_w1, indv_b1,
                                                        W + oW1, Nn);
  // cross-gene state
  kinitcg<<<8, 256, 0, stream>>>(cg_b1, W + oCGRAW);
  kcg1s<<<(Gn + 63) / 64, 256, 0, stream>>>(W + oW1, cg_W1, W + oCGRAW);
  kcg2<<<1, 256, 0, stream>>>(W + oCGRAW, cg_g1, cg_bt1, cg_W2, cg_b2, cg_g2, cg_bt2, W + oCG2);
  kfinal<<<(Gn + 63) / 64, 256, 0, stream>>>(W + oW1, W + oCG2, indv_w2, indv_b2, x, (float*)d_out);
}

// Round 13
// 687.711 us; speedup vs baseline: 1.1509x; 1.0251x over previous
//
#include <hip/hip_runtime.h>

typedef unsigned int u32;
typedef unsigned short u16;

// Problem constants (fixed by the reference)
constexpr int Gn  = 5000;     // genes
constexpr int Bn  = 32;       // batch graphs
constexpr int Pn  = 5000;     // perts
constexpr int Nn  = Bn * Gn;  // 160000
constexpr int ECO = 1600000;
constexpr int EGG = 100000;
constexpr int NTILES = Nn / 128;  // 1250, exact
constexpr int PTILES = 40;        // 5120 padded rows / 128
constexpr int NBK = 625;          // co dst-buckets (dst>>8), 625*256 == 160000 exactly
constexpr int EPB2 = ECO / 256;   // 6250 edges per sort block (exact)
constexpr int NBE = (EGG + 255) / 256;  // 391 blocks per small-graph edge pass

// ---- workspace layout (float offsets) ----
constexpr int oS2 = 128;     // reduced S2 raw sums (needed by kfinS3e2)
constexpr int oZERO = 1536;  // stays zero (bias)
constexpr int oA1 = 2048, oB1 = 2112, oA2 = 2176, oB2 = 2240;
constexpr int oA4 = 2304, oB4 = 2432;            // 128 each
constexpr int oA5 = 2560, oB5 = 2624;
constexpr int oAG = 2688, oBG = 2752;
constexpr int oAP1 = 2816, oBP1 = 2880, oAP2 = 2944, oBP2 = 3008;
constexpr int oAvec = 3072, oCvec = 3136, oCcP = 3200;
constexpr int oM  = 4096, oM1 = 8192;            // oM1: concatenated [M1|M2] 64x128
constexpr int oE2 = 16384, oEMB = 18432, oCGRAW = 20480, oCG2 = 22528;
constexpr int oRG  = 24576;
constexpr int oRP  = oRG  + Gn * 64;
constexpr int oQ   = oRP  + Gn * 64;
constexpr int oRGO = oQ   + Gn * 64;
constexpr int oRBG = oRGO + Pn * 64;
constexpr int oPM  = oRBG + Pn * 64;   // PM fp32 [Gn][64] (pad rows never written/read)
constexpr int oABG = oPM + Pn * 64;    // dead
constexpr int oM1B = oABG + Pn * 64;
constexpr int oM2B = oM1B + Pn * 64;
constexpr int oDGO = oM2B + Pn * 64;
constexpr int oDBG = oDGO + Pn;
constexpr int oDEG = oDBG + Pn;
constexpr int oW1  = oDEG + Nn;
constexpr int oBUF0 = oW1 + Nn;
constexpr int oBUF1 = oBUF0 + Nn * 64;
constexpr size_t WS_FLOATS = (size_t)oBUF1 + (size_t)Nn * 64;  // ~95 MB

__device__ inline u16 f2bf(float f) {
  u32 u = __float_as_uint(f);
  u = (u + 0x7fffu + ((u >> 16) & 1u)) >> 16;
  return (u16)u;
}
__device__ inline float bflo(u32 v) { return __uint_as_float(v << 16); }
__device__ inline float bfhi(u32 v) { return __uint_as_float(v & 0xffff0000u); }
__device__ inline float bf2f(u16 v) { return __uint_as_float((u32)v << 16); }

typedef __attribute__((ext_vector_type(8))) short short8v;  // 8 bf16 (4 VGPRs)
typedef __attribute__((ext_vector_type(4))) float f32x4;    // MFMA accumulator

// zero up to 4 disjoint ranges in one launch
__global__ __launch_bounds__(256) void kzero4(float* p0, int n0, float* p1, int n1,
                                              float* p2, int n2, float* p3, int n3) {
  int i = blockIdx.x * 256 + threadIdx.x;
  if (i < n0) p0[i] = 0.f;
  if (i < n1) p1[i] = 0.f;
  if (i < n2) p2[i] = 0.f;
  if (i < n3) p3[i] = 0.f;
}
__global__ __launch_bounds__(256) void kzero2(int* a, int* b, int n) {
  int i = blockIdx.x * 256 + threadIdx.x;
  if (i < n) { a[i] = 0; b[i] = 0; }
}

// merged 4-table row renorm (all tables are 5000x64); seg = blockIdx/160.
// seg0 also emits per-block column-stat partials (for the gene-tab BN).
__global__ __launch_bounds__(256) void krenorm4(const float* __restrict__ in0, const float* __restrict__ in1,
                                                const float* __restrict__ in2, const float* __restrict__ in3,
                                                float* __restrict__ o0, float* __restrict__ o1,
                                                float* __restrict__ o2, float* __restrict__ o3,
                                                u16* __restrict__ ob0, u16* __restrict__ ob1,
                                                float* __restrict__ partial) {
  int seg = blockIdx.x / 160, blk = blockIdx.x % 160;
  const float* in = seg == 0 ? in0 : seg == 1 ? in1 : seg == 2 ? in2 : in3;
  float* out = seg == 0 ? o0 : seg == 1 ? o1 : seg == 2 ? o2 : o3;
  u16* outb = seg == 0 ? ob0 : seg == 1 ? ob1 : nullptr;
  int lane = threadIdx.x & 63, wvv = threadIdx.x >> 6;
  int gw = blk * 4 + wvv, nw = 640;
  float ps = 0.f, pq = 0.f;
  for (int r = gw; r < 5000; r += nw) {
    float v = in[r * 64 + lane];
    float sq = v * v;
    for (int off = 32; off; off >>= 1) sq += __shfl_xor(sq, off, 64);
    float nn = sqrtf(sq);
    float s = fminf(1.f, 1.f / fmaxf(nn, 1e-12f));
    float o = v * s;
    out[r * 64 + lane] = o;
    if (outb) outb[r * 64 + lane] = f2bf(o);
    ps += o; pq += o * o;
  }
  if (seg != 0) return;
  __shared__ float red[4][64], red2[4][64];
  red[wvv][lane] = ps; red2[wvv][lane] = pq;
  __syncthreads();
  if (wvv == 0) {
    float s = red[0][lane] + red[1][lane] + red[2][lane] + red[3][lane];
    float q = red2[0][lane] + red2[1][lane] + red2[2][lane] + red2[3][lane];
    partial[blk * 128 + lane] = s;
    partial[blk * 128 + 64 + lane] = q;
  }
}

// reduce per-block partials [nblk][2*outc] over blocks, then BN-finalize.
__global__ __launch_bounds__(1024) void kredfin(const float* __restrict__ part, int nblk, int outc,
                                                const float* __restrict__ g, const float* __restrict__ bt,
                                                float* __restrict__ a, float* __restrict__ b,
                                                float* __restrict__ outSQ, float invn) {
  __shared__ float rs[16][64], rq[16][64];
  int t = threadIdx.x, c = t & 63, seg = t >> 6;
  int col = blockIdx.x * 64 + c;
  int pitch = 2 * outc;
  float s = 0.f, q = 0.f;
  for (int r = seg; r < nblk; r += 16) {
    s += part[(size_t)r * pitch + col];
    q += part[(size_t)r * pitch + outc + col];
  }
  rs[seg][c] = s; rq[seg][c] = q;
  __syncthreads();
  if (t < 64) {
    int cc = blockIdx.x * 64 + t;
    float S = 0.f, Q = 0.f;
#pragma unroll
    for (int i = 0; i < 16; i++) { S += rs[i][t]; Q += rq[i][t]; }
    float mean = S * invn;
    float var = Q * invn - mean * mean;
    float sc = g[cc] * rsqrtf(var + 1e-5f);
    a[cc] = sc;
    b[cc] = bt[cc] - mean * sc;
    if (outSQ) { outSQ[cc] = S; outSQ[outc + cc] = Q; }
  }
}

// reduce per-block per-graph partials [NTILES][128] -> S3B[32][64]
__global__ __launch_bounds__(64) void kredB(const float* __restrict__ part, float* __restrict__ S3B) {
  int b = blockIdx.x;   // graph 0..31
  int c = threadIdx.x;  // col 0..63
  float s = 0.f;
  int r0 = (b == 0) ? 0 : ((b - 1) * Gn) / 128;
  int r1 = ((b + 1) * Gn + 127) / 128;
  if (r1 > NTILES) r1 = NTILES;
  for (int r = r0; r < r1; r++) {
    int bLo = (r * 128) / Gn;
    if (bLo == b) s += part[(size_t)r * 128 + c];
    else if (bLo + 1 == b) s += part[(size_t)r * 128 + 64 + c];
  }
  S3B[b * 64 + c] = s;
}

// Mout[i*mpitch+j] = alpha * (A @ Bm)[i][j]; optional cvec = bias + beta * A @ (bv1+bv2)
__global__ __launch_bounds__(256) void ksmallmat(const float* __restrict__ A, const float* __restrict__ Bm,
                                                 float alpha, const float* __restrict__ bias,
                                                 const float* __restrict__ bv1, const float* __restrict__ bv2,
                                                 float beta, float* __restrict__ Mout, int mpitch,
                                                 float* __restrict__ cvec) {
  __shared__ float As[4096], Bs[4096];
  int t = threadIdx.x;
  for (int m = 0; m < 16; m++) { As[m * 256 + t] = A[m * 256 + t]; Bs[m * 256 + t] = Bm[m * 256 + t]; }
  __syncthreads();
  int j = t & 63, ig = t >> 6;
  for (int ii = 0; ii < 16; ii++) {
    int i = ig * 16 + ii;
    float acc = 0.f;
    for (int k = 0; k < 64; k++) acc += As[i * 64 + k] * Bs[k * 64 + j];
    Mout[i * mpitch + j] = alpha * acc;
  }
  if (cvec && t < 64) {
    float acc = bias ? bias[t] : 0.f;
    for (int k = 0; k < 64; k++) {
      float bb = (bv1 ? bv1[k] : 0.f) + (bv2 ? bv2[k] : 0.f);
      acc += beta * As[t * 64 + k] * bb;
    }
    cvec[t] = acc;
  }
}

// ===== merged go+bg small-graph CSR build =====
__global__ __launch_bounds__(256) void khist2(const int* __restrict__ dA, int* __restrict__ cA, int* __restrict__ tA,
                                              const int* __restrict__ dB, int* __restrict__ cB, int* __restrict__ tB,
                                              int E, int nbe) {
  int sel = blockIdx.x >= nbe;
  int blk = sel ? blockIdx.x - nbe : blockIdx.x;
  const int* dst = sel ? dB : dA;
  int* cnt = sel ? cB : cA;
  int* tick = sel ? tB : tA;
  int e = blk * 256 + threadIdx.x;
  if (e < E) tick[e] = atomicAdd(&cnt[dst[e]], 1);
}

__global__ __launch_bounds__(256) void kscan1m(const int* __restrict__ cA, const int* __restrict__ cB,
                                               int* __restrict__ bsA, int* __restrict__ bsB, int n, int nblk) {
  __shared__ int sh[256];
  int sel = blockIdx.x >= nblk;
  int b = sel ? blockIdx.x - nblk : blockIdx.x;
  const int* cnt = sel ? cB : cA;
  int* bsum = sel ? bsB : bsA;
  int t = threadIdx.x;
  int base = b * 1024 + t * 4;
  int s = 0;
#pragma unroll
  for (int j = 0; j < 4; j++) { int i = base + j; if (i < n) s += cnt[i]; }
  sh[t] = s; __syncthreads();
  for (int d = 128; d; d >>= 1) { if (t < d) sh[t] += sh[t + d]; __syncthreads(); }
  if (t == 0) bsum[b] = sh[0];
}

// segmented dual exclusive scan: lanes 0-127 scan A's nb block sums, 128-255 B's
__global__ __launch_bounds__(256) void kscan2m(int* __restrict__ bsA, int* __restrict__ bsB, int nb,
                                               int* __restrict__ totA, int* __restrict__ totB) {
  __shared__ int sh[256];
  int t = threadIdx.x;
  int sel = t >> 7, lt = t & 127;
  int* bsum = sel ? bsB : bsA;
  int v = (lt < nb) ? bsum[lt] : 0;
  sh[t] = v;
  __syncthreads();
  for (int d = 1; d < 128; d <<= 1) {
    int u = (lt >= d) ? sh[t - d] : 0;
    __syncthreads();
    sh[t] += u;
    __syncthreads();
  }
  if (lt < nb) bsum[lt] = sh[t] - v;  // exclusive
  if (lt == nb - 1) *(sel ? totB : totA) = sh[t];
}

__global__ __launch_bounds__(256) void kscan3m(int* __restrict__ cA, int* __restrict__ cB,
                                               const int* __restrict__ bsA, const int* __restrict__ bsB,
                                               int n, int nblk) {
  __shared__ int sh[256];
  int sel = blockIdx.x >= nblk;
  int b = sel ? blockIdx.x - nblk : blockIdx.x;
  int* cnt = sel ? cB : cA;
  const int* bsum = sel ? bsB : bsA;
  int t = threadIdx.x;
  int base = b * 1024 + t * 4;
  int c0 = (base + 0 < n) ? cnt[base + 0] : 0;
  int c1 = (base + 1 < n) ? cnt[base + 1] : 0;
  int c2 = (base + 2 < n) ? cnt[base + 2] : 0;
  int c3 = (base + 3 < n) ? cnt[base + 3] : 0;
  int tot = c0 + c1 + c2 + c3;
  sh[t] = tot; __syncthreads();
  for (int d = 1; d < 256; d <<= 1) {
    int v = (t >= d) ? sh[t - d] : 0;
    __syncthreads();
    sh[t] += v;
    __syncthreads();
  }
  int excl = sh[t] - tot + bsum[b];
  if (base + 0 < n) cnt[base + 0] = excl;
  if (base + 1 < n) cnt[base + 1] = excl + c0;
  if (base + 2 < n) cnt[base + 2] = excl + c0 + c1;
  if (base + 3 < n) cnt[base + 3] = excl + c0 + c1 + c2;
}

__global__ __launch_bounds__(256) void kfilltm(const int* __restrict__ sA, const int* __restrict__ dA,
                                               const float* __restrict__ wA, const int* __restrict__ oA,
                                               const int* __restrict__ tA, float2* __restrict__ pA,
                                               const int* __restrict__ sB, const int* __restrict__ dB,
                                               const float* __restrict__ wB, const int* __restrict__ oB,
                                               const int* __restrict__ tB, float2* __restrict__ pB,
                                               int E, int nbe) {
  int sel = blockIdx.x >= nbe;
  int blk = sel ? blockIdx.x - nbe : blockIdx.x;
  const int* src = sel ? sB : sA;
  const int* dst = sel ? dB : dA;
  const float* w = sel ? wB : wA;
  const int* off = sel ? oB : oA;
  const int* tick = sel ? tB : tA;
  float2* pack = sel ? pB : pA;
  int e = blk * 256 + threadIdx.x;
  if (e >= E) return;
  int d = dst[e];
  pack[off[d] + tick[e]] = make_float2(w[e], __int_as_float(src[e]));
}

__global__ __launch_bounds__(256) void kdinvrowm(const int* __restrict__ oA, const float2* __restrict__ pA,
                                                 float* __restrict__ vA, const int* __restrict__ oB,
                                                 const float2* __restrict__ pB, float* __restrict__ vB,
                                                 int n, int nbe) {
  int sel = blockIdx.x >= nbe;
  int blk = sel ? blockIdx.x - nbe : blockIdx.x;
  const int* off = sel ? oB : oA;
  const float2* pack = sel ? pB : pA;
  float* dinv = sel ? vB : vA;
  int i = blk * 256 + threadIdx.x;
  if (i >= n) return;
  int b0 = off[i], b1 = off[i + 1];
  float s = 1.f;
  for (int j = b0; j < b1; j++) s += pack[j].x;
  dinv[i] = rsqrtf(s);
}

// merged go+bg gather into pgi (go cols 0-63, bg cols 64-127)
__global__ __launch_bounds__(256) void kgatherm(const int* __restrict__ oA, const float2* __restrict__ pA,
                                                const float* __restrict__ vA, const float* __restrict__ tA,
                                                const int* __restrict__ oB, const float2* __restrict__ pB,
                                                const float* __restrict__ vB, const float* __restrict__ tB,
                                                u16* __restrict__ aggb, int n, int halfBlocks) {
  int sel = blockIdx.x >= halfBlocks;
  int blk = sel ? blockIdx.x - halfBlocks : blockIdx.x;
  const int* off = sel ? oB : oA;
  const float2* pack = sel ? pB : pA;
  const float* dinv = sel ? vB : vA;
  const float* tab = sel ? tB : tA;
  int coff = sel ? 64 : 0;
  int lane = threadIdx.x & 63;
  int wvv = blk * 4 + (threadIdx.x >> 6);
  int nw = halfBlocks * 4;
  for (int i = wvv; i < n; i += nw) {
    int b0 = off[i], b1 = off[i + 1];
    float di = dinv[i];
    float acc = di * tab[(i % Gn) * 64 + lane];
    for (int base = b0; base < b1; base += 64) {
      int m = b1 - base; if (m > 64) m = 64;
      float cj = 0.f; int idxj = 0;
      if (lane < m) {
        float2 p = pack[base + lane];
        int s = __float_as_int(p.y) & 0x3FFFF;
        cj = p.x * dinv[s];
        idxj = (s % Gn) * 64;
      }
      int j = 0;
      for (; j + 1 < m; j += 2) {
        float c0 = __shfl(cj, j, 64);     int i0 = __shfl(idxj, j, 64);
        float c1 = __shfl(cj, j + 1, 64); int i1 = __shfl(idxj, j + 1, 64);
        float t0 = tab[i0 + lane];
        float t1 = tab[i1 + lane];
        acc = fmaf(c0, t0, acc);
        acc = fmaf(c1, t1, acc);
      }
      if (j < m) {
        float c0 = __shfl(cj, j, 64); int i0 = __shfl(idxj, j, 64);
        acc = fmaf(c0, tab[i0 + lane], acc);
      }
    }
    acc *= di;
    aggb[(size_t)i * 128 + coff + lane] = f2bf(acc);
  }
}

// ===== co-CSR build v2: per-block LDS counting sort, fully streaming writes =====
__global__ __launch_bounds__(256) void kpsort(const int* __restrict__ src, const int* __restrict__ dst,
                                              const float* __restrict__ w, float2* __restrict__ stg,
                                              int* __restrict__ Cg, int* __restrict__ Lg) {
  __shared__ int cnt[NBK];
  __shared__ int loff[NBK];
  __shared__ int cur[NBK];
  __shared__ int ssc[256];
  __shared__ float2 sbuf[EPB2];
  int t = threadIdx.x;
  int e0 = blockIdx.x * EPB2;
  for (int i = t; i < NBK; i += 256) cnt[i] = 0;
  __syncthreads();
  for (int e = e0 + t; e < e0 + EPB2; e += 256) atomicAdd(&cnt[dst[e] >> 8], 1);
  __syncthreads();
  int i0 = t * 3;
  int c3[3];
  int s = 0;
#pragma unroll
  for (int j = 0; j < 3; j++) { int i = i0 + j; c3[j] = (i < NBK) ? cnt[i] : 0; s += c3[j]; }
  ssc[t] = s;
  __syncthreads();
  for (int d = 1; d < 256; d <<= 1) {
    int u = (t >= d) ? ssc[t - d] : 0;
    __syncthreads();
    ssc[t] += u;
    __syncthreads();
  }
  int base = ssc[t] - s;
#pragma unroll
  for (int j = 0; j < 3; j++) {
    int i = i0 + j;
    if (i < NBK) { loff[i] = base; cur[i] = base; }
    base += c3[j];
  }
  __syncthreads();
  for (int e = e0 + t; e < e0 + EPB2; e += 256) {
    int d = dst[e];
    int pos = atomicAdd(&cur[d >> 8], 1);
    sbuf[pos] = make_float2(w[e], __int_as_float(src[e] | ((d & 255) << 18)));
  }
  __syncthreads();
  for (int i = t; i < EPB2; i += 256) stg[(size_t)e0 + i] = sbuf[i];
  for (int i = t; i < NBK; i += 256) {
    Cg[blockIdx.x * NBK + i] = cnt[i];
    Lg[blockIdx.x * NBK + i] = loff[i];
  }
}

// column-sum C over blocks -> bucket totals T
__global__ __launch_bounds__(256) void ksumT(const int* __restrict__ Cg, int* __restrict__ T) {
  int bk = blockIdx.x * 256 + threadIdx.x;
  if (bk >= NBK) return;
  int s = 0;
  for (int blk = 0; blk < 256; blk++) s += Cg[blk * NBK + bk];
  T[bk] = s;
}

// single-block exclusive scan of NBK bucket totals -> bbase; total -> off[Nn]
__global__ __launch_bounds__(256) void kpscan(const int* __restrict__ bcnt, int* __restrict__ bbase,
                                              int* __restrict__ offN) {
  __shared__ int sh[256];
  int t = threadIdx.x;
  int i0 = t * 3;
  int c[3];
  int s = 0;
#pragma unroll
  for (int j = 0; j < 3; j++) { int i = i0 + j; c[j] = (i < NBK) ? bcnt[i] : 0; s += c[j]; }
  sh[t] = s;
  __syncthreads();
  for (int d = 1; d < 256; d <<= 1) {
    int u = (t >= d) ? sh[t - d] : 0;
    __syncthreads();
    sh[t] += u;
    __syncthreads();
  }
  int base = sh[t] - s;
#pragma unroll
  for (int j = 0; j < 3; j++) {
    int i = i0 + j;
    if (i < NBK) bbase[i] = base;
    base += c[j];
  }
  if (t == 255) { bbase[NBK] = base; *offN = base; }
}

// one block per bucket: gather 256 block-segments into LDS, row-hist/scan -> off, dinv;
// LDS-cursor scatter into pack (writes confined to the bucket's contiguous ~20KB range)
__global__ __launch_bounds__(256) void kpcsr2(const int* __restrict__ bbase, const int* __restrict__ Cg,
                                              const int* __restrict__ Lg, const float2* __restrict__ stg,
                                              int* __restrict__ off, float2* __restrict__ pack,
                                              float* __restrict__ dinv) {
  constexpr int CAP = 4096;  // mean 2560, sigma ~51 -> 30-sigma headroom
  __shared__ float2 ebuf[CAP];
  __shared__ int rh[256];
  __shared__ int sc2[256];
  __shared__ float ws[256];
  __shared__ int nEs;
  int bk = blockIdx.x, t = threadIdx.x;
  int myC = Cg[t * NBK + bk];
  int myL = Lg[t * NBK + bk];
  sc2[t] = myC;
  __syncthreads();
  for (int d = 1; d < 256; d <<= 1) {
    int u = (t >= d) ? sc2[t - d] : 0;
    __syncthreads();
    sc2[t] += u;
    __syncthreads();
  }
  int myO = sc2[t] - myC;
  if (t == 255) nEs = sc2[255];
  rh[t] = 0; ws[t] = 0.f;
  __syncthreads();
  int nE = nEs;
  {
    const float2* sp = &stg[(size_t)t * EPB2 + myL];
    for (int i = 0; i < myC; i++) ebuf[myO + i] = sp[i];
  }
  __syncthreads();
  for (int i = t; i < nE; i += 256) {
    float2 p = ebuf[i];
    int r = (__float_as_int(p.y) >> 18) & 255;
    atomicAdd(&rh[r], 1);
    atomicAdd(&ws[r], p.x);
  }
  __syncthreads();
  int cnt = rh[t];
  sc2[t] = cnt;
  __syncthreads();
  for (int d = 1; d < 256; d <<= 1) {
    int u = (t >= d) ? sc2[t - d] : 0;
    __syncthreads();
    sc2[t] += u;
    __syncthreads();
  }
  int gpos = bbase[bk] + sc2[t] - cnt;
  int grow = (bk << 8) + t;  // 625*256 == 160000: always valid
  off[grow] = gpos;
  dinv[grow] = rsqrtf(1.f + ws[t]);
  rh[t] = gpos;  // cursor
  __syncthreads();
  for (int i = t; i < nE; i += 256) {
    float2 p = ebuf[i];
    int r = (__float_as_int(p.y) >> 18) & 255;
    int pos = atomicAdd(&rh[r], 1);
    pack[pos] = p;
  }
}

// ===== fused co-gather + t1 (best-measured variant, R8: 59.5us, occ 75%):
// 4-edge-parallel: wave = 4 groups x 16 lanes; group q handles edge st*4+q each step,
// lane holds float4 of the 64-col fp32 table row PM. Cross-group shfl_xor reduce at row end.
// t1[i] = di*(di*PM[i%Gn] + sum coef*PM[s%Gn]) + Q[i%Gn]
__global__ __launch_bounds__(256) void kgt1(const int* __restrict__ off, const float2* __restrict__ pack,
                                            const float* __restrict__ dinv, const float4* __restrict__ PM4,
                                            const float4* __restrict__ Q4, u16* __restrict__ Ybf,
                                            float* __restrict__ partS) {
  __shared__ float sred[4][64], sqred[4][64];
  int t = threadIdx.x;
  int lane = t & 63, wvv = t >> 6;
  int q = lane >> 4, kq = lane & 15;
  int gw = blockIdx.x * 4 + wvv, nw = gridDim.x * 4;
  float4 sS = make_float4(0.f, 0.f, 0.f, 0.f);
  float4 sQ = make_float4(0.f, 0.f, 0.f, 0.f);
  for (int i = gw; i < Nn; i += nw) {
    int g = i % Gn;
    int b0 = off[i], b1 = off[i + 1];
    float di = dinv[i];
    float4 acc = make_float4(0.f, 0.f, 0.f, 0.f);
    if (q == 0) {
      float4 pm = PM4[g * 16 + kq];
      acc.x = di * pm.x; acc.y = di * pm.y; acc.z = di * pm.z; acc.w = di * pm.w;
    }
    for (int base = b0; base < b1; base += 64) {
      int m = b1 - base; if (m > 64) m = 64;
      float cj = 0.f; int idx16 = 0;
      if (lane < m) {
        float2 p = pack[base + lane];
        int s = __float_as_int(p.y) & 0x3FFFF;
        cj = p.x * dinv[s];
        idx16 = (s % Gn) * 16;
      }
      int steps = (m + 3) >> 2;
      for (int st = 0; st < steps; st++) {
        int e = st * 4 + q;
        float c = __shfl(cj, e, 64);
        int ix = __shfl(idx16, e, 64);
        if (e < m) {
          float4 tv = PM4[ix + kq];
          acc.x = fmaf(c, tv.x, acc.x);
          acc.y = fmaf(c, tv.y, acc.y);
          acc.z = fmaf(c, tv.z, acc.z);
          acc.w = fmaf(c, tv.w, acc.w);
        }
      }
    }
    // cross-group reduce (xor 16, 32): all lanes end with the full edge sum
    acc.x += __shfl_xor(acc.x, 16, 64); acc.y += __shfl_xor(acc.y, 16, 64);
    acc.z += __shfl_xor(acc.z, 16, 64); acc.w += __shfl_xor(acc.w, 16, 64);
    acc.x += __shfl_xor(acc.x, 32, 64); acc.y += __shfl_xor(acc.y, 32, 64);
    acc.z += __shfl_xor(acc.z, 32, 64); acc.w += __shfl_xor(acc.w, 32, 64);
    float4 qv = Q4[g * 16 + kq];
    float4 v;
    v.x = fmaf(di, acc.x, qv.x); v.y = fmaf(di, acc.y, qv.y);
    v.z = fmaf(di, acc.z, qv.z); v.w = fmaf(di, acc.w, qv.w);
    if (q == 0) {
      sS.x += v.x; sS.y += v.y; sS.z += v.z; sS.w += v.w;
      sQ.x += v.x * v.x; sQ.y += v.y * v.y; sQ.z += v.z * v.z; sQ.w += v.w * v.w;
      uint2 o;
      o.x = (u32)f2bf(v.x) | ((u32)f2bf(v.y) << 16);
      o.y = (u32)f2bf(v.z) | ((u32)f2bf(v.w) << 16);
      *(uint2*)&Ybf[(size_t)i * 64 + kq * 4] = o;
    }
  }
  if (q == 0) {
    sred[wvv][kq * 4 + 0] = sS.x; sred[wvv][kq * 4 + 1] = sS.y;
    sred[wvv][kq * 4 + 2] = sS.z; sred[wvv][kq * 4 + 3] = sS.w;
    sqred[wvv][kq * 4 + 0] = sQ.x; sqred[wvv][kq * 4 + 1] = sQ.y;
    sqred[wvv][kq * 4 + 2] = sQ.z; sqred[wvv][kq * 4 + 3] = sQ.w;
  }
  __syncthreads();
  if (t < 64) {
    float s = sred[0][t] + sred[1][t] + sred[2][t] + sred[3][t];
    float qq = sqred[0][t] + sqred[1][t] + sqred[2][t] + sqred[3][t];
    partS[(size_t)blockIdx.x * 128 + t] = s;
    partS[(size_t)blockIdx.x * 128 + 64 + t] = qq;
  }
}

// ===================== MFMA GEMM (one 128-row tile per block) =====================
template <int K, int OUTC, bool PRE, bool EB, bool PERG, bool STATS, bool OUTF32, bool STATB>
__global__ __launch_bounds__(256, 3) void mfgemm(
    const u16* __restrict__ Xb, const float* __restrict__ Wg, const float* __restrict__ bias,
    const float* __restrict__ pa, const float* __restrict__ pb,
    const float* __restrict__ perg, u16* __restrict__ Ybf, float* __restrict__ stats,
    float* __restrict__ statB, int rows) {
  constexpr int NT  = OUTC / 16;   // 16-col output tiles per wave-row
  constexpr int KH  = K / 32;      // MFMA K-steps
  constexpr int SLK = K / 8;       // 16B slots per input row
  constexpr int SLO = OUTC / 8;    // 16B slots per output row
  constexpr int XROW = (K > OUTC ? K : OUTC) * 2;  // bytes per xs row (shared in/out stage)
  __shared__ __align__(16) unsigned char xsb[128 * XROW];
  __shared__ __align__(16) unsigned char wsb[OUTC * K * 2];
  __shared__ float sstat[STATS ? 2 * OUTC : 1];
  __shared__ float sstatB[STATB ? 128 : 1];
  int t = threadIdx.x;
  int l = t & 63, w = t >> 6, lrow = l & 15, lk = l >> 4;
  int R0 = blockIdx.x * 128;

  // ---- stage weights: fp32 -> bf16, swizzled ----
  for (int idx = t; idx < OUTC * SLK; idx += 256) {
    int oc = idx / SLK, s8 = idx % SLK;
    const float* wp = &Wg[oc * K + s8 * 8];
    uint4 o;
    o.x = (u32)f2bf(wp[0]) | ((u32)f2bf(wp[1]) << 16);
    o.y = (u32)f2bf(wp[2]) | ((u32)f2bf(wp[3]) << 16);
    o.z = (u32)f2bf(wp[4]) | ((u32)f2bf(wp[5]) << 16);
    o.w = (u32)f2bf(wp[6]) | ((u32)f2bf(wp[7]) << 16);
    *(uint4*)&wsb[oc * (2 * K) + ((s8 * 16) ^ ((oc & 7) << 4))] = o;
  }
  if constexpr (STATS) for (int idx = t; idx < 2 * OUTC; idx += 256) sstat[idx] = 0.f;
  if constexpr (STATB) for (int idx = t; idx < 128; idx += 256) sstatB[idx] = 0.f;

  // ---- stage input tile: coalesced 16B loads ----
#pragma unroll
  for (int m = 0; m < SLK / 2; m++) {
    int f = m * 256 + t;
    int r = f / SLK, s8 = f % SLK;
    uint4 u = *(const uint4*)&Xb[(size_t)(R0 + r) * K + s8 * 8];
    if constexpr (PRE) {
      int c0 = s8 * 8;
      float4 A0 = *(const float4*)&pa[c0];
      float4 A1 = *(const float4*)&pa[c0 + 4];
      const float* pbb = EB ? &pb[((R0 + r) / Gn) * 64] : pb;
      float4 B0 = *(const float4*)&pbb[c0];
      float4 B1 = *(const float4*)&pbb[c0 + 4];
      float v0 = fmaxf(fmaf(A0.x, bflo(u.x), B0.x), 0.f);
      float v1 = fmaxf(fmaf(A0.y, bfhi(u.x), B0.y), 0.f);
      float v2 = fmaxf(fmaf(A0.z, bflo(u.y), B0.z), 0.f);
      float v3 = fmaxf(fmaf(A0.w, bfhi(u.y), B0.w), 0.f);
      float v4 = fmaxf(fmaf(A1.x, bflo(u.z), B1.x), 0.f);
      float v5 = fmaxf(fmaf(A1.y, bfhi(u.z), B1.y), 0.f);
      float v6 = fmaxf(fmaf(A1.z, bflo(u.w), B1.z), 0.f);
      float v7 = fmaxf(fmaf(A1.w, bfhi(u.w), B1.w), 0.f);
      u.x = (u32)f2bf(v0) | ((u32)f2bf(v1) << 16);
      u.y = (u32)f2bf(v2) | ((u32)f2bf(v3) << 16);
      u.z = (u32)f2bf(v4) | ((u32)f2bf(v5) << 16);
      u.w = (u32)f2bf(v6) | ((u32)f2bf(v7) << 16);
    }
    *(uint4*)&xsb[r * XROW + ((s8 * 16) ^ ((r & 7) << 4))] = u;
  }
  float bcol[NT];
#pragma unroll
  for (int nt = 0; nt < NT; nt++) bcol[nt] = bias[nt * 16 + lrow];
  __syncthreads();

  // ---- MFMA: wave w owns rows w*32..w*32+31, all OUTC cols ----
  short8v af[2][KH];
#pragma unroll
  for (int rt = 0; rt < 2; rt++)
#pragma unroll
    for (int h = 0; h < KH; h++) {
      int row = w * 32 + rt * 16 + lrow;
      af[rt][h] = *(const short8v*)&xsb[row * XROW + ((h * 64 + lk * 16) ^ ((row & 7) << 4))];
    }
  f32x4 acc[2][NT];
#pragma unroll
  for (int rt = 0; rt < 2; rt++)
#pragma unroll
    for (int nt = 0; nt < NT; nt++) {
      f32x4 z = {0.f, 0.f, 0.f, 0.f};
      acc[rt][nt] = z;
    }
#pragma unroll
  for (int nt = 0; nt < NT; nt++) {
    int brow = nt * 16 + lrow;
#pragma unroll
    for (int h = 0; h < KH; h++) {
      short8v bfr = *(const short8v*)&wsb[brow * (2 * K) + ((h * 64 + lk * 16) ^ ((brow & 7) << 4))];
      acc[0][nt] = __builtin_amdgcn_mfma_f32_16x16x32_bf16(af[0][h], bfr, acc[0][nt], 0, 0, 0);
      acc[1][nt] = __builtin_amdgcn_mfma_f32_16x16x32_bf16(af[1][h], bfr, acc[1][nt], 0, 0, 0);
    }
  }
  __syncthreads();  // all xs reads done -> safe to reuse xs as output stage

  // ---- epilogue ----
  float sS[NT], sQ[NT], sB0[NT], sB1[NT];
#pragma unroll
  for (int nt = 0; nt < NT; nt++) { sS[nt] = 0.f; sQ[nt] = 0.f; sB0[nt] = 0.f; sB1[nt] = 0.f; }
  int hiStart = STATB ? (R0 / Gn + 1) * Gn : 0x7fffffff;
  float* Yf = (float*)Ybf;
#pragma unroll
  for (int rt = 0; rt < 2; rt++) {
#pragma unroll
    for (int r = 0; r < 4; r++) {
      int orow = w * 32 + rt * 16 + lk * 4 + r;
      int grow = R0 + orow;
      bool valid = grow < rows;
      int qoff = 0;
      if constexpr (PERG) qoff = (grow % Gn) * 64;
#pragma unroll
      for (int nt = 0; nt < NT; nt++) {
        float v = acc[rt][nt][r] + bcol[nt];
        if constexpr (PERG) v += perg[qoff + nt * 16 + lrow];
        if (valid) {
          if constexpr (STATS) { sS[nt] += v; sQ[nt] += v * v; }
          if constexpr (STATB) { if (grow >= hiStart) sB1[nt] += v; else sB0[nt] += v; }
        }
        if constexpr (OUTF32) {
          if (valid) Yf[(size_t)grow * OUTC + nt * 16 + lrow] = v;
        } else {
          *(u16*)&xsb[orow * (2 * OUTC) + ((2 * (nt * 16 + lrow)) ^ ((orow & 7) << 4))] = f2bf(v);
        }
      }
    }
  }
  if constexpr (STATS) {
#pragma unroll
    for (int nt = 0; nt < NT; nt++) {
      atomicAdd(&sstat[nt * 16 + lrow], sS[nt]);
      atomicAdd(&sstat[OUTC + nt * 16 + lrow], sQ[nt]);
    }
  }
  if constexpr (STATB) {
#pragma unroll
    for (int nt = 0; nt < NT; nt++) {
      atomicAdd(&sstatB[nt * 16 + lrow], sB0[nt]);
      atomicAdd(&sstatB[64 + nt * 16 + lrow], sB1[nt]);
    }
  }
  __syncthreads();

  if constexpr (!OUTF32) {
#pragma unroll
    for (int m = 0; m < SLO / 2; m++) {
      int f = m * 256 + t;
      int r = f / SLO, c8 = f % SLO;
      uint4 o = *(const uint4*)&xsb[r * (2 * OUTC) + ((16 * c8) ^ ((r & 7) << 4))];
      *(uint4*)&Ybf[(size_t)(R0 + r) * OUTC + c8 * 8] = o;
    }
  }
  if constexpr (STATS)
    for (int idx = t; idx < 2 * OUTC; idx += 256) stats[(size_t)blockIdx.x * 2 * OUTC + idx] = sstat[idx];
  if constexpr (STATB)
    for (int idx = t; idx < 128; idx += 256) statB[(size_t)blockIdx.x * 128 + idx] = sstatB[idx];
}

// finalize S3 analytically; Avec = a3*a2, e2[b] = a3*(b2+emb[b]) + b3.
__global__ __launch_bounds__(256) void kfinS3e2(const float* __restrict__ S2, const float* __restrict__ g,
                                                const float* __restrict__ bt, const float* __restrict__ a2,
                                                const float* __restrict__ b2, const float* __restrict__ emb,
                                                const float* __restrict__ S3B,
                                                float* __restrict__ Avec, float* __restrict__ e2) {
  __shared__ float a3s[64], b3s[64];
  int t = threadIdx.x;
  if (t < 64) {
    float a2c = a2[t], b2c = b2[t];
    float su = 0.f, sxc = 0.f, sc2 = 0.f;
    for (int b = 0; b < Bn; b++) {
      float cb = b2c + emb[b * 64 + t];
      float sb = S3B[b * 64 + t];
      su += cb;
      sxc += cb * sb;
      sc2 += cb * cb;
    }
    float Su = a2c * S2[t] + (float)Gn * su;
    float Sq = a2c * a2c * S2[64 + t] + 2.f * a2c * sxc + (float)Gn * sc2;
    float mean = Su * (1.f / Nn);
    float var = Sq * (1.f / Nn) - mean * mean;
    float sc = g[t] * rsqrtf(var + 1e-5f);
    float sh = bt[t] - mean * sc;
    a3s[t] = sc; b3s[t] = sh;
    Avec[t] = sc * a2c;
  }
  __syncthreads();
  for (int idx = t; idx < 2048; idx += 256) {
    int c = idx & 63;
    e2[idx] = a3s[c] * (b2[c] + emb[idx]) + b3s[c];
  }
}

// w1[i] = dot(a5*R2(bf16)+b5, indv_w1[i%G]) + indv_b1[i%G]
__global__ __launch_bounds__(256) void k13_kernel(const u16* __restrict__ R2, const float* __restrict__ a5,
                                                  const float* __restrict__ b5, const float* __restrict__ iw1,
                                                  const float* __restrict__ ib1, float* __restrict__ w1out,
                                                  int rows) {
  int t = blockIdx.x * 256 + threadIdx.x;
  int i = t >> 4, j = t & 15;
  if (i >= rows) return;
  int g = i % Gn;
  uint2 u = *(const uint2*)&R2[(size_t)i * 64 + j * 4];
  float rx = bflo(u.x), ry = bfhi(u.x), rz = bflo(u.y), rw = bfhi(u.y);
  float4 a = ((const float4*)a5)[j];
  float4 b = ((const float4*)b5)[j];
  float4 w = ((const float4*)iw1)[g * 16 + j];
  float p = (a.x * rx + b.x) * w.x + (a.y * ry + b.y) * w.y +
            (a.z * rz + b.z) * w.z + (a.w * rw + b.w) * w.w;
  for (int off = 8; off; off >>= 1) p += __shfl_xor(p, off, 64);
  if (j == 0) w1out[i] = p + ib1[g];
}

// init cgraw with bias
__global__ __launch_bounds__(256) void kinitcg(const float* __restrict__ cgb1, float* __restrict__ cgraw) {
  int idx = blockIdx.x * 256 + threadIdx.x;
  if (idx < Bn * 64) cgraw[idx] = cgb1[idx & 63];
}

// split-K GEMM: cgraw[b][col] += sum_{k in chunk} w1[b][k]*cgW1[col][k]
__global__ __launch_bounds__(256) void kcg1s(const float* __restrict__ w1, const float* __restrict__ cgW1,
                                             float* __restrict__ cgraw) {
  __shared__ float w1s[64 * 36];
  __shared__ float cgs[64 * 65];
  int t = threadIdx.x;
  int k0 = blockIdx.x * 64;
  int kmax = Gn - k0; if (kmax > 64) kmax = 64;
  for (int idx = t; idx < 2048; idx += 256) {
    int row = idx >> 6, k = idx & 63;
    w1s[k * 36 + row] = (k < kmax) ? w1[row * Gn + k0 + k] : 0.f;
  }
  for (int idx = t; idx < 4096; idx += 256) {
    int col = idx >> 6, k = idx & 63;
    cgs[k * 65 + col] = (k < kmax) ? cgW1[col * Gn + k0 + k] : 0.f;
  }
  __syncthreads();
  int col = t & 63, rg = t >> 6;
  float acc[8];
#pragma unroll
  for (int i = 0; i < 8; i++) acc[i] = 0.f;
  for (int k = 0; k < 64; k++) {
    float wk = cgs[k * 65 + col];
    const float* wr = &w1s[k * 36 + rg * 8];
    float4 r0 = *(const float4*)wr;
    float4 r1 = *(const float4*)(wr + 4);
    acc[0] = fmaf(r0.x, wk, acc[0]);
    acc[1] = fmaf(r0.y, wk, acc[1]);
    acc[2] = fmaf(r0.z, wk, acc[2]);
    acc[3] = fmaf(r0.w, wk, acc[3]);
    acc[4] = fmaf(r1.x, wk, acc[4]);
    acc[5] = fmaf(r1.y, wk, acc[5]);
    acc[6] = fmaf(r1.z, wk, acc[6]);
    acc[7] = fmaf(r1.w, wk, acc[7]);
  }
#pragma unroll
  for (int i = 0; i < 8; i++) atomicAdd(&cgraw[(rg * 8 + i) * 64 + col], acc[i]);
}

// single-block: cg2 = bn2(relu(bn1(cgraw)) @ W2^T + b2)   (BN over 32 rows)
__global__ __launch_bounds__(256) void kcg2(const float* __restrict__ cgraw, const float* __restrict__ g1,
                                            const float* __restrict__ bt1, const float* __restrict__ W2,
                                            const float* __restrict__ b2, const float* __restrict__ g2,
                                            const float* __restrict__ bt2, float* __restrict__ cg2out) {
  int t = threadIdx.x, c = t & 63, bg = t >> 6;
  __shared__ float hmid[2048], sred[4][64], qred[4][64], asc[64], bsh[64];
  float y[8];
  float ps = 0.f, pq = 0.f;
  for (int jb = 0; jb < 8; jb++) {
    int b = bg * 8 + jb;
    float v = cgraw[b * 64 + c];
    y[jb] = v; ps += v; pq += v * v;
  }
  sred[bg][c] = ps; qred[bg][c] = pq;
  __syncthreads();
  if (t < 64) {
    float s = sred[0][t] + sred[1][t] + sred[2][t] + sred[3][t];
    float q = qred[0][t] + qred[1][t] + qred[2][t] + qred[3][t];
    float mean = s * (1.f / 32.f), var = q * (1.f / 32.f) - mean * mean;
    float sc = g1[t] * rsqrtf(var + 1e-5f);
    asc[t] = sc; bsh[t] = bt1[t] - mean * sc;
  }
  __syncthreads();
  for (int jb = 0; jb < 8; jb++) { int b = bg * 8 + jb; hmid[b * 64 + c] = fmaxf(asc[c] * y[jb] + bsh[c], 0.f); }
  __syncthreads();
  ps = 0.f; pq = 0.f;
  for (int jb = 0; jb < 8; jb++) {
    int b = bg * 8 + jb;
    float a = b2[c];
    for (int k = 0; k < 64; k++) a += hmid[b * 64 + k] * W2[c * 64 + k];
    y[jb] = a; ps += a; pq += a * a;
  }
  sred[bg][c] = ps; qred[bg][c] = pq;
  __syncthreads();
  if (t < 64) {
    float s = sred[0][t] + sred[1][t] + sred[2][t] + sred[3][t];
    float q = qred[0][t] + qred[1][t] + qred[2][t] + qred[3][t];
    float mean = s * (1.f / 32.f), var = q * (1.f / 32.f) - mean * mean;
    float sc = g2[t] * rsqrtf(var + 1e-5f);
    asc[t] = sc; bsh[t] = bt2[t] - mean * sc;
  }
  __syncthreads();
  for (int jb = 0; jb < 8; jb++) { int b = bg * 8 + jb; cg2out[b * 64 + c] = asc[c] * y[jb] + bsh[c]; }
}

// single-block: emb = mlp3(pglob[pert_idx]) with BN over 32 rows (m2 is bf16)
__global__ __launch_bounds__(256) void kemb(const u16* __restrict__ m2, const float* __restrict__ aP2,
                                            const float* __restrict__ bP2, const int* __restrict__ pidx,
                                            const float* __restrict__ Wm, const float* __restrict__ bv,
                                            const float* __restrict__ gg, const float* __restrict__ btv,
                                            float* __restrict__ emb) {
  int t = threadIdx.x, c = t & 63, bg = t >> 6;
  __shared__ float xin[2048], hmid[2048], sred[4][64], qred[4][64], asc[64], bsh[64];
  for (int idx = t; idx < 2048; idx += 256) {
    int b = idx >> 6, cc = idx & 63;
    xin[idx] = aP2[cc] * bf2f(m2[(size_t)pidx[b] * 64 + cc]) + bP2[cc];
  }
  __syncthreads();
  float y[8];
  float ps = 0.f, pq = 0.f;
  for (int jb = 0; jb < 8; jb++) {
    int b = bg * 8 + jb;
    float a = bv[c];
    for (int k = 0; k < 64; k++) a += xin[b * 64 + k] * Wm[c * 64 + k];
    y[jb] = a; ps += a; pq += a * a;
  }
  sred[bg][c] = ps; qred[bg][c] = pq;
  __syncthreads();
  if (t < 64) {
    float s = sred[0][t] + sred[1][t] + sred[2][t] + sred[3][t];
    float q = qred[0][t] + qred[1][t] + qred[2][t] + qred[3][t];
    float mean = s * (1.f / 32.f), var = q * (1.f / 32.f) - mean * mean;
    float sc = gg[t] * rsqrtf(var + 1e-5f);
    asc[t] = sc; bsh[t] = btv[t] - mean * sc;
  }
  __syncthreads();
  for (int jb = 0; jb < 8; jb++) { int b = bg * 8 + jb; hmid[b * 64 + c] = fmaxf(asc[c] * y[jb] + bsh[c], 0.f); }
  __syncthreads();
  ps = 0.f; pq = 0.f;
  for (int jb = 0; jb < 8; jb++) {
    int b = bg * 8 + jb;
    float a = bv[64 + c];
    for (int k = 0; k < 64; k++) a += hmid[b * 64 + k] * Wm[4096 + c * 64 + k];
    y[jb] = a; ps += a; pq += a * a;
  }
  sred[bg][c] = ps; qred[bg][c] = pq;
  __syncthreads();
  if (t < 64) {
    float s = sred[0][t] + sred[1][t] + sred[2][t] + sred[3][t];
    float q = qred[0][t] + qred[1][t] + qred[2][t] + qred[3][t];
    float mean = s * (1.f / 32.f), var = q * (1.f / 32.f) - mean * mean;
    float sc = gg[64 + t] * rsqrtf(var + 1e-5f);
    asc[t] = sc; bsh[t] = btv[64 + t] - mean * sc;
  }
  __syncthreads();
  for (int jb = 0; jb < 8; jb++) { int b = bg * 8 + jb; emb[b * 64 + c] = asc[c] * y[jb] + bsh[c]; }
}

// final: out[b][g] = w1*iw2[g][0] + dot(cg2[b], iw2[g][1:65]) + ib2[g] + x[b][g]
__global__ __launch_bounds__(256) void kfinal(const float* __restrict__ w1, const float* __restrict__ cg2,
                                              const float* __restrict__ iw2, const float* __restrict__ ib2,
                                              const float* __restrict__ x, float* __restrict__ out) {
  __shared__ float iws[64 * 65], cgs[2048];
  int t = threadIdx.x;
  int g0 = blockIdx.x * 64;
  for (int idx = t; idx < 64 * 65; idx += 256) {
    int gi = g0 * 65 + idx;
    iws[idx] = (gi < Gn * 65) ? iw2[gi] : 0.f;
  }
  for (int idx = t; idx < 2048; idx += 256) cgs[idx] = cg2[idx];
  __syncthreads();
  int gl = t & 63, bg = t >> 6;
  int g = g0 + gl;
  if (g >= Gn) return;
  float bias = ib2[g];
  for (int jb = 0; jb < 8; jb++) {
    int b = bg * 8 + jb;
    float acc = w1[b * Gn + g] * iws[gl * 65] + bias;
    for (int k = 0; k < 64; k++) acc += cgs[b * 64 + k] * iws[gl * 65 + 1 + k];
    out[b * Gn + g] = acc + x[b * Gn + g];
  }
}

extern "C" void kernel_launch(void* const* d_in, const int* in_sizes, int n_in,
                              void* d_out, int out_size, void* d_ws, size_t ws_size,
                              hipStream_t stream) {
  (void)in_sizes; (void)n_in; (void)out_size;
  if (ws_size < WS_FLOATS * sizeof(float)) return;

  const float* x        = (const float*)d_in[0];
  const int*   pert_idx = (const int*)d_in[1];
  const int*   ei_co    = (const int*)d_in[2];
  const float* w_co     = (const float*)d_in[3];
  const int*   ei_go    = (const int*)d_in[4];
  const float* w_go     = (const float*)d_in[5];
  const int*   ei_bg    = (const int*)d_in[6];
  const float* w_bg     = (const float*)d_in[7];
  const float* gene_tab = (const float*)d_in[8];
  const float* pos_tab  = (const float*)d_in[9];
  const float* go_tab   = (const float*)d_in[10];
  const float* bg_tab   = (const float*)d_in[11];
  const float* bn_g     = (const float*)d_in[12];
  const float* bn_b     = (const float*)d_in[13];
  const float* sg_W     = (const float*)d_in[14];
  const float* sg_b     = (const float*)d_in[15];
  const float* mlp_W    = (const float*)d_in[16];
  const float* mlp_b    = (const float*)d_in[17];
  const float* mlp_g    = (const float*)d_in[18];
  const float* mlp_bt   = (const float*)d_in[19];
  const float* rec_W1   = (const float*)d_in[20];
  const float* rec_b1   = (const float*)d_in[21];
  const float* rec_g1   = (const float*)d_in[22];
  const float* rec_bt1  = (const float*)d_in[23];
  const float* rec_W2   = (const float*)d_in[24];
  const float* rec_b2   = (const float*)d_in[25];
  const float* rec_g2   = (const float*)d_in[26];
  const float* rec_bt2  = (const float*)d_in[27];
  const float* indv_w1  = (const float*)d_in[28];
  const float* indv_b1  = (const float*)d_in[29];
  const float* cg_W1    = (const float*)d_in[30];
  const float* cg_b1    = (const float*)d_in[31];
  const float* cg_g1    = (const float*)d_in[32];
  const float* cg_bt1   = (const float*)d_in[33];
  const float* cg_W2    = (const float*)d_in[34];
  const float* cg_b2    = (const float*)d_in[35];
  const float* cg_g2    = (const float*)d_in[36];
  const float* cg_bt2   = (const float*)d_in[37];
  const float* indv_w2  = (const float*)d_in[38];
  const float* indv_b2  = (const float*)d_in[39];

  float* W = (float*)d_ws;
  float* buf0 = W + oBUF0;
  float* buf1 = W + oBUF1;

  // CSR scratch lives in buf1 lower region (consumed by kgt1 before t2 writes buf1)
  int*    co_off    = (int*)(buf1);                  // 160001
  int*    bbase     = (int*)(buf1 + 200000);         // 626
  int*    Tbk       = (int*)(buf1 + 202000);         // 625 bucket totals
  int*    sbsum     = (int*)(buf1 + 320128);         // go block sums; bg at +64
  float2* co_pack   = (float2*)(buf1 + 400000);      // 1.6M float2
  int*    go_cnt    = (int*)(buf1 + 3700000);
  float2* go_pack   = (float2*)(buf1 + 3720000);
  int*    bg_cnt    = (int*)(buf1 + 4000000);
  float2* bg_pack   = (float2*)(buf1 + 4020000);
  u16*    RPB       = (u16*)(buf1 + 4220000);        // [5120][64] bf16 renormed pos tab
  int*    Cg        = (int*)(buf1 + 4500000);        // [256][625] per-block bucket counts
  int*    Lg        = (int*)(buf1 + 4700000);        // [256][625] per-block local offsets
  int*    go_ticket = (int*)(buf1 + 6200000);
  int*    bg_ticket = (int*)(buf1 + 6400000);
  u16*    pgi       = (u16*)(buf1 + 6600000);        // [5120][128] bf16: go cols 0-63, bg 64-127
  u16*    RGB       = (u16*)(buf1 + 6800000);        // [5120][64] bf16 renormed gene tab
  float2* co_stg    = (float2*)(buf1 + 6963840);     // 1.6M float2 block-major sorted staging

  // stats partial buffers: buf1 upper region (dead co_stg space by the time they're used)
  float* partS = buf1 + 8000000;   // up to [2048][128]
  float* partB = buf1 + 8650000;   // [1250][128]

  // --- phase 0: zero pads + stats (one launch), renorm all 4 tables (one launch) ---
  kzero4<<<30, 256, 0, stream>>>(W, 2048,
                                 buf1 + 6800000 + 160000, 3840,    // RGB pad rows 5000..5119
                                 buf1 + 4220000 + 160000, 3840,    // RPB pad rows 5000..5119
                                 buf1 + 6600000 + 320000, 7680);   // pgi pad rows 5000..5119
  krenorm4<<<640, 256, 0, stream>>>(gene_tab, pos_tab, go_tab, bg_tab,
                                    W + oRG, W + oRP, W + oRGO, W + oRBG,
                                    RGB, RPB, partS);
  kredfin<<<1, 1024, 0, stream>>>(partS, 160, 64, bn_g, bn_b, W + oAG, W + oBG, nullptr, 1.f / Gn);
  ksmallmat<<<1, 256, 0, stream>>>(mlp_W + 8192, sg_W, 0.2f, mlp_b + 128, sg_b, nullptr, 0.2f,
                                   W + oM, 64, W + oCvec);
  ksmallmat<<<1, 256, 0, stream>>>(mlp_W, sg_W + 4096, 1.f, nullptr, nullptr, nullptr, 0.f,
                                   W + oM1, 128, nullptr);
  ksmallmat<<<1, 256, 0, stream>>>(mlp_W, sg_W + 8192, 1.f, mlp_b, sg_b + 64, sg_b + 128, 1.f,
                                   W + oM1 + 64, 128, W + oCcP);
  // Q = relu(AG*RG+BG) @ Mw^T + Cvec  (fp32, added per-row by the fused t1 gather)
  mfgemm<64, 64, true, false, false, false, true, false><<<PTILES, 256, 0, stream>>>(
      RGB, mlp_W + 8192, W + oCvec, W + oAG, W + oBG, nullptr, (u16*)(W + oQ), nullptr, nullptr, Gn);
  // PM = RP @ M^T  (fp32 gather table for fused t1; pad rows never written/read)
  mfgemm<64, 64, false, false, false, false, true, false><<<PTILES, 256, 0, stream>>>(
      RPB, W + oM, W + oZERO, nullptr, nullptr, nullptr, (u16*)(W + oPM), nullptr, nullptr, Gn);

  // --- go+bg graphs (merged dual-graph pipeline) ---
  kzero2<<<20, 256, 0, stream>>>(go_cnt, bg_cnt, 5001);
  khist2<<<2 * NBE, 256, 0, stream>>>(ei_go + EGG, go_cnt, go_ticket,
                                      ei_bg + EGG, bg_cnt, bg_ticket, EGG, NBE);
  kscan1m<<<10, 256, 0, stream>>>(go_cnt, bg_cnt, sbsum, sbsum + 64, Pn, 5);
  kscan2m<<<1, 256, 0, stream>>>(sbsum, sbsum + 64, 5, go_cnt + Pn, bg_cnt + Pn);
  kscan3m<<<10, 256, 0, stream>>>(go_cnt, bg_cnt, sbsum, sbsum + 64, Pn, 5);
  kfilltm<<<2 * NBE, 256, 0, stream>>>(ei_go, ei_go + EGG, w_go, go_cnt, go_ticket, go_pack,
                                       ei_bg, ei_bg + EGG, w_bg, bg_cnt, bg_ticket, bg_pack, EGG, NBE);
  kdinvrowm<<<40, 256, 0, stream>>>(go_cnt, go_pack, W + oDGO, bg_cnt, bg_pack, W + oDBG, Pn, 20);
  kgatherm<<<1024, 256, 0, stream>>>(go_cnt, go_pack, W + oDGO, W + oRGO,
                                     bg_cnt, bg_pack, W + oDBG, W + oRBG, pgi, Pn, 512);

  // --- pert path (MFMA, bf16) ---
  mfgemm<128, 64, false, false, false, true, false, false><<<PTILES, 256, 0, stream>>>(
      pgi, W + oM1, W + oCcP, nullptr, nullptr, nullptr, (u16*)(W + oM1B), partS, nullptr, Pn);
  kredfin<<<1, 1024, 0, stream>>>(partS, PTILES, 64, mlp_g, mlp_bt, W + oAP1, W + oBP1, nullptr, 1.f / Pn);
  mfgemm<64, 64, true, false, false, true, false, false><<<PTILES, 256, 0, stream>>>(
      (u16*)(W + oM1B), mlp_W + 4096, mlp_b + 64, W + oAP1, W + oBP1, nullptr,
      (u16*)(W + oM2B), partS, nullptr, Pn);
  kredfin<<<1, 1024, 0, stream>>>(partS, PTILES, 64, mlp_g + 64, mlp_bt + 64, W + oAP2, W + oBP2, nullptr, 1.f / Pn);
  kemb<<<1, 256, 0, stream>>>((u16*)(W + oM2B), W + oAP2, W + oBP2, pert_idx,
                              mlp_W + 16384, mlp_b + 256, mlp_g + 256, mlp_bt + 256, W + oEMB);

  // --- co graph: LDS counting-sort CSR build ---
  kpsort<<<256, 256, 0, stream>>>(ei_co, ei_co + ECO, w_co, co_stg, Cg, Lg);
  ksumT<<<3, 256, 0, stream>>>(Cg, Tbk);
  kpscan<<<1, 256, 0, stream>>>(Tbk, bbase, co_off + Nn);
  kpcsr2<<<NBK, 256, 0, stream>>>(bbase, Cg, Lg, co_stg, co_off, co_pack, W + oDEG);

  // --- fused gather+t1 (best-measured kgt1): t1 -> buf0 (bf16), partial stats ---
  kgt1<<<2048, 256, 0, stream>>>(co_off, co_pack, W + oDEG, (const float4*)(W + oPM),
                                 (const float4*)(W + oQ), (u16*)buf0, partS);
  kredfin<<<1, 1024, 0, stream>>>(partS, 2048, 64, mlp_g + 128, mlp_bt + 128, W + oA1, W + oB1, nullptr, 1.f / Nn);

  // --- main N pipeline: t1(buf0) -> t2(buf1) -> r1(buf0) -> r2(buf1) ---
  mfgemm<64, 64, true, false, false, true, false, true><<<NTILES, 256, 0, stream>>>(
      (const u16*)buf0, mlp_W + 12288, mlp_b + 192, W + oA1, W + oB1, nullptr,
      (u16*)buf1, partS, partB, Nn);
  kredfin<<<1, 1024, 0, stream>>>(partS, NTILES, 64, mlp_g + 192, mlp_bt + 192, W + oA2, W + oB2, W + oS2, 1.f / Nn);
  kredB<<<32, 64, 0, stream>>>(partB, W + oE2);
  kfinS3e2<<<1, 256, 0, stream>>>(W + oS2, bn_g + 64, bn_b + 64, W + oA2, W + oB2, W + oEMB,
                                  W + oE2, W + oAvec, W + oE2);
  mfgemm<64, 128, true, true, false, true, false, false><<<NTILES, 256, 0, stream>>>(
      (const u16*)buf1, rec_W1, rec_b1, W + oAvec, W + oE2, nullptr, (u16*)buf0, partS, nullptr, Nn);
  kredfin<<<2, 1024, 0, stream>>>(partS, NTILES, 128, rec_g1, rec_bt1, W + oA4, W + oB4, nullptr, 1.f / Nn);
  mfgemm<128, 64, true, false, false, true, false, false><<<NTILES, 256, 0, stream>>>(
      (const u16*)buf0, rec_W2, rec_b2, W + oA4, W + oB4, nullptr, (u16*)buf1, partS, nullptr, Nn);
  kredfin<<<1, 1024, 0, stream>>>(partS, NTILES, 64, rec_g2, rec_bt2, W + oA5, W + oB5, nullptr, 1.f / Nn);
  k13_kernel<<<(Nn * 16 + 255) / 256, 256, 0, stream>>>((const u16*)buf1, W + oA5, W + oB5, indv_w1, indv_b1,
                                                        W + oW1, Nn);
  // cross-gene state
  kinitcg<<<8, 256, 0, stream>>>(cg_b1, W + oCGRAW);
  kcg1s<<<(Gn + 63) / 64, 256, 0, stream>>>(W + oW1, cg_W1, W + oCGRAW);
  kcg2<<<1, 256, 0, stream>>>(W + oCGRAW, cg_g1, cg_bt1, cg_W2, cg_b2, cg_g2, cg_bt2, W + oCG2);
  kfinal<<<(Gn + 63) / 64, 256, 0, stream>>>(W + oW1, W + oCG2, indv_w2, indv_b2, x, (float*)d_out);
}